// Round 14
// baseline (267.476 us; speedup 1.0000x reference)
//
#include <hip/hip_runtime.h>
#include <cstdint>
#include <cstddef>
#include <math.h>

typedef unsigned short u16;
typedef short bf16x8 __attribute__((ext_vector_type(8)));
typedef float f32x4 __attribute__((ext_vector_type(4)));

// ---------- helpers ----------
__device__ __forceinline__ u16 f2bf(float f) {
  union { float f; uint32_t u; } c; c.f = f;
  uint32_t u = c.u;
  return (u16)((u + 0x7FFFu + ((u >> 16) & 1u)) >> 16);
}
__device__ __forceinline__ float bf2f(u16 h) {
  union { uint32_t u; float f; } c; c.u = ((uint32_t)h) << 16;
  return c.f;
}
__device__ __forceinline__ float sigmoidf_(float x) { return 1.f / (1.f + expf(-x)); }

__device__ __forceinline__ void glds16(const void* g, void* l) {
  __builtin_amdgcn_global_load_lds((const __attribute__((address_space(1))) void*)g,
                                   (__attribute__((address_space(3))) void*)l, 16, 0, 0);
}

// column permutation: valid (s<=e) pairs compacted in natural order, invalid at end
__device__ __forceinline__ int col_rank(int p) {
  int s = p / 100, e = p - s * 100;
  int tri = (s * (s - 1)) >> 1;
  return (e >= s) ? (p - tri - s) : (5050 + tri + e);
}

// ---------- conv2: 256->256 grouped k=3, 4-way ic-split reduction (fp32 exact) ----------
__global__ void conv2_r(const float* __restrict__ in, const float* __restrict__ w,
                        const float* __restrict__ bias, float* __restrict__ out) {
  int u = blockIdx.x * 256 + threadIdx.x;   // 102400
  int r = u & 3;
  int quad = u >> 2;
  int sub = quad % 25;
  int tmp = quad / 25;
  int oc = tmp & 255;
  int bb = tmp >> 8;
  int t4 = sub * 4;
  int g = oc >> 6;
  const float* ip = in + ((size_t)bb * 256 + g * 64 + r * 16) * 100 + t4;
  const float* wp = w + (size_t)oc * 192 + r * 48;
  float s0 = 0.f, s1 = 0.f, s2 = 0.f, s3 = 0.f;
  #pragma unroll 4
  for (int i = 0; i < 16; ++i) {
    const float* rr = ip + (size_t)i * 100;
    float4 a = *(const float4*)rr;
    float xm = (t4 > 0) ? rr[-1] : 0.f;
    float xp = (t4 < 96) ? rr[4] : 0.f;
    float w0 = wp[i * 3 + 0], w1 = wp[i * 3 + 1], w2 = wp[i * 3 + 2];
    s0 += w0 * xm + w1 * a.x + w2 * a.y;
    s1 += w0 * a.x + w1 * a.y + w2 * a.z;
    s2 += w0 * a.y + w1 * a.z + w2 * a.w;
    s3 += w0 * a.z + w1 * a.w + w2 * xp;
  }
  s0 += __shfl_xor(s0, 1); s0 += __shfl_xor(s0, 2);
  s1 += __shfl_xor(s1, 1); s1 += __shfl_xor(s1, 2);
  s2 += __shfl_xor(s2, 1); s2 += __shfl_xor(s2, 2);
  s3 += __shfl_xor(s3, 1); s3 += __shfl_xor(s3, 2);
  if (r == 0) {
    float b = bias[oc];
    float4 o;
    o.x = fmaxf(s0 + b, 0.f); o.y = fmaxf(s1 + b, 0.f);
    o.z = fmaxf(s2 + b, 0.f); o.w = fmaxf(s3 + b, 0.f);
    *(float4*)(out + ((size_t)bb * 256 + oc) * 100 + t4) = o;
  }
}

// ---------- fused s1/e1/p branches, 4-way ic-split reduction ----------
__global__ void branch_r(const float* __restrict__ in, const float* __restrict__ wS,
                         const float* __restrict__ bS, const float* __restrict__ wE,
                         const float* __restrict__ bE, const float* __restrict__ wP,
                         const float* __restrict__ bP, float* __restrict__ outS,
                         float* __restrict__ outE, u16* __restrict__ Pt) {
  int u = blockIdx.x * 256 + threadIdx.x;   // 256000
  int r = u & 3;
  int quad = u >> 2;                        // 64000
  int sub = quad % 25;
  int tmp = quad / 25;
  int ocx = tmp % 640;
  int bb = tmp / 640;
  int t4 = sub * 4;
  const float* wp;
  const float* ip;
  int oc, iters;
  if (ocx < 512) {
    int sel = ocx >> 8;
    oc = ocx & 255;
    wp = (sel ? wE : wS) + (size_t)oc * 192 + r * 48;
    int g = oc >> 6;
    ip = in + ((size_t)bb * 256 + g * 64 + r * 16) * 100 + t4;
    iters = 16;
  } else {
    oc = ocx - 512;
    wp = wP + (size_t)oc * 768 + r * 192;
    ip = in + ((size_t)bb * 256 + r * 64) * 100 + t4;
    iters = 64;
  }
  float s0 = 0.f, s1 = 0.f, s2 = 0.f, s3 = 0.f;
  for (int i = 0; i < iters; ++i) {
    const float* rr = ip + (size_t)i * 100;
    float4 a = *(const float4*)rr;
    float xm = (t4 > 0) ? rr[-1] : 0.f;
    float xp = (t4 < 96) ? rr[4] : 0.f;
    float w0 = wp[i * 3 + 0], w1 = wp[i * 3 + 1], w2 = wp[i * 3 + 2];
    s0 += w0 * xm + w1 * a.x + w2 * a.y;
    s1 += w0 * a.x + w1 * a.y + w2 * a.z;
    s2 += w0 * a.y + w1 * a.z + w2 * a.w;
    s3 += w0 * a.z + w1 * a.w + w2 * xp;
  }
  s0 += __shfl_xor(s0, 1); s0 += __shfl_xor(s0, 2);
  s1 += __shfl_xor(s1, 1); s1 += __shfl_xor(s1, 2);
  s2 += __shfl_xor(s2, 1); s2 += __shfl_xor(s2, 2);
  s3 += __shfl_xor(s3, 1); s3 += __shfl_xor(s3, 2);
  if (r == 0) {
    if (ocx < 512) {
      float b = (ocx < 256) ? bS[oc] : bE[oc];
      float* out = (ocx < 256) ? outS : outE;
      float4 o;
      o.x = fmaxf(s0 + b, 0.f); o.y = fmaxf(s1 + b, 0.f);
      o.z = fmaxf(s2 + b, 0.f); o.w = fmaxf(s3 + b, 0.f);
      *(float4*)(out + ((size_t)bb * 256 + oc) * 100 + t4) = o;
    } else {
      float b = bP[oc];
      Pt[((size_t)bb * 100 + t4 + 0) * 128 + oc] = f2bf(fmaxf(s0 + b, 0.f));
      Pt[((size_t)bb * 100 + t4 + 1) * 128 + oc] = f2bf(fmaxf(s1 + b, 0.f));
      Pt[((size_t)bb * 100 + t4 + 2) * 128 + oc] = f2bf(fmaxf(s2 + b, 0.f));
      Pt[((size_t)bb * 100 + t4 + 3) * 128 + oc] = f2bf(fmaxf(s3 + b, 0.f));
    }
  }
}

// ---------- fused prep: castw + cast_wq + invperm + tileinfo + zp + mask rows + conv1 ----------
__global__ void prep_fused(const float* __restrict__ w2a, const float* __restrict__ w2b,
                           const float* __restrict__ w2c, u16* __restrict__ w2a_bf,
                           u16* __restrict__ w2b_pk, u16* __restrict__ w2c_pk,
                           const float* __restrict__ w3d, u16* __restrict__ Wq,
                           int* __restrict__ invperm, int* __restrict__ tinfo,
                           int* __restrict__ order, u16* __restrict__ zp,
                           u16* __restrict__ Mt, const float* __restrict__ inputs,
                           const float* __restrict__ w_b1, const float* __restrict__ b_b1,
                           float* __restrict__ base1) {
  __shared__ __align__(16) u16 ML[4 * 3200];   // 25.6 KB: 4 mask rows
  __shared__ int C[128];
  int bid = blockIdx.x, tid = threadIdx.x;
  if (bid < 576) {
    int i = bid * 256 + tid;
    if (i < 65536) w2a_bf[i] = f2bf(w2a[i]);
    if (i < 147456) {
      int oc = i / 1152, r = i % 1152, kk = r >> 7, ic = r & 127;
      int src = (oc * 128 + ic) * 9 + kk;
      w2b_pk[i] = f2bf(w2b[src]);
      w2c_pk[i] = f2bf(w2c[src]);
    }
  } else if (bid < 640) {
    int u = (bid - 576) * 256 + tid;  // 16384 threads
    int o = u >> 5, n = u & 31;
    const float* src = w3d + (size_t)o * 4096 + n;
    u16* dst = Wq + (size_t)u * 128;
    for (int c0 = 0; c0 < 128; c0 += 8) {
      __align__(16) u16 h[8];
      #pragma unroll
      for (int j = 0; j < 8; ++j) h[j] = f2bf(src[(size_t)(c0 + j) * 32]);
      *(uint4*)(dst + c0) = *(const uint4*)h;
    }
  } else if (bid < 680) {
    int p = (bid - 640) * 256 + tid;
    if (p < 10000) invperm[col_rank(p)] = p;
  } else if (bid == 680) {
    if (tid < 128) zp[tid] = 0;
    int t = tid;
    int kbmin = 0, cnt = 0;
    if (t < 79) {
      int rlo = t * 128;
      int rhi = rlo + 128;
      if (rhi > 5050) rhi = 5050;
      if (rlo < 5050) {
        int s = 0;
        while (100 * (s + 1) - ((s + 1) * s) / 2 <= rlo) ++s;
        int cum = 100 * s - (s * (s - 1)) / 2;
        int tmin = 100, tmax = -1;
        for (int r = rlo; r < rhi; ++r) {
          while (r - cum >= 100 - s) { ++s; cum = 100 * s - (s * (s - 1)) / 2; }
          int e = s + (r - cum);
          float L = (float)(e - s + 2);
          float sp2 = (float)s - 0.5f * L;
          float ep2 = (float)(e + 1) + 0.5f * L;
          int a = (int)floorf(sp2) - 1;
          if (a < 0) a = 0;
          int b = (int)floorf(ep2) + 2;
          if (b > 99) b = 99;
          if (a < tmin) tmin = a;
          if (b > tmax) tmax = b;
        }
        kbmin = tmin >> 1;
        cnt = (tmax >> 1) - kbmin + 1;
      }
      tinfo[2 * t] = kbmin;
      tinfo[2 * t + 1] = cnt;
    }
    if (t < 128) C[t] = (t < 79) ? cnt : -1;
    __syncthreads();
    if (t < 79) {
      int pos = 0;
      int ct = C[t];
      for (int u = 0; u < 79; ++u) {
        int cu = C[u];
        pos += (cu > ct) || (cu == ct && u < t);
      }
      order[pos] = t;
    }
  } else if (bid < 1961) {
    // mask rows: 4 rows per block, built in LDS then written coalesced
    int r0 = (bid - 681) * 4;                  // 0..5116
    uint32_t* MZ = (uint32_t*)ML;
    for (int i = tid; i < 6400; i += 256) MZ[i] = 0;
    __syncthreads();
    int g = tid >> 6, lane = tid & 63;
    int r = r0 + g;
    if (r < 5050 && lane < 32) {
      int n = lane;
      int s = (int)((201.0 - sqrt((double)(40401 - 8 * r))) * 0.5);
      if (s < 0) s = 0;
      while (s * (201 - s) / 2 > r) --s;
      while ((s + 1) * (200 - s) / 2 <= r) ++s;
      int e = s + (r - s * (201 - s) / 2);
      double sp = (double)s, ep = (double)(e + 1);
      double L = ep - sp + 1.0;
      double sp2 = sp - L * 0.5;
      double ep2 = ep + L * 0.5;
      double step = (ep2 - sp2) / 95.0;
      double win[8];
      #pragma unroll
      for (int k = 0; k < 8; ++k) win[k] = 0.0;
      int base = -1;
      #pragma unroll
      for (int jj = 0; jj < 3; ++jj) {
        double pos = sp2 + step * (double)(n * 3 + jj);
        double ip;
        double fr = modf(pos, &ip);
        int it = (int)ip;
        if (it >= 0 && it < 99) {
          if (base < 0) base = it;
          int off = it - base;
          win[off] += (1.0 - fr) / 3.0;
          win[off + 1] += fr / 3.0;
        }
      }
      if (base >= 0) {
        u16* dst = ML + g * 3200 + n;
        #pragma unroll
        for (int k = 0; k < 8; ++k) {
          int t = base + k;
          if (t < 100) dst[t * 32] = f2bf((float)win[k]);
        }
      }
    }
    __syncthreads();
    for (int i = tid; i < 1600; i += 256) {    // 4 rows x 400 uint4
      int rl = i / 400, off = i - rl * 400;
      *(uint4*)(Mt + (size_t)(r0 + rl) * 3200 + off * 8) = ((const uint4*)ML)[i];
    }
  } else {
    // conv1: inputs -> base1 (grouped 4x100->256, k=3, relu), 4-way ic-split
    int u = (bid - 1961) * 256 + tid;          // < 102400
    int r = u & 3;
    int quad = u >> 2;
    int sub = quad % 25;
    int tmp = quad / 25;
    int oc = tmp & 255;
    int bb = tmp >> 8;
    int t4 = sub * 4;
    int g = oc >> 6;
    const float* ip = inputs + ((size_t)bb * 400 + g * 100 + r * 25) * 100 + t4;
    const float* wp = w_b1 + (size_t)oc * 300 + r * 75;
    float s0 = 0.f, s1 = 0.f, s2 = 0.f, s3 = 0.f;
    #pragma unroll 5
    for (int i = 0; i < 25; ++i) {
      const float* rr = ip + (size_t)i * 100;
      float4 a = *(const float4*)rr;
      float xm = (t4 > 0) ? rr[-1] : 0.f;
      float xp = (t4 < 96) ? rr[4] : 0.f;
      float w0 = wp[i * 3 + 0], w1 = wp[i * 3 + 1], w2 = wp[i * 3 + 2];
      s0 += w0 * xm + w1 * a.x + w2 * a.y;
      s1 += w0 * a.x + w1 * a.y + w2 * a.z;
      s2 += w0 * a.y + w1 * a.z + w2 * a.w;
      s3 += w0 * a.z + w1 * a.w + w2 * xp;
    }
    s0 += __shfl_xor(s0, 1); s0 += __shfl_xor(s0, 2);
    s1 += __shfl_xor(s1, 1); s1 += __shfl_xor(s1, 2);
    s2 += __shfl_xor(s2, 1); s2 += __shfl_xor(s2, 2);
    s3 += __shfl_xor(s3, 1); s3 += __shfl_xor(s3, 2);
    if (r == 0) {
      float b = b_b1[oc];
      float4 o;
      o.x = fmaxf(s0 + b, 0.f); o.y = fmaxf(s1 + b, 0.f);
      o.z = fmaxf(s2 + b, 0.f); o.w = fmaxf(s3 + b, 0.f);
      *(float4*)(base1 + ((size_t)bb * 256 + oc) * 100 + t4) = o;
    }
  }
}

// ---------- shared MFMA pieces (T2 XOR-swizzled reads; sources pre-swizzled) ----------
template<int MI>
__device__ __forceinline__ void mfma_stepT(const u16* As, const u16* Bs, int l, int wm, int wn,
                                           f32x4 (&acc)[MI][4]) {
  int m15 = l & 15, q = l >> 4, sw = m15 & 7;
  #pragma unroll
  for (int kk = 0; kk < 2; ++kk) {
    int koff = ((kk * 4 + q) ^ sw) * 8;
    bf16x8 av[MI], bv[4];
    #pragma unroll
    for (int i = 0; i < MI; ++i)
      av[i] = *(const bf16x8*)(As + (size_t)(wm * (MI * 16) + i * 16 + m15) * 64 + koff);
    #pragma unroll
    for (int j = 0; j < 4; ++j)
      bv[j] = *(const bf16x8*)(Bs + (size_t)(wn * 64 + j * 16 + m15) * 64 + koff);
    #pragma unroll
    for (int i = 0; i < MI; ++i) {
      #pragma unroll
      for (int j = 0; j < 4; ++j)
        acc[i][j] = __builtin_amdgcn_mfma_f32_16x16x32_bf16(av[i], bv[j], acc[i][j], 0, 0, 0);
    }
  }
}

// ---------- coalesced epilogue: stage relu'd bf16 tile in LDS (swizzled), write 128B runs ----
__device__ __forceinline__ void epilogue_coal(f32x4 (&acc)[4][4], u16* SH, u16* OUT,
                                              const float* bias, int row0, int col0, int tid,
                                              int l, int wm, int wn, int N, int OC,
                                              long long NPB, const int* colmap) {
  uint32_t* W = (uint32_t*)SH;
  int r4 = (l >> 4) * 4, c1 = l & 15;
  int bb0 = row0 % OC;
  #pragma unroll
  for (int i = 0; i < 4; ++i) {
    int ob = wm * 64 + i * 16 + r4;
    float b0 = bias[bb0 + ob + 0], b1 = bias[bb0 + ob + 1];
    float b2 = bias[bb0 + ob + 2], b3 = bias[bb0 + ob + 3];
    int jj = ob >> 1;
    #pragma unroll
    for (int j = 0; j < 4; ++j) {
      int col = wn * 64 + j * 16 + c1;
      f32x4 v = acc[i][j];
      uint32_t lo = (uint32_t)f2bf(fmaxf(v[0] + b0, 0.f)) |
                    ((uint32_t)f2bf(fmaxf(v[1] + b1, 0.f)) << 16);
      uint32_t hi = (uint32_t)f2bf(fmaxf(v[2] + b2, 0.f)) |
                    ((uint32_t)f2bf(fmaxf(v[3] + b3, 0.f)) << 16);
      W[col * 64 + (jj ^ (col & 31))] = lo;
      W[col * 64 + ((jj + 1) ^ (col & 31))] = hi;
    }
  }
  __syncthreads();
  int col = tid >> 1, half = tid & 1;
  int gcol = col0 + col;
  if (gcol < N) {
    int pcol = colmap ? colmap[gcol] : gcol;
    const uint32_t* Wc = W + col * 64;
    __align__(16) uint32_t tbuf[32];
    #pragma unroll
    for (int k = 0; k < 32; ++k) tbuf[k] = Wc[(half * 32 + k) ^ (col & 31)];
    u16* dst = OUT + (size_t)(row0 / OC) * (size_t)OC * (size_t)NPB + (size_t)pcol * OC +
               bb0 + half * 64;
    #pragma unroll
    for (int q = 0; q < 8; ++q) *(uint4*)(dst + q * 8) = *(const uint4*)(tbuf + q * 4);
  }
}

// ---------- generic BT-GEMM; single-buffer 2-barrier loop (m97 structure) ----------
__global__ __launch_bounds__(256, 2) void gemm_bt(const u16* __restrict__ A,
                                                  const u16* __restrict__ B,
                                                  u16* __restrict__ OUT,
                                                  const float* __restrict__ bias, int N, int K,
                                                  const int* __restrict__ tinfo,
                                                  const int* __restrict__ order, int kblocks,
                                                  int OC, long long NPB, int NclampB,
                                                  const int* __restrict__ colmap) {
  __shared__ __align__(16) u16 SH[2 * 128 * 64];
  u16* As = SH;
  u16* Bs = SH + 128 * 64;
  int mt = blockIdx.x;
  int nt = order ? order[blockIdx.y] : blockIdx.y;
  int col0 = nt * 128, row0 = mt * 128;
  int tid = threadIdx.x, w = tid >> 6, l = tid & 63;
  int wm = w >> 1, wn = w & 1;
  int lr = l >> 3;
  int lk_sw = ((l & 7) ^ lr) * 8;
  f32x4 acc[4][4] = {};
  size_t aoff[4];
  size_t boff[4];
  #pragma unroll
  for (int r = 0; r < 4; ++r) {
    int chunk = r * 4 + w;
    int rowA = row0 + chunk * 8 + lr;
    aoff[r] = (size_t)rowA * K + lk_sw;
    int colB = col0 + chunk * 8 + lr;
    if (colB >= NclampB) colB = NclampB - 1;
    boff[r] = (size_t)colB * K + lk_sw;
  }
  int kbmin = 0, cnt = kblocks;
  if (tinfo) { kbmin = tinfo[2 * nt]; cnt = tinfo[2 * nt + 1]; }
  for (int i = 0; i < cnt; ++i) {
    int k0 = (kbmin + i) * 64;
    #pragma unroll
    for (int r = 0; r < 4; ++r) {
      int chunk = r * 4 + w;
      glds16(A + aoff[r] + k0, As + chunk * 512);
      glds16(B + boff[r] + k0, Bs + chunk * 512);
    }
    __syncthreads();
    mfma_stepT<4>(As, Bs, l, wm, wn, acc);
    __syncthreads();
  }
  epilogue_coal(acc, SH, OUT, bias, row0, col0, tid, l, wm, wn, N, OC, NPB, colmap);
}

// ---------- qprep as MFMA GEMM + fused start/end sigmoid heads ----------
// NOTE: e1buf/s1buf must NOT alias Qb (GEMM blocks run concurrently with sigmoid blocks)
__global__ __launch_bounds__(256, 2) void qprep_sig(const u16* __restrict__ Wq,
                                                    const u16* __restrict__ Pt,
                                                    u16* __restrict__ Qb,
                                                    const float* __restrict__ s1,
                                                    const float* __restrict__ e1,
                                                    const float* __restrict__ ws2,
                                                    const float* __restrict__ bs2,
                                                    const float* __restrict__ we2,
                                                    const float* __restrict__ be2,
                                                    float* __restrict__ out) {
  if (blockIdx.x == 128) {
    int t = threadIdx.x & 127;
    int sel = threadIdx.x >> 7;
    int bb = blockIdx.y;
    if (t >= 100) return;
    const float* in = sel ? e1 : s1;
    const float* w = sel ? we2 : ws2;
    float s = sel ? be2[0] : bs2[0];
    #pragma unroll 8
    for (int c = 0; c < 256; ++c) s += w[c] * in[((size_t)bb * 256 + c) * 100 + t];
    out[80000 + sel * 400 + bb * 100 + t] = sigmoidf_(s);
    return;
  }
  __shared__ __align__(16) u16 As[128 * 64];
  __shared__ __align__(16) u16 Bs[128 * 64];
  int mt = blockIdx.x, nt = blockIdx.y;
  int col0 = nt * 128, row0 = mt * 128;
  int tid = threadIdx.x, w = tid >> 6, l = tid & 63;
  int wm = w >> 1, wn = w & 1;
  int lr = l >> 3;
  int lk_sw = ((l & 7) ^ lr) * 8;
  f32x4 acc[4][4] = {};
  size_t aoff[4];
  size_t boff[4];
  #pragma unroll
  for (int r = 0; r < 4; ++r) {
    int chunk = r * 4 + w;
    int rowA = row0 + chunk * 8 + lr;
    aoff[r] = (size_t)rowA * 128 + lk_sw;
    int colB = col0 + chunk * 8 + lr;
    if (colB >= 400) colB = 399;
    boff[r] = (size_t)colB * 128 + lk_sw;
  }
  #pragma unroll
  for (int kb = 0; kb < 2; ++kb) {
    int k0 = kb * 64;
    #pragma unroll
    for (int r = 0; r < 4; ++r) {
      int chunk = r * 4 + w;
      glds16(Wq + aoff[r] + k0, As + chunk * 512);
      glds16(Pt + boff[r] + k0, Bs + chunk * 512);
    }
    __syncthreads();
    mfma_stepT<4>(As, Bs, l, wm, wn, acc);
    __syncthreads();
  }
  int r4 = (l >> 4) * 4, c1 = l & 15;
  #pragma unroll
  for (int i = 0; i < 4; ++i) {
    int row = row0 + wm * 64 + i * 16 + r4;
    int o = row >> 5, n = row & 31;
    #pragma unroll
    for (int j = 0; j < 4; ++j) {
      int col = col0 + wn * 64 + j * 16 + c1;
      if (col < 400) {
        int b = col / 100, t = col - b * 100;
        f32x4 v = acc[i][j];
        __align__(8) u16 h[4];
        h[0] = f2bf(v[0]);
        h[1] = f2bf(v[1]);
        h[2] = f2bf(v[2]);
        h[3] = f2bf(v[3]);
        *(uint2*)(Qb + ((size_t)(b * 512 + o)) * 3200 + t * 32 + n) = *(const uint2*)h;
      }
    }
  }
}

// ---------- 3x3 conv as shifted BT-GEMM; FUSE=1 computes conf head in-epilogue ----------
template<int FUSE>
__global__ __launch_bounds__(256, 2) void conv3x3_gemm(const u16* __restrict__ Apk,
                                                       const u16* __restrict__ X,
                                                       u16* __restrict__ OUT,
                                                       const float* __restrict__ bias,
                                                       const u16* __restrict__ zp,
                                                       const float* __restrict__ w2d,
                                                       const float* __restrict__ b2d,
                                                       float* __restrict__ out) {
  __shared__ __align__(16) u16 SH[2 * 128 * 64];   // As | Bs ; reused by epilogues (32KB)
  u16* As = SH;
  u16* Bs = SH + 128 * 64;
  int nt = blockIdx.x;
  int col0 = nt * 128;
  int tid = threadIdx.x, w = tid >> 6, l = tid & 63;
  int wm = w >> 1, wn = w & 1;
  int lr = l >> 3;
  int lk_sw = ((l & 7) ^ lr) * 8;
  int cj[4], yy[4], xx[4];
  bool vv[4];
  size_t aoff[4];
  #pragma unroll
  for (int r = 0; r < 4; ++r) {
    int chunk = r * 4 + w;
    int c = col0 + chunk * 8 + lr;
    cj[r] = c;
    vv[r] = (c < 40000);
    int p = c % 10000;
    yy[r] = p / 100;
    xx[r] = p % 100;
    aoff[r] = (size_t)(chunk * 8 + lr) * 1152 + lk_sw;
  }
  f32x4 acc[4][4] = {};
  for (int s = 0; s < 9; ++s) {
    int dy = s / 3 - 1, dx = s % 3 - 1;
    int doff = dy * 100 + dx;
    #pragma unroll
    for (int half = 0; half < 2; ++half) {
      int k0 = s * 128 + half * 64;
      int c0 = half * 64;
      #pragma unroll
      for (int r = 0; r < 4; ++r) {
        int chunk = r * 4 + w;
        glds16(Apk + aoff[r] + k0, As + chunk * 512);
        int y2 = yy[r] + dy, x2 = xx[r] + dx;
        bool ok = vv[r] && ((unsigned)y2 < 100u) && ((unsigned)x2 < 100u);
        const u16* src = ok ? (X + (size_t)(cj[r] + doff) * 128 + c0 + lk_sw) : zp;
        glds16(src, Bs + chunk * 512);
      }
      __syncthreads();
      mfma_stepT<4>(As, Bs, l, wm, wn, acc);
      __syncthreads();
    }
  }
  if (FUSE == 0) {
    epilogue_coal(acc, SH, OUT, bias, 0, col0, tid, l, wm, wn, 40000, 128, 40000LL, nullptr);
  } else {
    // stage relu'd bf16 tile (128 ch x 128 cols) into LDS, swizzled u32 layout
    uint32_t* W = (uint32_t*)SH;
    int r4 = (l >> 4) * 4, c1 = l & 15;
    #pragma unroll
    for (int i = 0; i < 4; ++i) {
      int ob = wm * 64 + i * 16 + r4;
      float b0 = bias[ob + 0], b1 = bias[ob + 1], b2 = bias[ob + 2], b3 = bias[ob + 3];
      #pragma unroll
      for (int j = 0; j < 4; ++j) {
        int col = wn * 64 + j * 16 + c1;
        f32x4 v = acc[i][j];
        uint32_t lo = (uint32_t)f2bf(fmaxf(v[0] + b0, 0.f)) |
                      ((uint32_t)f2bf(fmaxf(v[1] + b1, 0.f)) << 16);
        uint32_t hi = (uint32_t)f2bf(fmaxf(v[2] + b2, 0.f)) |
                      ((uint32_t)f2bf(fmaxf(v[3] + b3, 0.f)) << 16);
        int jj = ob >> 1;
        W[col * 64 + (jj ^ (col & 31))] = lo;
        W[col * 64 + ((jj + 1) ^ (col & 31))] = hi;
      }
    }
    __syncthreads();
    int col = tid & 127, sel = tid >> 7;
    int gcol = col0 + col;
    if (gcol < 40000) {
      float sum = b2d[sel];
      const uint32_t* Wc = W + col * 64;
      const float* wd = w2d + sel * 128;
      #pragma unroll 8
      for (int c = 0; c < 64; ++c) {
        uint32_t v = Wc[c ^ (col & 31)];
        sum += wd[2 * c] * bf2f((u16)(v & 0xffffu)) + wd[2 * c + 1] * bf2f((u16)(v >> 16));
      }
      int b = gcol / 10000, pidx = gcol - b * 10000;
      out[((size_t)b * 2 + sel) * 10000 + pidx] = sigmoidf_(sum);
    }
  }
}

// ---------- launch ----------
extern "C" void kernel_launch(void* const* d_in, const int* in_sizes, int n_in, void* d_out,
                              int out_size, void* d_ws, size_t ws_size, hipStream_t stream) {
  const float* inputs = (const float*)d_in[0];
  const float* w_b1 = (const float*)d_in[1];
  const float* b_b1 = (const float*)d_in[2];
  const float* w_b2 = (const float*)d_in[3];
  const float* b_b2 = (const float*)d_in[4];
  const float* w_s1 = (const float*)d_in[5];
  const float* b_s1 = (const float*)d_in[6];
  const float* w_s2 = (const float*)d_in[7];
  const float* b_s2 = (const float*)d_in[8];
  const float* w_e1 = (const float*)d_in[9];
  const float* b_e1 = (const float*)d_in[10];
  const float* w_e2 = (const float*)d_in[11];
  const float* b_e2 = (const float*)d_in[12];
  const float* w_p1 = (const float*)d_in[13];
  const float* b_p1 = (const float*)d_in[14];
  const float* w3d = (const float*)d_in[15];
  const float* b3d = (const float*)d_in[16];
  const float* w2a = (const float*)d_in[17];
  const float* b2a = (const float*)d_in[18];
  const float* w2b = (const float*)d_in[19];
  const float* b2b = (const float*)d_in[20];
  const float* w2c = (const float*)d_in[21];
  const float* b2c = (const float*)d_in[22];
  const float* w2d = (const float*)d_in[23];
  const float* b2d = (const float*)d_in[24];
  float* out = (float*)d_out;
  char* ws = (char*)d_ws;

  int* tinfo = (int*)(ws + 0);
  int* order = (int*)(ws + 2048);
  u16* zp = (u16*)(ws + 16384);
  int* invperm = (int*)(ws + 45056);
  float* base1 = (float*)(ws + 90112);          // 409600
  float* base = (float*)(ws + 499712);          // 409600
  float* s1buf = (float*)(ws + 909312);         // 409600
  u16* Pt = (u16*)(ws + 1318912);               // 102400
  u16* w2a_bf = (u16*)(ws + 1421312);           // 131072
  u16* w2b_pk = (u16*)(ws + 1552384);           // 294912
  u16* w2c_pk = (u16*)(ws + 1847296);           // 294912
  u16* Qb = (u16*)(ws + 2142208);               // 13107200 (ends 15249408)
  u16* Mt = (u16*)(ws + 15249408);              // rows 0..5119 used -> ends 48017408
  float* e1buf = (float*)(ws + 48017408);       // 409600, in Mt-region free tail (no alias!)
  u16* C1t = (u16*)(ws + 79249408);             // 40960000  (end 120209408)
  u16* Wq = (u16*)(ws + 79249408);              // aliases C1t: dead before G1 writes C1t
  u16* x2t = Qb;   // alias: Qb dead after G1
  u16* x3t = C1t;  // alias: C1t dead after G2

  // 1) fused prep: weight casts, invperm, tile spans + order, zero page, mask rows, conv1
  prep_fused<<<2361, 256, 0, stream>>>(w2a, w2b, w2c, w2a_bf, w2b_pk, w2c_pk, w3d, Wq,
                                       invperm, tinfo, order, zp, Mt, inputs, w_b1, b_b1,
                                       base1);

  // 2-3) front end (fp32 exact, 4-way ic-split reductions)
  conv2_r<<<400, 256, 0, stream>>>(base1, w_b2, b_b2, base);
  branch_r<<<1000, 256, 0, stream>>>(base, w_s1, b_s1, w_e1, b_e1, w_p1, b_p1,
                                     s1buf, e1buf, Pt);

  // 4) qprep GEMM [16384 x 400 x 128] + fused start/end sigmoid heads
  qprep_sig<<<dim3(129, 4), 256, 0, stream>>>(Wq, Pt, Qb, s1buf, e1buf, w_s2, b_s2,
                                              w_e2, b_e2, out);

  // 5) G1: out3d, 128x128 tiles, longest-first; de-permuted coalesced store into C1t
  gemm_bt<<<dim3(16, 79), 256, 0, stream>>>(Qb, Mt, C1t, b3d, 10000, 3200, tinfo, order, 50,
                                            512, 10000LL, 10000, invperm);
  // 6) G2: 1x1 conv 512->128
  gemm_bt<<<dim3(1, 313), 256, 0, stream>>>(w2a_bf, C1t, x2t, b2a, 40000, 512, nullptr,
                                            nullptr, 8, 128, 40000LL, 40000, nullptr);
  // 7) G3: 3x3 conv 128->128
  conv3x3_gemm<0><<<dim3(313), 256, 0, stream>>>(w2b_pk, x2t, x3t, b2b, zp, nullptr, nullptr,
                                                 nullptr);
  // 8) G4: 3x3 conv 128->128 + fused conf head (no x4 global round-trip)
  conv3x3_gemm<1><<<dim3(313), 256, 0, stream>>>(w2c_pk, x3t, nullptr, b2c, zp, w2d, b2d,
                                                 out);
}

// Round 15
// 258.965 us; speedup vs baseline: 1.0329x; 1.0329x over previous
//
#include <hip/hip_runtime.h>
#include <cstdint>
#include <cstddef>
#include <math.h>

typedef unsigned short u16;
typedef short bf16x8 __attribute__((ext_vector_type(8)));
typedef float f32x4 __attribute__((ext_vector_type(4)));

// ---------- helpers ----------
__device__ __forceinline__ u16 f2bf(float f) {
  union { float f; uint32_t u; } c; c.f = f;
  uint32_t u = c.u;
  return (u16)((u + 0x7FFFu + ((u >> 16) & 1u)) >> 16);
}
__device__ __forceinline__ float bf2f(u16 h) {
  union { uint32_t u; float f; } c; c.u = ((uint32_t)h) << 16;
  return c.f;
}
__device__ __forceinline__ float sigmoidf_(float x) { return 1.f / (1.f + expf(-x)); }

__device__ __forceinline__ void glds16(const void* g, void* l) {
  __builtin_amdgcn_global_load_lds((const __attribute__((address_space(1))) void*)g,
                                   (__attribute__((address_space(3))) void*)l, 16, 0, 0);
}

// column permutation: valid (s<=e) pairs compacted in natural order, invalid at end
__device__ __forceinline__ int col_rank(int p) {
  int s = p / 100, e = p - s * 100;
  int tri = (s * (s - 1)) >> 1;
  return (e >= s) ? (p - tri - s) : (5050 + tri + e);
}

// ---------- front-end 1D convs, ILP version: 4 t per thread via float4 ----------
__global__ void conv1d_k3v(const float* __restrict__ in, const float* __restrict__ w,
                           const float* __restrict__ bias, float* __restrict__ out,
                           int Cin_total, int Cin_g, int ocPerGroup, int OC) {
  int idx = blockIdx.x * 256 + threadIdx.x;
  int sub = idx % 25;
  int tmp = idx / 25;
  int oc = tmp % OC;
  int bb = tmp / OC;
  if (bb >= 4) return;
  int t4 = sub * 4;
  int g = oc / ocPerGroup;
  const float* ip = in + ((size_t)bb * Cin_total + (size_t)g * Cin_g) * 100 + t4;
  const float* wp = w + (size_t)oc * Cin_g * 3;
  float bs = bias[oc];
  float s0 = bs, s1 = bs, s2 = bs, s3 = bs;
  #pragma unroll 4
  for (int ic = 0; ic < Cin_g; ++ic) {
    const float* r = ip + (size_t)ic * 100;
    float4 a = *(const float4*)r;
    float xm = (t4 > 0) ? r[-1] : 0.f;
    float xp = (t4 < 96) ? r[4] : 0.f;
    float w0 = wp[ic * 3 + 0], w1 = wp[ic * 3 + 1], w2 = wp[ic * 3 + 2];
    s0 += w0 * xm + w1 * a.x + w2 * a.y;
    s1 += w0 * a.x + w1 * a.y + w2 * a.z;
    s2 += w0 * a.y + w1 * a.z + w2 * a.w;
    s3 += w0 * a.z + w1 * a.w + w2 * xp;
  }
  float4 o;
  o.x = fmaxf(s0, 0.f); o.y = fmaxf(s1, 0.f);
  o.z = fmaxf(s2, 0.f); o.w = fmaxf(s3, 0.f);
  *(float4*)(out + ((size_t)bb * OC + oc) * 100 + t4) = o;
}

// fused s1/e1/p branches (all read `base`), ILP version
__global__ void conv1d_branch_v(const float* __restrict__ in, const float* __restrict__ wS,
                                const float* __restrict__ bS, const float* __restrict__ wE,
                                const float* __restrict__ bE, const float* __restrict__ wP,
                                const float* __restrict__ bP, float* __restrict__ outS,
                                float* __restrict__ outE, u16* __restrict__ Pt) {
  int idx = blockIdx.x * 256 + threadIdx.x;
  int sub = idx % 25;
  int tmp = idx / 25;
  int ocx = tmp % 640;
  int bb = tmp / 640;
  if (bb >= 4) return;
  int t4 = sub * 4;
  const float* w;
  const float* bias;
  const float* ip;
  int Cin_g, oc;
  if (ocx < 512) {
    int sel = ocx >> 8;
    oc = ocx & 255;
    w = sel ? wE : wS;
    bias = sel ? bE : bS;
    int g = oc >> 6;
    ip = in + ((size_t)bb * 256 + (size_t)g * 64) * 100 + t4;
    Cin_g = 64;
  } else {
    oc = ocx - 512;
    w = wP;
    bias = bP;
    ip = in + (size_t)bb * 256 * 100 + t4;
    Cin_g = 256;
  }
  const float* wp = w + (size_t)oc * Cin_g * 3;
  float bs = bias[oc];
  float s0 = bs, s1 = bs, s2 = bs, s3 = bs;
  #pragma unroll 4
  for (int ic = 0; ic < Cin_g; ++ic) {
    const float* r = ip + (size_t)ic * 100;
    float4 a = *(const float4*)r;
    float xm = (t4 > 0) ? r[-1] : 0.f;
    float xp = (t4 < 96) ? r[4] : 0.f;
    float w0 = wp[ic * 3 + 0], w1 = wp[ic * 3 + 1], w2 = wp[ic * 3 + 2];
    s0 += w0 * xm + w1 * a.x + w2 * a.y;
    s1 += w0 * a.x + w1 * a.y + w2 * a.z;
    s2 += w0 * a.y + w1 * a.z + w2 * a.w;
    s3 += w0 * a.z + w1 * a.w + w2 * xp;
  }
  if (ocx < 512) {
    float* out = (ocx < 256) ? outS : outE;
    float4 o;
    o.x = fmaxf(s0, 0.f); o.y = fmaxf(s1, 0.f);
    o.z = fmaxf(s2, 0.f); o.w = fmaxf(s3, 0.f);
    *(float4*)(out + ((size_t)bb * 256 + oc) * 100 + t4) = o;
  } else {
    Pt[((size_t)bb * 100 + t4 + 0) * 128 + oc] = f2bf(fmaxf(s0, 0.f));
    Pt[((size_t)bb * 100 + t4 + 1) * 128 + oc] = f2bf(fmaxf(s1, 0.f));
    Pt[((size_t)bb * 100 + t4 + 2) * 128 + oc] = f2bf(fmaxf(s2, 0.f));
    Pt[((size_t)bb * 100 + t4 + 3) * 128 + oc] = f2bf(fmaxf(s3, 0.f));
  }
}

// ---------- fused prep: castw + cast_wq + invperm + tileinfo + zp + mask rows + conv1 ----------
__global__ void prep_fused(const float* __restrict__ w2a, const float* __restrict__ w2b,
                           const float* __restrict__ w2c, u16* __restrict__ w2a_bf,
                           u16* __restrict__ w2b_pk, u16* __restrict__ w2c_pk,
                           const float* __restrict__ w3d, u16* __restrict__ Wq,
                           int* __restrict__ invperm, int* __restrict__ tinfo,
                           int* __restrict__ order, u16* __restrict__ zp,
                           u16* __restrict__ Mt, const float* __restrict__ inputs,
                           const float* __restrict__ w_b1, const float* __restrict__ b_b1,
                           float* __restrict__ base1) {
  __shared__ __align__(16) u16 ML[4 * 3200];   // 25.6 KB: 4 mask rows
  __shared__ int C[128];
  int bid = blockIdx.x, tid = threadIdx.x;
  if (bid < 576) {
    int i = bid * 256 + tid;
    if (i < 65536) w2a_bf[i] = f2bf(w2a[i]);
    if (i < 147456) {
      int oc = i / 1152, r = i % 1152, kk = r >> 7, ic = r & 127;
      int src = (oc * 128 + ic) * 9 + kk;
      w2b_pk[i] = f2bf(w2b[src]);
      w2c_pk[i] = f2bf(w2c[src]);
    }
  } else if (bid < 640) {
    int u = (bid - 576) * 256 + tid;  // 16384 threads
    int o = u >> 5, n = u & 31;
    const float* src = w3d + (size_t)o * 4096 + n;
    u16* dst = Wq + (size_t)u * 128;
    for (int c0 = 0; c0 < 128; c0 += 8) {
      __align__(16) u16 h[8];
      #pragma unroll
      for (int j = 0; j < 8; ++j) h[j] = f2bf(src[(size_t)(c0 + j) * 32]);
      *(uint4*)(dst + c0) = *(const uint4*)h;
    }
  } else if (bid < 680) {
    int p = (bid - 640) * 256 + tid;
    if (p < 10000) invperm[col_rank(p)] = p;
  } else if (bid == 680) {
    if (tid < 128) zp[tid] = 0;
    int t = tid;
    int kbmin = 0, cnt = 0;
    if (t < 79) {
      int rlo = t * 128;
      int rhi = rlo + 128;
      if (rhi > 5050) rhi = 5050;
      if (rlo < 5050) {
        int s = 0;
        while (100 * (s + 1) - ((s + 1) * s) / 2 <= rlo) ++s;
        int cum = 100 * s - (s * (s - 1)) / 2;
        int tmin = 100, tmax = -1;
        for (int r = rlo; r < rhi; ++r) {
          while (r - cum >= 100 - s) { ++s; cum = 100 * s - (s * (s - 1)) / 2; }
          int e = s + (r - cum);
          float L = (float)(e - s + 2);
          float sp2 = (float)s - 0.5f * L;
          float ep2 = (float)(e + 1) + 0.5f * L;
          int a = (int)floorf(sp2) - 1;
          if (a < 0) a = 0;
          int b = (int)floorf(ep2) + 2;
          if (b > 99) b = 99;
          if (a < tmin) tmin = a;
          if (b > tmax) tmax = b;
        }
        kbmin = tmin >> 1;
        cnt = (tmax >> 1) - kbmin + 1;
      }
      tinfo[2 * t] = kbmin;
      tinfo[2 * t + 1] = cnt;
    }
    if (t < 128) C[t] = (t < 79) ? cnt : -1;
    __syncthreads();
    if (t < 79) {
      int pos = 0;
      int ct = C[t];
      for (int u = 0; u < 79; ++u) {
        int cu = C[u];
        pos += (cu > ct) || (cu == ct && u < t);
      }
      order[pos] = t;
    }
  } else if (bid < 1961) {
    // mask rows: 4 rows per block, built in LDS then written coalesced
    int r0 = (bid - 681) * 4;                  // 0..5116
    uint32_t* MZ = (uint32_t*)ML;
    for (int i = tid; i < 6400; i += 256) MZ[i] = 0;
    __syncthreads();
    int g = tid >> 6, lane = tid & 63;
    int r = r0 + g;
    if (r < 5050 && lane < 32) {
      int n = lane;
      int s = (int)((201.0 - sqrt((double)(40401 - 8 * r))) * 0.5);
      if (s < 0) s = 0;
      while (s * (201 - s) / 2 > r) --s;
      while ((s + 1) * (200 - s) / 2 <= r) ++s;
      int e = s + (r - s * (201 - s) / 2);
      double sp = (double)s, ep = (double)(e + 1);
      double L = ep - sp + 1.0;
      double sp2 = sp - L * 0.5;
      double ep2 = ep + L * 0.5;
      double step = (ep2 - sp2) / 95.0;
      double win[8];
      #pragma unroll
      for (int k = 0; k < 8; ++k) win[k] = 0.0;
      int base = -1;
      #pragma unroll
      for (int jj = 0; jj < 3; ++jj) {
        double pos = sp2 + step * (double)(n * 3 + jj);
        double ip;
        double fr = modf(pos, &ip);
        int it = (int)ip;
        if (it >= 0 && it < 99) {
          if (base < 0) base = it;
          int off = it - base;
          win[off] += (1.0 - fr) / 3.0;
          win[off + 1] += fr / 3.0;
        }
      }
      if (base >= 0) {
        u16* dst = ML + g * 3200 + n;
        #pragma unroll
        for (int k = 0; k < 8; ++k) {
          int t = base + k;
          if (t < 100) dst[t * 32] = f2bf((float)win[k]);
        }
      }
    }
    __syncthreads();
    for (int i = tid; i < 1600; i += 256) {    // 4 rows x 400 uint4
      int rl = i / 400, off = i - rl * 400;
      *(uint4*)(Mt + (size_t)(r0 + rl) * 3200 + off * 8) = ((const uint4*)ML)[i];
    }
  } else {
    // conv1: inputs -> base1 (grouped 4x100->256, k=3, relu), ILP float4 version
    int idx = (bid - 1961) * 256 + tid;        // < 25600
    int sub = idx % 25;
    int tmp = idx / 25;
    int oc = tmp % 256;
    int bb = tmp / 256;
    if (bb >= 4) return;
    int t4 = sub * 4;
    int g = oc >> 6;
    const float* ip = inputs + ((size_t)bb * 400 + (size_t)g * 100) * 100 + t4;
    const float* wp = w_b1 + (size_t)oc * 300;
    float bs = b_b1[oc];
    float s0 = bs, s1 = bs, s2 = bs, s3 = bs;
    #pragma unroll 4
    for (int ic = 0; ic < 100; ++ic) {
      const float* rr = ip + (size_t)ic * 100;
      float4 a = *(const float4*)rr;
      float xm = (t4 > 0) ? rr[-1] : 0.f;
      float xp = (t4 < 96) ? rr[4] : 0.f;
      float w0 = wp[ic * 3 + 0], w1 = wp[ic * 3 + 1], w2 = wp[ic * 3 + 2];
      s0 += w0 * xm + w1 * a.x + w2 * a.y;
      s1 += w0 * a.x + w1 * a.y + w2 * a.z;
      s2 += w0 * a.y + w1 * a.z + w2 * a.w;
      s3 += w0 * a.z + w1 * a.w + w2 * xp;
    }
    float4 o;
    o.x = fmaxf(s0, 0.f); o.y = fmaxf(s1, 0.f);
    o.z = fmaxf(s2, 0.f); o.w = fmaxf(s3, 0.f);
    *(float4*)(base1 + ((size_t)bb * 256 + oc) * 100 + t4) = o;
  }
}

// ---------- shared MFMA pieces (T2 XOR-swizzled reads; sources pre-swizzled) ----------
template<int MI>
__device__ __forceinline__ void mfma_stepT(const u16* As, const u16* Bs, int l, int wm, int wn,
                                           f32x4 (&acc)[MI][4]) {
  int m15 = l & 15, q = l >> 4, sw = m15 & 7;
  #pragma unroll
  for (int kk = 0; kk < 2; ++kk) {
    int koff = ((kk * 4 + q) ^ sw) * 8;
    bf16x8 av[MI], bv[4];
    #pragma unroll
    for (int i = 0; i < MI; ++i)
      av[i] = *(const bf16x8*)(As + (size_t)(wm * (MI * 16) + i * 16 + m15) * 64 + koff);
    #pragma unroll
    for (int j = 0; j < 4; ++j)
      bv[j] = *(const bf16x8*)(Bs + (size_t)(wn * 64 + j * 16 + m15) * 64 + koff);
    #pragma unroll
    for (int i = 0; i < MI; ++i) {
      #pragma unroll
      for (int j = 0; j < 4; ++j)
        acc[i][j] = __builtin_amdgcn_mfma_f32_16x16x32_bf16(av[i], bv[j], acc[i][j], 0, 0, 0);
    }
  }
}

// ---------- coalesced epilogue: stage relu'd bf16 tile in LDS (swizzled), write 128B runs ----
__device__ __forceinline__ void epilogue_coal(f32x4 (&acc)[4][4], u16* SH, u16* OUT,
                                              const float* bias, int row0, int col0, int tid,
                                              int l, int wm, int wn, int N, int OC,
                                              long long NPB, const int* colmap) {
  uint32_t* W = (uint32_t*)SH;
  int r4 = (l >> 4) * 4, c1 = l & 15;
  int bb0 = row0 % OC;
  #pragma unroll
  for (int i = 0; i < 4; ++i) {
    int ob = wm * 64 + i * 16 + r4;
    float b0 = bias[bb0 + ob + 0], b1 = bias[bb0 + ob + 1];
    float b2 = bias[bb0 + ob + 2], b3 = bias[bb0 + ob + 3];
    int jj = ob >> 1;
    #pragma unroll
    for (int j = 0; j < 4; ++j) {
      int col = wn * 64 + j * 16 + c1;
      f32x4 v = acc[i][j];
      uint32_t lo = (uint32_t)f2bf(fmaxf(v[0] + b0, 0.f)) |
                    ((uint32_t)f2bf(fmaxf(v[1] + b1, 0.f)) << 16);
      uint32_t hi = (uint32_t)f2bf(fmaxf(v[2] + b2, 0.f)) |
                    ((uint32_t)f2bf(fmaxf(v[3] + b3, 0.f)) << 16);
      W[col * 64 + (jj ^ (col & 31))] = lo;
      W[col * 64 + ((jj + 1) ^ (col & 31))] = hi;
    }
  }
  __syncthreads();
  int col = tid >> 1, half = tid & 1;
  int gcol = col0 + col;
  if (gcol < N) {
    int pcol = colmap ? colmap[gcol] : gcol;
    const uint32_t* Wc = W + col * 64;
    __align__(16) uint32_t tbuf[32];
    #pragma unroll
    for (int k = 0; k < 32; ++k) tbuf[k] = Wc[(half * 32 + k) ^ (col & 31)];
    u16* dst = OUT + (size_t)(row0 / OC) * (size_t)OC * (size_t)NPB + (size_t)pcol * OC +
               bb0 + half * 64;
    #pragma unroll
    for (int q = 0; q < 8; ++q) *(uint4*)(dst + q * 8) = *(const uint4*)(tbuf + q * 4);
  }
}

// ---------- generic BT-GEMM; single-buffer 2-barrier loop (m97 structure) ----------
__global__ __launch_bounds__(256, 2) void gemm_bt(const u16* __restrict__ A,
                                                  const u16* __restrict__ B,
                                                  u16* __restrict__ OUT,
                                                  const float* __restrict__ bias, int N, int K,
                                                  const int* __restrict__ tinfo,
                                                  const int* __restrict__ order, int kblocks,
                                                  int OC, long long NPB, int NclampB,
                                                  const int* __restrict__ colmap) {
  __shared__ __align__(16) u16 SH[2 * 128 * 64];
  u16* As = SH;
  u16* Bs = SH + 128 * 64;
  int mt = blockIdx.x;
  int nt = order ? order[blockIdx.y] : blockIdx.y;
  int col0 = nt * 128, row0 = mt * 128;
  int tid = threadIdx.x, w = tid >> 6, l = tid & 63;
  int wm = w >> 1, wn = w & 1;
  int lr = l >> 3;
  int lk_sw = ((l & 7) ^ lr) * 8;
  f32x4 acc[4][4] = {};
  size_t aoff[4];
  size_t boff[4];
  #pragma unroll
  for (int r = 0; r < 4; ++r) {
    int chunk = r * 4 + w;
    int rowA = row0 + chunk * 8 + lr;
    aoff[r] = (size_t)rowA * K + lk_sw;
    int colB = col0 + chunk * 8 + lr;
    if (colB >= NclampB) colB = NclampB - 1;
    boff[r] = (size_t)colB * K + lk_sw;
  }
  int kbmin = 0, cnt = kblocks;
  if (tinfo) { kbmin = tinfo[2 * nt]; cnt = tinfo[2 * nt + 1]; }
  for (int i = 0; i < cnt; ++i) {
    int k0 = (kbmin + i) * 64;
    #pragma unroll
    for (int r = 0; r < 4; ++r) {
      int chunk = r * 4 + w;
      glds16(A + aoff[r] + k0, As + chunk * 512);
      glds16(B + boff[r] + k0, Bs + chunk * 512);
    }
    __syncthreads();
    mfma_stepT<4>(As, Bs, l, wm, wn, acc);
    __syncthreads();
  }
  epilogue_coal(acc, SH, OUT, bias, row0, col0, tid, l, wm, wn, N, OC, NPB, colmap);
}

// ---------- qprep as MFMA GEMM + fused start/end sigmoid heads ----------
// NOTE: e1buf/s1buf must NOT alias Qb (GEMM blocks run concurrently with sigmoid blocks)
__global__ __launch_bounds__(256, 2) void qprep_sig(const u16* __restrict__ Wq,
                                                    const u16* __restrict__ Pt,
                                                    u16* __restrict__ Qb,
                                                    const float* __restrict__ s1,
                                                    const float* __restrict__ e1,
                                                    const float* __restrict__ ws2,
                                                    const float* __restrict__ bs2,
                                                    const float* __restrict__ we2,
                                                    const float* __restrict__ be2,
                                                    float* __restrict__ out) {
  if (blockIdx.x == 128) {
    int t = threadIdx.x & 127;
    int sel = threadIdx.x >> 7;
    int bb = blockIdx.y;
    if (t >= 100) return;
    const float* in = sel ? e1 : s1;
    const float* w = sel ? we2 : ws2;
    float s = sel ? be2[0] : bs2[0];
    #pragma unroll 8
    for (int c = 0; c < 256; ++c) s += w[c] * in[((size_t)bb * 256 + c) * 100 + t];
    out[80000 + sel * 400 + bb * 100 + t] = sigmoidf_(s);
    return;
  }
  __shared__ __align__(16) u16 As[128 * 64];
  __shared__ __align__(16) u16 Bs[128 * 64];
  int mt = blockIdx.x, nt = blockIdx.y;
  int col0 = nt * 128, row0 = mt * 128;
  int tid = threadIdx.x, w = tid >> 6, l = tid & 63;
  int wm = w >> 1, wn = w & 1;
  int lr = l >> 3;
  int lk_sw = ((l & 7) ^ lr) * 8;
  f32x4 acc[4][4] = {};
  size_t aoff[4];
  size_t boff[4];
  #pragma unroll
  for (int r = 0; r < 4; ++r) {
    int chunk = r * 4 + w;
    int rowA = row0 + chunk * 8 + lr;
    aoff[r] = (size_t)rowA * 128 + lk_sw;
    int colB = col0 + chunk * 8 + lr;
    if (colB >= 400) colB = 399;
    boff[r] = (size_t)colB * 128 + lk_sw;
  }
  #pragma unroll
  for (int kb = 0; kb < 2; ++kb) {
    int k0 = kb * 64;
    #pragma unroll
    for (int r = 0; r < 4; ++r) {
      int chunk = r * 4 + w;
      glds16(Wq + aoff[r] + k0, As + chunk * 512);
      glds16(Pt + boff[r] + k0, Bs + chunk * 512);
    }
    __syncthreads();
    mfma_stepT<4>(As, Bs, l, wm, wn, acc);
    __syncthreads();
  }
  int r4 = (l >> 4) * 4, c1 = l & 15;
  #pragma unroll
  for (int i = 0; i < 4; ++i) {
    int row = row0 + wm * 64 + i * 16 + r4;
    int o = row >> 5, n = row & 31;
    #pragma unroll
    for (int j = 0; j < 4; ++j) {
      int col = col0 + wn * 64 + j * 16 + c1;
      if (col < 400) {
        int b = col / 100, t = col - b * 100;
        f32x4 v = acc[i][j];
        __align__(8) u16 h[4];
        h[0] = f2bf(v[0]);
        h[1] = f2bf(v[1]);
        h[2] = f2bf(v[2]);
        h[3] = f2bf(v[3]);
        *(uint2*)(Qb + ((size_t)(b * 512 + o)) * 3200 + t * 32 + n) = *(const uint2*)h;
      }
    }
  }
}

// ---------- 3x3 conv as shifted BT-GEMM; FUSE=1 computes conf head in-epilogue ----------
template<int FUSE>
__global__ __launch_bounds__(256, 2) void conv3x3_gemm(const u16* __restrict__ Apk,
                                                       const u16* __restrict__ X,
                                                       u16* __restrict__ OUT,
                                                       const float* __restrict__ bias,
                                                       const u16* __restrict__ zp,
                                                       const float* __restrict__ w2d,
                                                       const float* __restrict__ b2d,
                                                       float* __restrict__ out) {
  __shared__ __align__(16) u16 SH[2 * 128 * 64];   // As | Bs ; reused by epilogues (32KB)
  u16* As = SH;
  u16* Bs = SH + 128 * 64;
  int nt = blockIdx.x;
  int col0 = nt * 128;
  int tid = threadIdx.x, w = tid >> 6, l = tid & 63;
  int wm = w >> 1, wn = w & 1;
  int lr = l >> 3;
  int lk_sw = ((l & 7) ^ lr) * 8;
  int cj[4], yy[4], xx[4];
  bool vv[4];
  size_t aoff[4];
  #pragma unroll
  for (int r = 0; r < 4; ++r) {
    int chunk = r * 4 + w;
    int c = col0 + chunk * 8 + lr;
    cj[r] = c;
    vv[r] = (c < 40000);
    int p = c % 10000;
    yy[r] = p / 100;
    xx[r] = p % 100;
    aoff[r] = (size_t)(chunk * 8 + lr) * 1152 + lk_sw;
  }
  f32x4 acc[4][4] = {};
  for (int s = 0; s < 9; ++s) {
    int dy = s / 3 - 1, dx = s % 3 - 1;
    int doff = dy * 100 + dx;
    #pragma unroll
    for (int half = 0; half < 2; ++half) {
      int k0 = s * 128 + half * 64;
      int c0 = half * 64;
      #pragma unroll
      for (int r = 0; r < 4; ++r) {
        int chunk = r * 4 + w;
        glds16(Apk + aoff[r] + k0, As + chunk * 512);
        int y2 = yy[r] + dy, x2 = xx[r] + dx;
        bool ok = vv[r] && ((unsigned)y2 < 100u) && ((unsigned)x2 < 100u);
        const u16* src = ok ? (X + (size_t)(cj[r] + doff) * 128 + c0 + lk_sw) : zp;
        glds16(src, Bs + chunk * 512);
      }
      __syncthreads();
      mfma_stepT<4>(As, Bs, l, wm, wn, acc);
      __syncthreads();
    }
  }
  if (FUSE == 0) {
    epilogue_coal(acc, SH, OUT, bias, 0, col0, tid, l, wm, wn, 40000, 128, 40000LL, nullptr);
  } else {
    // stage relu'd bf16 tile (128 ch x 128 cols) into LDS, swizzled u32 layout
    uint32_t* W = (uint32_t*)SH;
    int r4 = (l >> 4) * 4, c1 = l & 15;
    #pragma unroll
    for (int i = 0; i < 4; ++i) {
      int ob = wm * 64 + i * 16 + r4;
      float b0 = bias[ob + 0], b1 = bias[ob + 1], b2 = bias[ob + 2], b3 = bias[ob + 3];
      #pragma unroll
      for (int j = 0; j < 4; ++j) {
        int col = wn * 64 + j * 16 + c1;
        f32x4 v = acc[i][j];
        uint32_t lo = (uint32_t)f2bf(fmaxf(v[0] + b0, 0.f)) |
                      ((uint32_t)f2bf(fmaxf(v[1] + b1, 0.f)) << 16);
        uint32_t hi = (uint32_t)f2bf(fmaxf(v[2] + b2, 0.f)) |
                      ((uint32_t)f2bf(fmaxf(v[3] + b3, 0.f)) << 16);
        int jj = ob >> 1;
        W[col * 64 + (jj ^ (col & 31))] = lo;
        W[col * 64 + ((jj + 1) ^ (col & 31))] = hi;
      }
    }
    __syncthreads();
    int col = tid & 127, sel = tid >> 7;
    int gcol = col0 + col;
    if (gcol < 40000) {
      float sum = b2d[sel];
      const uint32_t* Wc = W + col * 64;
      const float* wd = w2d + sel * 128;
      #pragma unroll 8
      for (int c = 0; c < 64; ++c) {
        uint32_t v = Wc[c ^ (col & 31)];
        sum += wd[2 * c] * bf2f((u16)(v & 0xffffu)) + wd[2 * c + 1] * bf2f((u16)(v >> 16));
      }
      int b = gcol / 10000, pidx = gcol - b * 10000;
      out[((size_t)b * 2 + sel) * 10000 + pidx] = sigmoidf_(sum);
    }
  }
}

// ---------- launch ----------
extern "C" void kernel_launch(void* const* d_in, const int* in_sizes, int n_in, void* d_out,
                              int out_size, void* d_ws, size_t ws_size, hipStream_t stream) {
  const float* inputs = (const float*)d_in[0];
  const float* w_b1 = (const float*)d_in[1];
  const float* b_b1 = (const float*)d_in[2];
  const float* w_b2 = (const float*)d_in[3];
  const float* b_b2 = (const float*)d_in[4];
  const float* w_s1 = (const float*)d_in[5];
  const float* b_s1 = (const float*)d_in[6];
  const float* w_s2 = (const float*)d_in[7];
  const float* b_s2 = (const float*)d_in[8];
  const float* w_e1 = (const float*)d_in[9];
  const float* b_e1 = (const float*)d_in[10];
  const float* w_e2 = (const float*)d_in[11];
  const float* b_e2 = (const float*)d_in[12];
  const float* w_p1 = (const float*)d_in[13];
  const float* b_p1 = (const float*)d_in[14];
  const float* w3d = (const float*)d_in[15];
  const float* b3d = (const float*)d_in[16];
  const float* w2a = (const float*)d_in[17];
  const float* b2a = (const float*)d_in[18];
  const float* w2b = (const float*)d_in[19];
  const float* b2b = (const float*)d_in[20];
  const float* w2c = (const float*)d_in[21];
  const float* b2c = (const float*)d_in[22];
  const float* w2d = (const float*)d_in[23];
  const float* b2d = (const float*)d_in[24];
  float* out = (float*)d_out;
  char* ws = (char*)d_ws;

  int* tinfo = (int*)(ws + 0);
  int* order = (int*)(ws + 2048);
  u16* zp = (u16*)(ws + 16384);
  int* invperm = (int*)(ws + 45056);
  float* base1 = (float*)(ws + 90112);          // 409600
  float* base = (float*)(ws + 499712);          // 409600
  float* s1buf = (float*)(ws + 909312);         // 409600
  u16* Pt = (u16*)(ws + 1318912);               // 102400
  u16* w2a_bf = (u16*)(ws + 1421312);           // 131072
  u16* w2b_pk = (u16*)(ws + 1552384);           // 294912
  u16* w2c_pk = (u16*)(ws + 1847296);           // 294912
  u16* Qb = (u16*)(ws + 2142208);               // 13107200 (ends 15249408)
  u16* Mt = (u16*)(ws + 15249408);              // rows 0..5119 used -> ends 48017408
  float* e1buf = (float*)(ws + 48017408);       // 409600, in Mt-region free tail (no alias!)
  u16* C1t = (u16*)(ws + 79249408);             // 40960000  (end 120209408)
  u16* Wq = (u16*)(ws + 79249408);              // aliases C1t: dead before G1 writes C1t
  u16* x2t = Qb;   // alias: Qb dead after G1
  u16* x3t = C1t;  // alias: C1t dead after G2

  // 1) fused prep: weight casts, invperm, tile spans + order, zero page, mask rows, conv1
  prep_fused<<<2061, 256, 0, stream>>>(w2a, w2b, w2c, w2a_bf, w2b_pk, w2c_pk, w3d, Wq,
                                       invperm, tinfo, order, zp, Mt, inputs, w_b1, b_b1,
                                       base1);

  // 2-3) front end (fp32 exact, ILP-vectorized)
  conv1d_k3v<<<100, 256, 0, stream>>>(base1, w_b2, b_b2, base, 256, 64, 64, 256);
  conv1d_branch_v<<<250, 256, 0, stream>>>(base, w_s1, b_s1, w_e1, b_e1, w_p1, b_p1,
                                           s1buf, e1buf, Pt);

  // 4) qprep GEMM [16384 x 400 x 128] + fused start/end sigmoid heads
  qprep_sig<<<dim3(129, 4), 256, 0, stream>>>(Wq, Pt, Qb, s1buf, e1buf, w_s2, b_s2,
                                              w_e2, b_e2, out);

  // 5) G1: out3d, 128x128 tiles, longest-first; de-permuted coalesced store into C1t
  gemm_bt<<<dim3(16, 79), 256, 0, stream>>>(Qb, Mt, C1t, b3d, 10000, 3200, tinfo, order, 50,
                                            512, 10000LL, 10000, invperm);
  // 6) G2: 1x1 conv 512->128
  gemm_bt<<<dim3(1, 313), 256, 0, stream>>>(w2a_bf, C1t, x2t, b2a, 40000, 512, nullptr,
                                            nullptr, 8, 128, 40000LL, 40000, nullptr);
  // 7) G3: 3x3 conv 128->128
  conv3x3_gemm<0><<<dim3(313), 256, 0, stream>>>(w2b_pk, x2t, x3t, b2b, zp, nullptr, nullptr,
                                                 nullptr);
  // 8) G4: 3x3 conv 128->128 + fused conf head (no x4 global round-trip)
  conv3x3_gemm<1><<<dim3(313), 256, 0, stream>>>(w2c_pk, x3t, nullptr, b2c, zp, w2d, b2d,
                                                 out);
}

// Round 16
// 245.325 us; speedup vs baseline: 1.0903x; 1.0556x over previous
//
#include <hip/hip_runtime.h>
#include <cstdint>
#include <cstddef>
#include <math.h>

typedef unsigned short u16;
typedef short bf16x8 __attribute__((ext_vector_type(8)));
typedef float f32x4 __attribute__((ext_vector_type(4)));

// ---------- helpers ----------
__device__ __forceinline__ u16 f2bf(float f) {
  union { float f; uint32_t u; } c; c.f = f;
  uint32_t u = c.u;
  return (u16)((u + 0x7FFFu + ((u >> 16) & 1u)) >> 16);
}
__device__ __forceinline__ float bf2f(u16 h) {
  union { uint32_t u; float f; } c; c.u = ((uint32_t)h) << 16;
  return c.f;
}
__device__ __forceinline__ float sigmoidf_(float x) { return 1.f / (1.f + expf(-x)); }

__device__ __forceinline__ void glds16(const void* g, void* l) {
  __builtin_amdgcn_global_load_lds((const __attribute__((address_space(1))) void*)g,
                                   (__attribute__((address_space(3))) void*)l, 16, 0, 0);
}

// column permutation: valid (s<=e) pairs compacted in natural order, invalid at end
__device__ __forceinline__ int col_rank(int p) {
  int s = p / 100, e = p - s * 100;
  int tri = (s * (s - 1)) >> 1;
  return (e >= s) ? (p - tri - s) : (5050 + tri + e);
}

// ---------- front-end 1D convs, ILP version: 4 t per thread via float4 ----------
__global__ void conv1d_k3v(const float* __restrict__ in, const float* __restrict__ w,
                           const float* __restrict__ bias, float* __restrict__ out,
                           int Cin_total, int Cin_g, int ocPerGroup, int OC) {
  int idx = blockIdx.x * 256 + threadIdx.x;
  int sub = idx % 25;
  int tmp = idx / 25;
  int oc = tmp % OC;
  int bb = tmp / OC;
  if (bb >= 4) return;
  int t4 = sub * 4;
  int g = oc / ocPerGroup;
  const float* ip = in + ((size_t)bb * Cin_total + (size_t)g * Cin_g) * 100 + t4;
  const float* wp = w + (size_t)oc * Cin_g * 3;
  float bs = bias[oc];
  float s0 = bs, s1 = bs, s2 = bs, s3 = bs;
  #pragma unroll 4
  for (int ic = 0; ic < Cin_g; ++ic) {
    const float* r = ip + (size_t)ic * 100;
    float4 a = *(const float4*)r;
    float xm = (t4 > 0) ? r[-1] : 0.f;
    float xp = (t4 < 96) ? r[4] : 0.f;
    float w0 = wp[ic * 3 + 0], w1 = wp[ic * 3 + 1], w2 = wp[ic * 3 + 2];
    s0 += w0 * xm + w1 * a.x + w2 * a.y;
    s1 += w0 * a.x + w1 * a.y + w2 * a.z;
    s2 += w0 * a.y + w1 * a.z + w2 * a.w;
    s3 += w0 * a.z + w1 * a.w + w2 * xp;
  }
  float4 o;
  o.x = fmaxf(s0, 0.f); o.y = fmaxf(s1, 0.f);
  o.z = fmaxf(s2, 0.f); o.w = fmaxf(s3, 0.f);
  *(float4*)(out + ((size_t)bb * OC + oc) * 100 + t4) = o;
}

// fused s1/e1/p branches; s/e full-reduction (well-occupied), p-part 4-way ic-split
__global__ void branch_split(const float* __restrict__ in, const float* __restrict__ wS,
                             const float* __restrict__ bS, const float* __restrict__ wE,
                             const float* __restrict__ bE, const float* __restrict__ wP,
                             const float* __restrict__ bP, float* __restrict__ outS,
                             float* __restrict__ outE, u16* __restrict__ Pt) {
  int idx = blockIdx.x * 256 + threadIdx.x;
  if (idx < 51200) {
    // s/e branches: 1 thread per 4 outputs, 64-iteration loop (round-15 path)
    int sub = idx % 25;
    int tmp = idx / 25;
    int ocx = tmp & 511;
    int bb = tmp >> 9;
    int t4 = sub * 4;
    int sel = ocx >> 8;
    int oc = ocx & 255;
    const float* w = sel ? wE : wS;
    const float* bias = sel ? bE : bS;
    int g = oc >> 6;
    const float* ip = in + ((size_t)bb * 256 + (size_t)g * 64) * 100 + t4;
    const float* wp = w + (size_t)oc * 192;
    float bs = bias[oc];
    float s0 = bs, s1 = bs, s2 = bs, s3 = bs;
    #pragma unroll 4
    for (int ic = 0; ic < 64; ++ic) {
      const float* r = ip + (size_t)ic * 100;
      float4 a = *(const float4*)r;
      float xm = (t4 > 0) ? r[-1] : 0.f;
      float xp = (t4 < 96) ? r[4] : 0.f;
      float w0 = wp[ic * 3 + 0], w1 = wp[ic * 3 + 1], w2 = wp[ic * 3 + 2];
      s0 += w0 * xm + w1 * a.x + w2 * a.y;
      s1 += w0 * a.x + w1 * a.y + w2 * a.z;
      s2 += w0 * a.y + w1 * a.z + w2 * a.w;
      s3 += w0 * a.z + w1 * a.w + w2 * xp;
    }
    float* out = sel ? outE : outS;
    float4 o;
    o.x = fmaxf(s0, 0.f); o.y = fmaxf(s1, 0.f);
    o.z = fmaxf(s2, 0.f); o.w = fmaxf(s3, 0.f);
    *(float4*)(out + ((size_t)bb * 256 + oc) * 100 + t4) = o;
  } else {
    // p branch: 4-way ic-split (quad of adjacent lanes), 64-iteration loop
    int j = idx - 51200;                 // < 51200
    int r = j & 3;
    int quad = j >> 2;                   // < 12800
    int sub = quad % 25;
    int tmp = quad / 25;
    int oc = tmp & 127;
    int bb = tmp >> 7;
    int t4 = sub * 4;
    const float* wp = wP + (size_t)oc * 768 + r * 192;
    const float* ip = in + ((size_t)bb * 256 + r * 64) * 100 + t4;
    float s0 = 0.f, s1 = 0.f, s2 = 0.f, s3 = 0.f;
    #pragma unroll 4
    for (int i = 0; i < 64; ++i) {
      const float* rr = ip + (size_t)i * 100;
      float4 a = *(const float4*)rr;
      float xm = (t4 > 0) ? rr[-1] : 0.f;
      float xp = (t4 < 96) ? rr[4] : 0.f;
      float w0 = wp[i * 3 + 0], w1 = wp[i * 3 + 1], w2 = wp[i * 3 + 2];
      s0 += w0 * xm + w1 * a.x + w2 * a.y;
      s1 += w0 * a.x + w1 * a.y + w2 * a.z;
      s2 += w0 * a.y + w1 * a.z + w2 * a.w;
      s3 += w0 * a.z + w1 * a.w + w2 * xp;
    }
    s0 += __shfl_xor(s0, 1); s0 += __shfl_xor(s0, 2);
    s1 += __shfl_xor(s1, 1); s1 += __shfl_xor(s1, 2);
    s2 += __shfl_xor(s2, 1); s2 += __shfl_xor(s2, 2);
    s3 += __shfl_xor(s3, 1); s3 += __shfl_xor(s3, 2);
    if (r == 0) {
      float b = bP[oc];
      Pt[((size_t)bb * 100 + t4 + 0) * 128 + oc] = f2bf(fmaxf(s0 + b, 0.f));
      Pt[((size_t)bb * 100 + t4 + 1) * 128 + oc] = f2bf(fmaxf(s1 + b, 0.f));
      Pt[((size_t)bb * 100 + t4 + 2) * 128 + oc] = f2bf(fmaxf(s2 + b, 0.f));
      Pt[((size_t)bb * 100 + t4 + 3) * 128 + oc] = f2bf(fmaxf(s3 + b, 0.f));
    }
  }
}

// ---------- fused prep: castw + cast_wq + invperm + tileinfo + zp + mask rows + conv1 ----------
__global__ void prep_fused(const float* __restrict__ w2a, const float* __restrict__ w2b,
                           const float* __restrict__ w2c, u16* __restrict__ w2a_bf,
                           u16* __restrict__ w2b_pk, u16* __restrict__ w2c_pk,
                           const float* __restrict__ w3d, u16* __restrict__ Wq,
                           int* __restrict__ invperm, int* __restrict__ tinfo,
                           int* __restrict__ order, u16* __restrict__ zp,
                           u16* __restrict__ Mt, const float* __restrict__ inputs,
                           const float* __restrict__ w_b1, const float* __restrict__ b_b1,
                           float* __restrict__ base1) {
  __shared__ __align__(16) u16 ML[4 * 3200];   // 25.6 KB: 4 mask rows
  __shared__ int C[128];
  int bid = blockIdx.x, tid = threadIdx.x;
  if (bid < 576) {
    int i = bid * 256 + tid;
    if (i < 65536) w2a_bf[i] = f2bf(w2a[i]);
    if (i < 147456) {
      int oc = i / 1152, r = i % 1152, kk = r >> 7, ic = r & 127;
      int src = (oc * 128 + ic) * 9 + kk;
      w2b_pk[i] = f2bf(w2b[src]);
      w2c_pk[i] = f2bf(w2c[src]);
    }
  } else if (bid < 640) {
    int u = (bid - 576) * 256 + tid;  // 16384 threads
    int o = u >> 5, n = u & 31;
    const float* src = w3d + (size_t)o * 4096 + n;
    u16* dst = Wq + (size_t)u * 128;
    for (int c0 = 0; c0 < 128; c0 += 8) {
      __align__(16) u16 h[8];
      #pragma unroll
      for (int j = 0; j < 8; ++j) h[j] = f2bf(src[(size_t)(c0 + j) * 32]);
      *(uint4*)(dst + c0) = *(const uint4*)h;
    }
  } else if (bid < 680) {
    int p = (bid - 640) * 256 + tid;
    if (p < 10000) invperm[col_rank(p)] = p;
  } else if (bid == 680) {
    if (tid < 128) zp[tid] = 0;
    int t = tid;
    int kbmin = 0, cnt = 0;
    if (t < 79) {
      int rlo = t * 128;
      int rhi = rlo + 128;
      if (rhi > 5050) rhi = 5050;
      if (rlo < 5050) {
        int s = 0;
        while (100 * (s + 1) - ((s + 1) * s) / 2 <= rlo) ++s;
        int cum = 100 * s - (s * (s - 1)) / 2;
        int tmin = 100, tmax = -1;
        for (int r = rlo; r < rhi; ++r) {
          while (r - cum >= 100 - s) { ++s; cum = 100 * s - (s * (s - 1)) / 2; }
          int e = s + (r - cum);
          float L = (float)(e - s + 2);
          float sp2 = (float)s - 0.5f * L;
          float ep2 = (float)(e + 1) + 0.5f * L;
          int a = (int)floorf(sp2) - 1;
          if (a < 0) a = 0;
          int b = (int)floorf(ep2) + 2;
          if (b > 99) b = 99;
          if (a < tmin) tmin = a;
          if (b > tmax) tmax = b;
        }
        kbmin = tmin >> 1;
        cnt = (tmax >> 1) - kbmin + 1;
      }
      tinfo[2 * t] = kbmin;
      tinfo[2 * t + 1] = cnt;
    }
    if (t < 128) C[t] = (t < 79) ? cnt : -1;
    __syncthreads();
    if (t < 79) {
      int pos = 0;
      int ct = C[t];
      for (int u = 0; u < 79; ++u) {
        int cu = C[u];
        pos += (cu > ct) || (cu == ct && u < t);
      }
      order[pos] = t;
    }
  } else if (bid < 1961) {
    // mask rows: 4 rows per block, built in LDS then written coalesced
    int r0 = (bid - 681) * 4;                  // 0..5116
    uint32_t* MZ = (uint32_t*)ML;
    for (int i = tid; i < 6400; i += 256) MZ[i] = 0;
    __syncthreads();
    int g = tid >> 6, lane = tid & 63;
    int r = r0 + g;
    if (r < 5050 && lane < 32) {
      int n = lane;
      int s = (int)((201.0 - sqrt((double)(40401 - 8 * r))) * 0.5);
      if (s < 0) s = 0;
      while (s * (201 - s) / 2 > r) --s;
      while ((s + 1) * (200 - s) / 2 <= r) ++s;
      int e = s + (r - s * (201 - s) / 2);
      double sp = (double)s, ep = (double)(e + 1);
      double L = ep - sp + 1.0;
      double sp2 = sp - L * 0.5;
      double ep2 = ep + L * 0.5;
      double step = (ep2 - sp2) / 95.0;
      double win[8];
      #pragma unroll
      for (int k = 0; k < 8; ++k) win[k] = 0.0;
      int base = -1;
      #pragma unroll
      for (int jj = 0; jj < 3; ++jj) {
        double pos = sp2 + step * (double)(n * 3 + jj);
        double ip;
        double fr = modf(pos, &ip);
        int it = (int)ip;
        if (it >= 0 && it < 99) {
          if (base < 0) base = it;
          int off = it - base;
          win[off] += (1.0 - fr) / 3.0;
          win[off + 1] += fr / 3.0;
        }
      }
      if (base >= 0) {
        u16* dst = ML + g * 3200 + n;
        #pragma unroll
        for (int k = 0; k < 8; ++k) {
          int t = base + k;
          if (t < 100) dst[t * 32] = f2bf((float)win[k]);
        }
      }
    }
    __syncthreads();
    for (int i = tid; i < 1600; i += 256) {    // 4 rows x 400 uint4
      int rl = i / 400, off = i - rl * 400;
      *(uint4*)(Mt + (size_t)(r0 + rl) * 3200 + off * 8) = ((const uint4*)ML)[i];
    }
  } else {
    // conv1: inputs -> base1 (grouped 4x100->256, k=3, relu), ILP float4 version
    int idx = (bid - 1961) * 256 + tid;        // < 25600
    int sub = idx % 25;
    int tmp = idx / 25;
    int oc = tmp % 256;
    int bb = tmp / 256;
    if (bb >= 4) return;
    int t4 = sub * 4;
    int g = oc >> 6;
    const float* ip = inputs + ((size_t)bb * 400 + (size_t)g * 100) * 100 + t4;
    const float* wp = w_b1 + (size_t)oc * 300;
    float bs = b_b1[oc];
    float s0 = bs, s1 = bs, s2 = bs, s3 = bs;
    #pragma unroll 4
    for (int ic = 0; ic < 100; ++ic) {
      const float* rr = ip + (size_t)ic * 100;
      float4 a = *(const float4*)rr;
      float xm = (t4 > 0) ? rr[-1] : 0.f;
      float xp = (t4 < 96) ? rr[4] : 0.f;
      float w0 = wp[ic * 3 + 0], w1 = wp[ic * 3 + 1], w2 = wp[ic * 3 + 2];
      s0 += w0 * xm + w1 * a.x + w2 * a.y;
      s1 += w0 * a.x + w1 * a.y + w2 * a.z;
      s2 += w0 * a.y + w1 * a.z + w2 * a.w;
      s3 += w0 * a.z + w1 * a.w + w2 * xp;
    }
    float4 o;
    o.x = fmaxf(s0, 0.f); o.y = fmaxf(s1, 0.f);
    o.z = fmaxf(s2, 0.f); o.w = fmaxf(s3, 0.f);
    *(float4*)(base1 + ((size_t)bb * 256 + oc) * 100 + t4) = o;
  }
}

// ---------- shared MFMA pieces (T2 XOR-swizzled reads; sources pre-swizzled) ----------
template<int MI>
__device__ __forceinline__ void mfma_stepT(const u16* As, const u16* Bs, int l, int wm, int wn,
                                           f32x4 (&acc)[MI][4]) {
  int m15 = l & 15, q = l >> 4, sw = m15 & 7;
  #pragma unroll
  for (int kk = 0; kk < 2; ++kk) {
    int koff = ((kk * 4 + q) ^ sw) * 8;
    bf16x8 av[MI], bv[4];
    #pragma unroll
    for (int i = 0; i < MI; ++i)
      av[i] = *(const bf16x8*)(As + (size_t)(wm * (MI * 16) + i * 16 + m15) * 64 + koff);
    #pragma unroll
    for (int j = 0; j < 4; ++j)
      bv[j] = *(const bf16x8*)(Bs + (size_t)(wn * 64 + j * 16 + m15) * 64 + koff);
    #pragma unroll
    for (int i = 0; i < MI; ++i) {
      #pragma unroll
      for (int j = 0; j < 4; ++j)
        acc[i][j] = __builtin_amdgcn_mfma_f32_16x16x32_bf16(av[i], bv[j], acc[i][j], 0, 0, 0);
    }
  }
}

// ---------- coalesced epilogue: stage relu'd bf16 tile in LDS (swizzled), write 128B runs ----
__device__ __forceinline__ void epilogue_coal(f32x4 (&acc)[4][4], u16* SH, u16* OUT,
                                              const float* bias, int row0, int col0, int tid,
                                              int l, int wm, int wn, int N, int OC,
                                              long long NPB, const int* colmap) {
  uint32_t* W = (uint32_t*)SH;
  int r4 = (l >> 4) * 4, c1 = l & 15;
  int bb0 = row0 % OC;
  #pragma unroll
  for (int i = 0; i < 4; ++i) {
    int ob = wm * 64 + i * 16 + r4;
    float b0 = bias[bb0 + ob + 0], b1 = bias[bb0 + ob + 1];
    float b2 = bias[bb0 + ob + 2], b3 = bias[bb0 + ob + 3];
    int jj = ob >> 1;
    #pragma unroll
    for (int j = 0; j < 4; ++j) {
      int col = wn * 64 + j * 16 + c1;
      f32x4 v = acc[i][j];
      uint32_t lo = (uint32_t)f2bf(fmaxf(v[0] + b0, 0.f)) |
                    ((uint32_t)f2bf(fmaxf(v[1] + b1, 0.f)) << 16);
      uint32_t hi = (uint32_t)f2bf(fmaxf(v[2] + b2, 0.f)) |
                    ((uint32_t)f2bf(fmaxf(v[3] + b3, 0.f)) << 16);
      W[col * 64 + (jj ^ (col & 31))] = lo;
      W[col * 64 + ((jj + 1) ^ (col & 31))] = hi;
    }
  }
  __syncthreads();
  int col = tid >> 1, half = tid & 1;
  int gcol = col0 + col;
  if (gcol < N) {
    int pcol = colmap ? colmap[gcol] : gcol;
    const uint32_t* Wc = W + col * 64;
    __align__(16) uint32_t tbuf[32];
    #pragma unroll
    for (int k = 0; k < 32; ++k) tbuf[k] = Wc[(half * 32 + k) ^ (col & 31)];
    u16* dst = OUT + (size_t)(row0 / OC) * (size_t)OC * (size_t)NPB + (size_t)pcol * OC +
               bb0 + half * 64;
    #pragma unroll
    for (int q = 0; q < 8; ++q) *(uint4*)(dst + q * 8) = *(const uint4*)(tbuf + q * 4);
  }
}

// ---------- generic BT-GEMM; single-buffer 2-barrier loop (m97 structure) ----------
__global__ __launch_bounds__(256, 2) void gemm_bt(const u16* __restrict__ A,
                                                  const u16* __restrict__ B,
                                                  u16* __restrict__ OUT,
                                                  const float* __restrict__ bias, int N, int K,
                                                  const int* __restrict__ tinfo,
                                                  const int* __restrict__ order, int kblocks,
                                                  int OC, long long NPB, int NclampB,
                                                  const int* __restrict__ colmap) {
  __shared__ __align__(16) u16 SH[2 * 128 * 64];
  u16* As = SH;
  u16* Bs = SH + 128 * 64;
  int mt = blockIdx.x;
  int nt = order ? order[blockIdx.y] : blockIdx.y;
  int col0 = nt * 128, row0 = mt * 128;
  int tid = threadIdx.x, w = tid >> 6, l = tid & 63;
  int wm = w >> 1, wn = w & 1;
  int lr = l >> 3;
  int lk_sw = ((l & 7) ^ lr) * 8;
  f32x4 acc[4][4] = {};
  size_t aoff[4];
  size_t boff[4];
  #pragma unroll
  for (int r = 0; r < 4; ++r) {
    int chunk = r * 4 + w;
    int rowA = row0 + chunk * 8 + lr;
    aoff[r] = (size_t)rowA * K + lk_sw;
    int colB = col0 + chunk * 8 + lr;
    if (colB >= NclampB) colB = NclampB - 1;
    boff[r] = (size_t)colB * K + lk_sw;
  }
  int kbmin = 0, cnt = kblocks;
  if (tinfo) { kbmin = tinfo[2 * nt]; cnt = tinfo[2 * nt + 1]; }
  for (int i = 0; i < cnt; ++i) {
    int k0 = (kbmin + i) * 64;
    #pragma unroll
    for (int r = 0; r < 4; ++r) {
      int chunk = r * 4 + w;
      glds16(A + aoff[r] + k0, As + chunk * 512);
      glds16(B + boff[r] + k0, Bs + chunk * 512);
    }
    __syncthreads();
    mfma_stepT<4>(As, Bs, l, wm, wn, acc);
    __syncthreads();
  }
  epilogue_coal(acc, SH, OUT, bias, row0, col0, tid, l, wm, wn, N, OC, NPB, colmap);
}

// ---------- qprep as MFMA GEMM + fused start/end sigmoid heads ----------
// NOTE: e1buf/s1buf must NOT alias Qb (GEMM blocks run concurrently with sigmoid blocks)
__global__ __launch_bounds__(256, 2) void qprep_sig(const u16* __restrict__ Wq,
                                                    const u16* __restrict__ Pt,
                                                    u16* __restrict__ Qb,
                                                    const float* __restrict__ s1,
                                                    const float* __restrict__ e1,
                                                    const float* __restrict__ ws2,
                                                    const float* __restrict__ bs2,
                                                    const float* __restrict__ we2,
                                                    const float* __restrict__ be2,
                                                    float* __restrict__ out) {
  if (blockIdx.x == 128) {
    int t = threadIdx.x & 127;
    int sel = threadIdx.x >> 7;
    int bb = blockIdx.y;
    if (t >= 100) return;
    const float* in = sel ? e1 : s1;
    const float* w = sel ? we2 : ws2;
    float s = sel ? be2[0] : bs2[0];
    #pragma unroll 8
    for (int c = 0; c < 256; ++c) s += w[c] * in[((size_t)bb * 256 + c) * 100 + t];
    out[80000 + sel * 400 + bb * 100 + t] = sigmoidf_(s);
    return;
  }
  __shared__ __align__(16) u16 As[128 * 64];
  __shared__ __align__(16) u16 Bs[128 * 64];
  int mt = blockIdx.x, nt = blockIdx.y;
  int col0 = nt * 128, row0 = mt * 128;
  int tid = threadIdx.x, w = tid >> 6, l = tid & 63;
  int wm = w >> 1, wn = w & 1;
  int lr = l >> 3;
  int lk_sw = ((l & 7) ^ lr) * 8;
  f32x4 acc[4][4] = {};
  size_t aoff[4];
  size_t boff[4];
  #pragma unroll
  for (int r = 0; r < 4; ++r) {
    int chunk = r * 4 + w;
    int rowA = row0 + chunk * 8 + lr;
    aoff[r] = (size_t)rowA * 128 + lk_sw;
    int colB = col0 + chunk * 8 + lr;
    if (colB >= 400) colB = 399;
    boff[r] = (size_t)colB * 128 + lk_sw;
  }
  #pragma unroll
  for (int kb = 0; kb < 2; ++kb) {
    int k0 = kb * 64;
    #pragma unroll
    for (int r = 0; r < 4; ++r) {
      int chunk = r * 4 + w;
      glds16(Wq + aoff[r] + k0, As + chunk * 512);
      glds16(Pt + boff[r] + k0, Bs + chunk * 512);
    }
    __syncthreads();
    mfma_stepT<4>(As, Bs, l, wm, wn, acc);
    __syncthreads();
  }
  int r4 = (l >> 4) * 4, c1 = l & 15;
  #pragma unroll
  for (int i = 0; i < 4; ++i) {
    int row = row0 + wm * 64 + i * 16 + r4;
    int o = row >> 5, n = row & 31;
    #pragma unroll
    for (int j = 0; j < 4; ++j) {
      int col = col0 + wn * 64 + j * 16 + c1;
      if (col < 400) {
        int b = col / 100, t = col - b * 100;
        f32x4 v = acc[i][j];
        __align__(8) u16 h[4];
        h[0] = f2bf(v[0]);
        h[1] = f2bf(v[1]);
        h[2] = f2bf(v[2]);
        h[3] = f2bf(v[3]);
        *(uint2*)(Qb + ((size_t)(b * 512 + o)) * 3200 + t * 32 + n) = *(const uint2*)h;
      }
    }
  }
}

// ---------- 3x3 conv as shifted BT-GEMM; FUSE=1 computes conf head in-epilogue ----------
template<int FUSE>
__global__ __launch_bounds__(256, 2) void conv3x3_gemm(const u16* __restrict__ Apk,
                                                       const u16* __restrict__ X,
                                                       u16* __restrict__ OUT,
                                                       const float* __restrict__ bias,
                                                       const u16* __restrict__ zp,
                                                       const float* __restrict__ w2d,
                                                       const float* __restrict__ b2d,
                                                       float* __restrict__ out) {
  __shared__ __align__(16) u16 SH[2 * 128 * 64];   // As | Bs ; reused by epilogues (32KB)
  u16* As = SH;
  u16* Bs = SH + 128 * 64;
  int nt = blockIdx.x;
  int col0 = nt * 128;
  int tid = threadIdx.x, w = tid >> 6, l = tid & 63;
  int wm = w >> 1, wn = w & 1;
  int lr = l >> 3;
  int lk_sw = ((l & 7) ^ lr) * 8;
  int cj[4], yy[4], xx[4];
  bool vv[4];
  size_t aoff[4];
  #pragma unroll
  for (int r = 0; r < 4; ++r) {
    int chunk = r * 4 + w;
    int c = col0 + chunk * 8 + lr;
    cj[r] = c;
    vv[r] = (c < 40000);
    int p = c % 10000;
    yy[r] = p / 100;
    xx[r] = p % 100;
    aoff[r] = (size_t)(chunk * 8 + lr) * 1152 + lk_sw;
  }
  f32x4 acc[4][4] = {};
  for (int s = 0; s < 9; ++s) {
    int dy = s / 3 - 1, dx = s % 3 - 1;
    int doff = dy * 100 + dx;
    #pragma unroll
    for (int half = 0; half < 2; ++half) {
      int k0 = s * 128 + half * 64;
      int c0 = half * 64;
      #pragma unroll
      for (int r = 0; r < 4; ++r) {
        int chunk = r * 4 + w;
        glds16(Apk + aoff[r] + k0, As + chunk * 512);
        int y2 = yy[r] + dy, x2 = xx[r] + dx;
        bool ok = vv[r] && ((unsigned)y2 < 100u) && ((unsigned)x2 < 100u);
        const u16* src = ok ? (X + (size_t)(cj[r] + doff) * 128 + c0 + lk_sw) : zp;
        glds16(src, Bs + chunk * 512);
      }
      __syncthreads();
      mfma_stepT<4>(As, Bs, l, wm, wn, acc);
      __syncthreads();
    }
  }
  if (FUSE == 0) {
    epilogue_coal(acc, SH, OUT, bias, 0, col0, tid, l, wm, wn, 40000, 128, 40000LL, nullptr);
  } else {
    // stage relu'd bf16 tile (128 ch x 128 cols) into LDS, swizzled u32 layout
    uint32_t* W = (uint32_t*)SH;
    int r4 = (l >> 4) * 4, c1 = l & 15;
    #pragma unroll
    for (int i = 0; i < 4; ++i) {
      int ob = wm * 64 + i * 16 + r4;
      float b0 = bias[ob + 0], b1 = bias[ob + 1], b2 = bias[ob + 2], b3 = bias[ob + 3];
      #pragma unroll
      for (int j = 0; j < 4; ++j) {
        int col = wn * 64 + j * 16 + c1;
        f32x4 v = acc[i][j];
        uint32_t lo = (uint32_t)f2bf(fmaxf(v[0] + b0, 0.f)) |
                      ((uint32_t)f2bf(fmaxf(v[1] + b1, 0.f)) << 16);
        uint32_t hi = (uint32_t)f2bf(fmaxf(v[2] + b2, 0.f)) |
                      ((uint32_t)f2bf(fmaxf(v[3] + b3, 0.f)) << 16);
        int jj = ob >> 1;
        W[col * 64 + (jj ^ (col & 31))] = lo;
        W[col * 64 + ((jj + 1) ^ (col & 31))] = hi;
      }
    }
    __syncthreads();
    int col = tid & 127, sel = tid >> 7;
    int gcol = col0 + col;
    if (gcol < 40000) {
      float sum = b2d[sel];
      const uint32_t* Wc = W + col * 64;
      const float* wd = w2d + sel * 128;
      #pragma unroll 8
      for (int c = 0; c < 64; ++c) {
        uint32_t v = Wc[c ^ (col & 31)];
        sum += wd[2 * c] * bf2f((u16)(v & 0xffffu)) + wd[2 * c + 1] * bf2f((u16)(v >> 16));
      }
      int b = gcol / 10000, pidx = gcol - b * 10000;
      out[((size_t)b * 2 + sel) * 10000 + pidx] = sigmoidf_(sum);
    }
  }
}

// ---------- launch ----------
extern "C" void kernel_launch(void* const* d_in, const int* in_sizes, int n_in, void* d_out,
                              int out_size, void* d_ws, size_t ws_size, hipStream_t stream) {
  const float* inputs = (const float*)d_in[0];
  const float* w_b1 = (const float*)d_in[1];
  const float* b_b1 = (const float*)d_in[2];
  const float* w_b2 = (const float*)d_in[3];
  const float* b_b2 = (const float*)d_in[4];
  const float* w_s1 = (const float*)d_in[5];
  const float* b_s1 = (const float*)d_in[6];
  const float* w_s2 = (const float*)d_in[7];
  const float* b_s2 = (const float*)d_in[8];
  const float* w_e1 = (const float*)d_in[9];
  const float* b_e1 = (const float*)d_in[10];
  const float* w_e2 = (const float*)d_in[11];
  const float* b_e2 = (const float*)d_in[12];
  const float* w_p1 = (const float*)d_in[13];
  const float* b_p1 = (const float*)d_in[14];
  const float* w3d = (const float*)d_in[15];
  const float* b3d = (const float*)d_in[16];
  const float* w2a = (const float*)d_in[17];
  const float* b2a = (const float*)d_in[18];
  const float* w2b = (const float*)d_in[19];
  const float* b2b = (const float*)d_in[20];
  const float* w2c = (const float*)d_in[21];
  const float* b2c = (const float*)d_in[22];
  const float* w2d = (const float*)d_in[23];
  const float* b2d = (const float*)d_in[24];
  float* out = (float*)d_out;
  char* ws = (char*)d_ws;

  int* tinfo = (int*)(ws + 0);
  int* order = (int*)(ws + 2048);
  u16* zp = (u16*)(ws + 16384);
  int* invperm = (int*)(ws + 45056);
  float* base1 = (float*)(ws + 90112);          // 409600
  float* base = (float*)(ws + 499712);          // 409600
  float* s1buf = (float*)(ws + 909312);         // 409600
  u16* Pt = (u16*)(ws + 1318912);               // 102400
  u16* w2a_bf = (u16*)(ws + 1421312);           // 131072
  u16* w2b_pk = (u16*)(ws + 1552384);           // 294912
  u16* w2c_pk = (u16*)(ws + 1847296);           // 294912
  u16* Qb = (u16*)(ws + 2142208);               // 13107200 (ends 15249408)
  u16* Mt = (u16*)(ws + 15249408);              // rows 0..5119 used -> ends 48017408
  float* e1buf = (float*)(ws + 48017408);       // 409600, in Mt-region free tail (no alias!)
  u16* C1t = (u16*)(ws + 79249408);             // 40960000  (end 120209408)
  u16* Wq = (u16*)(ws + 79249408);              // aliases C1t: dead before G1 writes C1t
  u16* x2t = Qb;   // alias: Qb dead after G1
  u16* x3t = C1t;  // alias: C1t dead after G2

  // 1) fused prep: weight casts, invperm, tile spans + order, zero page, mask rows, conv1
  prep_fused<<<2061, 256, 0, stream>>>(w2a, w2b, w2c, w2a_bf, w2b_pk, w2c_pk, w3d, Wq,
                                       invperm, tinfo, order, zp, Mt, inputs, w_b1, b_b1,
                                       base1);

  // 2-3) front end (fp32 exact; p-branch ic-split 4-way for occupancy)
  conv1d_k3v<<<100, 256, 0, stream>>>(base1, w_b2, b_b2, base, 256, 64, 64, 256);
  branch_split<<<400, 256, 0, stream>>>(base, w_s1, b_s1, w_e1, b_e1, w_p1, b_p1,
                                        s1buf, e1buf, Pt);

  // 4) qprep GEMM [16384 x 400 x 128] + fused start/end sigmoid heads
  qprep_sig<<<dim3(129, 4), 256, 0, stream>>>(Wq, Pt, Qb, s1buf, e1buf, w_s2, b_s2,
                                              w_e2, b_e2, out);

  // 5) G1: out3d, 128x128 tiles, longest-first; de-permuted coalesced store into C1t
  gemm_bt<<<dim3(16, 79), 256, 0, stream>>>(Qb, Mt, C1t, b3d, 10000, 3200, tinfo, order, 50,
                                            512, 10000LL, 10000, invperm);
  // 6) G2: 1x1 conv 512->128
  gemm_bt<<<dim3(1, 313), 256, 0, stream>>>(w2a_bf, C1t, x2t, b2a, 40000, 512, nullptr,
                                            nullptr, 8, 128, 40000LL, 40000, nullptr);
  // 7) G3: 3x3 conv 128->128
  conv3x3_gemm<0><<<dim3(313), 256, 0, stream>>>(w2b_pk, x2t, x3t, b2b, zp, nullptr, nullptr,
                                                 nullptr);
  // 8) G4: 3x3 conv 128->128 + fused conf head (no x4 global round-trip)
  conv3x3_gemm<1><<<dim3(313), 256, 0, stream>>>(w2c_pk, x3t, nullptr, b2c, zp, w2d, b2d,
                                                 out);
}

// Round 17
// 232.607 us; speedup vs baseline: 1.1499x; 1.0547x over previous
//
#include <hip/hip_runtime.h>
#include <cstdint>
#include <cstddef>
#include <math.h>

typedef unsigned short u16;
typedef short bf16x8 __attribute__((ext_vector_type(8)));
typedef float f32x4 __attribute__((ext_vector_type(4)));

// ---------- helpers ----------
__device__ __forceinline__ u16 f2bf(float f) {
  union { float f; uint32_t u; } c; c.f = f;
  uint32_t u = c.u;
  return (u16)((u + 0x7FFFu + ((u >> 16) & 1u)) >> 16);
}
__device__ __forceinline__ float bf2f(u16 h) {
  union { uint32_t u; float f; } c; c.u = ((uint32_t)h) << 16;
  return c.f;
}
__device__ __forceinline__ float sigmoidf_(float x) { return 1.f / (1.f + expf(-x)); }

__device__ __forceinline__ void glds16(const void* g, void* l) {
  __builtin_amdgcn_global_load_lds((const __attribute__((address_space(1))) void*)g,
                                   (__attribute__((address_space(3))) void*)l, 16, 0, 0);
}

// column permutation: valid (s<=e) pairs compacted in natural order, invalid at end
__device__ __forceinline__ int col_rank(int p) {
  int s = p / 100, e = p - s * 100;
  int tri = (s * (s - 1)) >> 1;
  return (e >= s) ? (p - tri - s) : (5050 + tri + e);
}

// ---------- front-end 1D convs, ILP version: 4 t per thread via float4 ----------
__global__ void conv1d_k3v(const float* __restrict__ in, const float* __restrict__ w,
                           const float* __restrict__ bias, float* __restrict__ out,
                           int Cin_total, int Cin_g, int ocPerGroup, int OC) {
  int idx = blockIdx.x * 256 + threadIdx.x;
  int sub = idx % 25;
  int tmp = idx / 25;
  int oc = tmp % OC;
  int bb = tmp / OC;
  if (bb >= 4) return;
  int t4 = sub * 4;
  int g = oc / ocPerGroup;
  const float* ip = in + ((size_t)bb * Cin_total + (size_t)g * Cin_g) * 100 + t4;
  const float* wp = w + (size_t)oc * Cin_g * 3;
  float bs = bias[oc];
  float s0 = bs, s1 = bs, s2 = bs, s3 = bs;
  #pragma unroll 4
  for (int ic = 0; ic < Cin_g; ++ic) {
    const float* r = ip + (size_t)ic * 100;
    float4 a = *(const float4*)r;
    float xm = (t4 > 0) ? r[-1] : 0.f;
    float xp = (t4 < 96) ? r[4] : 0.f;
    float w0 = wp[ic * 3 + 0], w1 = wp[ic * 3 + 1], w2 = wp[ic * 3 + 2];
    s0 += w0 * xm + w1 * a.x + w2 * a.y;
    s1 += w0 * a.x + w1 * a.y + w2 * a.z;
    s2 += w0 * a.y + w1 * a.z + w2 * a.w;
    s3 += w0 * a.z + w1 * a.w + w2 * xp;
  }
  float4 o;
  o.x = fmaxf(s0, 0.f); o.y = fmaxf(s1, 0.f);
  o.z = fmaxf(s2, 0.f); o.w = fmaxf(s3, 0.f);
  *(float4*)(out + ((size_t)bb * OC + oc) * 100 + t4) = o;
}

// fused s1/e1/p branches; s/e full-reduction (well-occupied), p-part 4-way ic-split
__global__ void branch_split(const float* __restrict__ in, const float* __restrict__ wS,
                             const float* __restrict__ bS, const float* __restrict__ wE,
                             const float* __restrict__ bE, const float* __restrict__ wP,
                             const float* __restrict__ bP, float* __restrict__ outS,
                             float* __restrict__ outE, u16* __restrict__ Pt) {
  int idx = blockIdx.x * 256 + threadIdx.x;
  if (idx < 51200) {
    int sub = idx % 25;
    int tmp = idx / 25;
    int ocx = tmp & 511;
    int bb = tmp >> 9;
    int t4 = sub * 4;
    int sel = ocx >> 8;
    int oc = ocx & 255;
    const float* w = sel ? wE : wS;
    const float* bias = sel ? bE : bS;
    int g = oc >> 6;
    const float* ip = in + ((size_t)bb * 256 + (size_t)g * 64) * 100 + t4;
    const float* wp = w + (size_t)oc * 192;
    float bs = bias[oc];
    float s0 = bs, s1 = bs, s2 = bs, s3 = bs;
    #pragma unroll 4
    for (int ic = 0; ic < 64; ++ic) {
      const float* r = ip + (size_t)ic * 100;
      float4 a = *(const float4*)r;
      float xm = (t4 > 0) ? r[-1] : 0.f;
      float xp = (t4 < 96) ? r[4] : 0.f;
      float w0 = wp[ic * 3 + 0], w1 = wp[ic * 3 + 1], w2 = wp[ic * 3 + 2];
      s0 += w0 * xm + w1 * a.x + w2 * a.y;
      s1 += w0 * a.x + w1 * a.y + w2 * a.z;
      s2 += w0 * a.y + w1 * a.z + w2 * a.w;
      s3 += w0 * a.z + w1 * a.w + w2 * xp;
    }
    float* out = sel ? outE : outS;
    float4 o;
    o.x = fmaxf(s0, 0.f); o.y = fmaxf(s1, 0.f);
    o.z = fmaxf(s2, 0.f); o.w = fmaxf(s3, 0.f);
    *(float4*)(out + ((size_t)bb * 256 + oc) * 100 + t4) = o;
  } else {
    int j = idx - 51200;
    int r = j & 3;
    int quad = j >> 2;
    int sub = quad % 25;
    int tmp = quad / 25;
    int oc = tmp & 127;
    int bb = tmp >> 7;
    int t4 = sub * 4;
    const float* wp = wP + (size_t)oc * 768 + r * 192;
    const float* ip = in + ((size_t)bb * 256 + r * 64) * 100 + t4;
    float s0 = 0.f, s1 = 0.f, s2 = 0.f, s3 = 0.f;
    #pragma unroll 4
    for (int i = 0; i < 64; ++i) {
      const float* rr = ip + (size_t)i * 100;
      float4 a = *(const float4*)rr;
      float xm = (t4 > 0) ? rr[-1] : 0.f;
      float xp = (t4 < 96) ? rr[4] : 0.f;
      float w0 = wp[i * 3 + 0], w1 = wp[i * 3 + 1], w2 = wp[i * 3 + 2];
      s0 += w0 * xm + w1 * a.x + w2 * a.y;
      s1 += w0 * a.x + w1 * a.y + w2 * a.z;
      s2 += w0 * a.y + w1 * a.z + w2 * a.w;
      s3 += w0 * a.z + w1 * a.w + w2 * xp;
    }
    s0 += __shfl_xor(s0, 1); s0 += __shfl_xor(s0, 2);
    s1 += __shfl_xor(s1, 1); s1 += __shfl_xor(s1, 2);
    s2 += __shfl_xor(s2, 1); s2 += __shfl_xor(s2, 2);
    s3 += __shfl_xor(s3, 1); s3 += __shfl_xor(s3, 2);
    if (r == 0) {
      float b = bP[oc];
      Pt[((size_t)bb * 100 + t4 + 0) * 128 + oc] = f2bf(fmaxf(s0 + b, 0.f));
      Pt[((size_t)bb * 100 + t4 + 1) * 128 + oc] = f2bf(fmaxf(s1 + b, 0.f));
      Pt[((size_t)bb * 100 + t4 + 2) * 128 + oc] = f2bf(fmaxf(s2 + b, 0.f));
      Pt[((size_t)bb * 100 + t4 + 3) * 128 + oc] = f2bf(fmaxf(s3 + b, 0.f));
    }
  }
}

// ---------- fused prep; conv1 FIRST (bids 0-399, 4-way ic-split), mask rows 2/block ----------
__global__ void prep_fused(const float* __restrict__ w2a, const float* __restrict__ w2b,
                           const float* __restrict__ w2c, u16* __restrict__ w2a_bf,
                           u16* __restrict__ w2b_pk, u16* __restrict__ w2c_pk,
                           const float* __restrict__ w3d, u16* __restrict__ Wq,
                           int* __restrict__ invperm, int* __restrict__ tinfo,
                           int* __restrict__ order, u16* __restrict__ zp,
                           u16* __restrict__ Mt, const float* __restrict__ inputs,
                           const float* __restrict__ w_b1, const float* __restrict__ b_b1,
                           float* __restrict__ base1) {
  __shared__ __align__(16) u16 ML[2 * 3200];   // 12.8 KB: 2 mask rows
  __shared__ int C[128];
  int bid = blockIdx.x, tid = threadIdx.x;
  if (bid < 400) {
    // conv1: inputs -> base1 (grouped 4x100->256, k=3, relu), 4-way ic-split
    int u = bid * 256 + tid;           // < 102400
    int r = u & 3;
    int quad = u >> 2;
    int sub = quad % 25;
    int tmp = quad / 25;
    int oc = tmp & 255;
    int bb = tmp >> 8;
    int t4 = sub * 4;
    int g = oc >> 6;
    const float* ip = inputs + ((size_t)bb * 400 + g * 100 + r * 25) * 100 + t4;
    const float* wp = w_b1 + (size_t)oc * 300 + r * 75;
    float s0 = 0.f, s1 = 0.f, s2 = 0.f, s3 = 0.f;
    #pragma unroll 5
    for (int i = 0; i < 25; ++i) {
      const float* rr = ip + (size_t)i * 100;
      float4 a = *(const float4*)rr;
      float xm = (t4 > 0) ? rr[-1] : 0.f;
      float xp = (t4 < 96) ? rr[4] : 0.f;
      float w0 = wp[i * 3 + 0], w1 = wp[i * 3 + 1], w2 = wp[i * 3 + 2];
      s0 += w0 * xm + w1 * a.x + w2 * a.y;
      s1 += w0 * a.x + w1 * a.y + w2 * a.z;
      s2 += w0 * a.y + w1 * a.z + w2 * a.w;
      s3 += w0 * a.z + w1 * a.w + w2 * xp;
    }
    s0 += __shfl_xor(s0, 1); s0 += __shfl_xor(s0, 2);
    s1 += __shfl_xor(s1, 1); s1 += __shfl_xor(s1, 2);
    s2 += __shfl_xor(s2, 1); s2 += __shfl_xor(s2, 2);
    s3 += __shfl_xor(s3, 1); s3 += __shfl_xor(s3, 2);
    if (r == 0) {
      float b = b_b1[oc];
      float4 o;
      o.x = fmaxf(s0 + b, 0.f); o.y = fmaxf(s1 + b, 0.f);
      o.z = fmaxf(s2 + b, 0.f); o.w = fmaxf(s3 + b, 0.f);
      *(float4*)(base1 + ((size_t)bb * 256 + oc) * 100 + t4) = o;
    }
  } else if (bid < 976) {
    int i = (bid - 400) * 256 + tid;
    if (i < 65536) w2a_bf[i] = f2bf(w2a[i]);
    if (i < 147456) {
      int oc = i / 1152, r = i % 1152, kk = r >> 7, ic = r & 127;
      int src = (oc * 128 + ic) * 9 + kk;
      w2b_pk[i] = f2bf(w2b[src]);
      w2c_pk[i] = f2bf(w2c[src]);
    }
  } else if (bid < 1040) {
    int u = (bid - 976) * 256 + tid;  // 16384 threads
    int o = u >> 5, n = u & 31;
    const float* src = w3d + (size_t)o * 4096 + n;
    u16* dst = Wq + (size_t)u * 128;
    for (int c0 = 0; c0 < 128; c0 += 8) {
      __align__(16) u16 h[8];
      #pragma unroll
      for (int j = 0; j < 8; ++j) h[j] = f2bf(src[(size_t)(c0 + j) * 32]);
      *(uint4*)(dst + c0) = *(const uint4*)h;
    }
  } else if (bid < 1080) {
    int p = (bid - 1040) * 256 + tid;
    if (p < 10000) invperm[col_rank(p)] = p;
  } else if (bid == 1080) {
    if (tid < 128) zp[tid] = 0;
    int t = tid;
    int kbmin = 0, cnt = 0;
    if (t < 79) {
      int rlo = t * 128;
      int rhi = rlo + 128;
      if (rhi > 5050) rhi = 5050;
      if (rlo < 5050) {
        int s = 0;
        while (100 * (s + 1) - ((s + 1) * s) / 2 <= rlo) ++s;
        int cum = 100 * s - (s * (s - 1)) / 2;
        int tmin = 100, tmax = -1;
        for (int r = rlo; r < rhi; ++r) {
          while (r - cum >= 100 - s) { ++s; cum = 100 * s - (s * (s - 1)) / 2; }
          int e = s + (r - cum);
          float L = (float)(e - s + 2);
          float sp2 = (float)s - 0.5f * L;
          float ep2 = (float)(e + 1) + 0.5f * L;
          int a = (int)floorf(sp2) - 1;
          if (a < 0) a = 0;
          int b = (int)floorf(ep2) + 2;
          if (b > 99) b = 99;
          if (a < tmin) tmin = a;
          if (b > tmax) tmax = b;
        }
        kbmin = tmin >> 1;
        cnt = (tmax >> 1) - kbmin + 1;
      }
      tinfo[2 * t] = kbmin;
      tinfo[2 * t + 1] = cnt;
    }
    if (t < 128) C[t] = (t < 79) ? cnt : -1;
    __syncthreads();
    if (t < 79) {
      int pos = 0;
      int ct = C[t];
      for (int u = 0; u < 79; ++u) {
        int cu = C[u];
        pos += (cu > ct) || (cu == ct && u < t);
      }
      order[pos] = t;
    }
  } else {
    // mask rows: 2 rows per block (12.8KB LDS), built in LDS then written coalesced
    int r0 = (bid - 1081) * 2;                 // 0..5118
    uint32_t* MZ = (uint32_t*)ML;
    for (int i = tid; i < 3200; i += 256) MZ[i] = 0;
    __syncthreads();
    int g = tid >> 6, lane = tid & 63;
    int r = r0 + g;
    if (g < 2 && r < 5050 && lane < 32) {
      int n = lane;
      int s = (int)((201.0 - sqrt((double)(40401 - 8 * r))) * 0.5);
      if (s < 0) s = 0;
      while (s * (201 - s) / 2 > r) --s;
      while ((s + 1) * (200 - s) / 2 <= r) ++s;
      int e = s + (r - s * (201 - s) / 2);
      double sp = (double)s, ep = (double)(e + 1);
      double L = ep - sp + 1.0;
      double sp2 = sp - L * 0.5;
      double ep2 = ep + L * 0.5;
      double step = (ep2 - sp2) / 95.0;
      double win[8];
      #pragma unroll
      for (int k = 0; k < 8; ++k) win[k] = 0.0;
      int base = -1;
      #pragma unroll
      for (int jj = 0; jj < 3; ++jj) {
        double pos = sp2 + step * (double)(n * 3 + jj);
        double ip;
        double fr = modf(pos, &ip);
        int it = (int)ip;
        if (it >= 0 && it < 99) {
          if (base < 0) base = it;
          int off = it - base;
          win[off] += (1.0 - fr) / 3.0;
          win[off + 1] += fr / 3.0;
        }
      }
      if (base >= 0) {
        u16* dst = ML + g * 3200 + n;
        #pragma unroll
        for (int k = 0; k < 8; ++k) {
          int t = base + k;
          if (t < 100) dst[t * 32] = f2bf((float)win[k]);
        }
      }
    }
    __syncthreads();
    for (int i = tid; i < 800; i += 256) {     // 2 rows x 400 uint4
      int rl = i / 400, off = i - rl * 400;
      *(uint4*)(Mt + (size_t)(r0 + rl) * 3200 + off * 8) = ((const uint4*)ML)[i];
    }
  }
}

// ---------- shared MFMA pieces (T2 XOR-swizzled reads; sources pre-swizzled) ----------
template<int MI>
__device__ __forceinline__ void mfma_stepT(const u16* As, const u16* Bs, int l, int wm, int wn,
                                           f32x4 (&acc)[MI][4]) {
  int m15 = l & 15, q = l >> 4, sw = m15 & 7;
  #pragma unroll
  for (int kk = 0; kk < 2; ++kk) {
    int koff = ((kk * 4 + q) ^ sw) * 8;
    bf16x8 av[MI], bv[4];
    #pragma unroll
    for (int i = 0; i < MI; ++i)
      av[i] = *(const bf16x8*)(As + (size_t)(wm * (MI * 16) + i * 16 + m15) * 64 + koff);
    #pragma unroll
    for (int j = 0; j < 4; ++j)
      bv[j] = *(const bf16x8*)(Bs + (size_t)(wn * 64 + j * 16 + m15) * 64 + koff);
    #pragma unroll
    for (int i = 0; i < MI; ++i) {
      #pragma unroll
      for (int j = 0; j < 4; ++j)
        acc[i][j] = __builtin_amdgcn_mfma_f32_16x16x32_bf16(av[i], bv[j], acc[i][j], 0, 0, 0);
    }
  }
}

// ---------- coalesced epilogue: stage relu'd bf16 tile in LDS (swizzled), write 128B runs ----
__device__ __forceinline__ void epilogue_coal(f32x4 (&acc)[4][4], u16* SH, u16* OUT,
                                              const float* bias, int row0, int col0, int tid,
                                              int l, int wm, int wn, int N, int OC,
                                              long long NPB, const int* colmap) {
  uint32_t* W = (uint32_t*)SH;
  int r4 = (l >> 4) * 4, c1 = l & 15;
  int bb0 = row0 % OC;
  #pragma unroll
  for (int i = 0; i < 4; ++i) {
    int ob = wm * 64 + i * 16 + r4;
    float b0 = bias[bb0 + ob + 0], b1 = bias[bb0 + ob + 1];
    float b2 = bias[bb0 + ob + 2], b3 = bias[bb0 + ob + 3];
    int jj = ob >> 1;
    #pragma unroll
    for (int j = 0; j < 4; ++j) {
      int col = wn * 64 + j * 16 + c1;
      f32x4 v = acc[i][j];
      uint32_t lo = (uint32_t)f2bf(fmaxf(v[0] + b0, 0.f)) |
                    ((uint32_t)f2bf(fmaxf(v[1] + b1, 0.f)) << 16);
      uint32_t hi = (uint32_t)f2bf(fmaxf(v[2] + b2, 0.f)) |
                    ((uint32_t)f2bf(fmaxf(v[3] + b3, 0.f)) << 16);
      W[col * 64 + (jj ^ (col & 31))] = lo;
      W[col * 64 + ((jj + 1) ^ (col & 31))] = hi;
    }
  }
  __syncthreads();
  int col = tid >> 1, half = tid & 1;
  int gcol = col0 + col;
  if (gcol < N) {
    int pcol = colmap ? colmap[gcol] : gcol;
    const uint32_t* Wc = W + col * 64;
    __align__(16) uint32_t tbuf[32];
    #pragma unroll
    for (int k = 0; k < 32; ++k) tbuf[k] = Wc[(half * 32 + k) ^ (col & 31)];
    u16* dst = OUT + (size_t)(row0 / OC) * (size_t)OC * (size_t)NPB + (size_t)pcol * OC +
               bb0 + half * 64;
    #pragma unroll
    for (int q = 0; q < 8; ++q) *(uint4*)(dst + q * 8) = *(const uint4*)(tbuf + q * 4);
  }
}

// ---------- generic BT-GEMM; single-buffer 2-barrier loop (m97 structure) ----------
__global__ __launch_bounds__(256, 2) void gemm_bt(const u16* __restrict__ A,
                                                  const u16* __restrict__ B,
                                                  u16* __restrict__ OUT,
                                                  const float* __restrict__ bias, int N, int K,
                                                  const int* __restrict__ tinfo,
                                                  const int* __restrict__ order, int kblocks,
                                                  int OC, long long NPB, int NclampB,
                                                  const int* __restrict__ colmap) {
  __shared__ __align__(16) u16 SH[2 * 128 * 64];
  u16* As = SH;
  u16* Bs = SH + 128 * 64;
  int mt = blockIdx.x;
  int nt = order ? order[blockIdx.y] : blockIdx.y;
  int col0 = nt * 128, row0 = mt * 128;
  int tid = threadIdx.x, w = tid >> 6, l = tid & 63;
  int wm = w >> 1, wn = w & 1;
  int lr = l >> 3;
  int lk_sw = ((l & 7) ^ lr) * 8;
  f32x4 acc[4][4] = {};
  size_t aoff[4];
  size_t boff[4];
  #pragma unroll
  for (int r = 0; r < 4; ++r) {
    int chunk = r * 4 + w;
    int rowA = row0 + chunk * 8 + lr;
    aoff[r] = (size_t)rowA * K + lk_sw;
    int colB = col0 + chunk * 8 + lr;
    if (colB >= NclampB) colB = NclampB - 1;
    boff[r] = (size_t)colB * K + lk_sw;
  }
  int kbmin = 0, cnt = kblocks;
  if (tinfo) { kbmin = tinfo[2 * nt]; cnt = tinfo[2 * nt + 1]; }
  for (int i = 0; i < cnt; ++i) {
    int k0 = (kbmin + i) * 64;
    #pragma unroll
    for (int r = 0; r < 4; ++r) {
      int chunk = r * 4 + w;
      glds16(A + aoff[r] + k0, As + chunk * 512);
      glds16(B + boff[r] + k0, Bs + chunk * 512);
    }
    __syncthreads();
    mfma_stepT<4>(As, Bs, l, wm, wn, acc);
    __syncthreads();
  }
  epilogue_coal(acc, SH, OUT, bias, row0, col0, tid, l, wm, wn, N, OC, NPB, colmap);
}

// ---------- qprep as MFMA GEMM + fused start/end sigmoid heads ----------
// NOTE: e1buf/s1buf must NOT alias Qb (GEMM blocks run concurrently with sigmoid blocks)
__global__ __launch_bounds__(256, 2) void qprep_sig(const u16* __restrict__ Wq,
                                                    const u16* __restrict__ Pt,
                                                    u16* __restrict__ Qb,
                                                    const float* __restrict__ s1,
                                                    const float* __restrict__ e1,
                                                    const float* __restrict__ ws2,
                                                    const float* __restrict__ bs2,
                                                    const float* __restrict__ we2,
                                                    const float* __restrict__ be2,
                                                    float* __restrict__ out) {
  if (blockIdx.x == 128) {
    int t = threadIdx.x & 127;
    int sel = threadIdx.x >> 7;
    int bb = blockIdx.y;
    if (t >= 100) return;
    const float* in = sel ? e1 : s1;
    const float* w = sel ? we2 : ws2;
    float s = sel ? be2[0] : bs2[0];
    #pragma unroll 8
    for (int c = 0; c < 256; ++c) s += w[c] * in[((size_t)bb * 256 + c) * 100 + t];
    out[80000 + sel * 400 + bb * 100 + t] = sigmoidf_(s);
    return;
  }
  __shared__ __align__(16) u16 As[128 * 64];
  __shared__ __align__(16) u16 Bs[128 * 64];
  int mt = blockIdx.x, nt = blockIdx.y;
  int col0 = nt * 128, row0 = mt * 128;
  int tid = threadIdx.x, w = tid >> 6, l = tid & 63;
  int wm = w >> 1, wn = w & 1;
  int lr = l >> 3;
  int lk_sw = ((l & 7) ^ lr) * 8;
  f32x4 acc[4][4] = {};
  size_t aoff[4];
  size_t boff[4];
  #pragma unroll
  for (int r = 0; r < 4; ++r) {
    int chunk = r * 4 + w;
    int rowA = row0 + chunk * 8 + lr;
    aoff[r] = (size_t)rowA * 128 + lk_sw;
    int colB = col0 + chunk * 8 + lr;
    if (colB >= 400) colB = 399;
    boff[r] = (size_t)colB * 128 + lk_sw;
  }
  #pragma unroll
  for (int kb = 0; kb < 2; ++kb) {
    int k0 = kb * 64;
    #pragma unroll
    for (int r = 0; r < 4; ++r) {
      int chunk = r * 4 + w;
      glds16(Wq + aoff[r] + k0, As + chunk * 512);
      glds16(Pt + boff[r] + k0, Bs + chunk * 512);
    }
    __syncthreads();
    mfma_stepT<4>(As, Bs, l, wm, wn, acc);
    __syncthreads();
  }
  int r4 = (l >> 4) * 4, c1 = l & 15;
  #pragma unroll
  for (int i = 0; i < 4; ++i) {
    int row = row0 + wm * 64 + i * 16 + r4;
    int o = row >> 5, n = row & 31;
    #pragma unroll
    for (int j = 0; j < 4; ++j) {
      int col = col0 + wn * 64 + j * 16 + c1;
      if (col < 400) {
        int b = col / 100, t = col - b * 100;
        f32x4 v = acc[i][j];
        __align__(8) u16 h[4];
        h[0] = f2bf(v[0]);
        h[1] = f2bf(v[1]);
        h[2] = f2bf(v[2]);
        h[3] = f2bf(v[3]);
        *(uint2*)(Qb + ((size_t)(b * 512 + o)) * 3200 + t * 32 + n) = *(const uint2*)h;
      }
    }
  }
}

// ---------- 3x3 conv as shifted BT-GEMM; FUSE=1 computes conf head in-epilogue ----------
template<int FUSE>
__global__ __launch_bounds__(256, 2) void conv3x3_gemm(const u16* __restrict__ Apk,
                                                       const u16* __restrict__ X,
                                                       u16* __restrict__ OUT,
                                                       const float* __restrict__ bias,
                                                       const u16* __restrict__ zp,
                                                       const float* __restrict__ w2d,
                                                       const float* __restrict__ b2d,
                                                       float* __restrict__ out) {
  __shared__ __align__(16) u16 SH[2 * 128 * 64];   // As | Bs ; reused by epilogues (32KB)
  u16* As = SH;
  u16* Bs = SH + 128 * 64;
  int nt = blockIdx.x;
  int col0 = nt * 128;
  int tid = threadIdx.x, w = tid >> 6, l = tid & 63;
  int wm = w >> 1, wn = w & 1;
  int lr = l >> 3;
  int lk_sw = ((l & 7) ^ lr) * 8;
  int cj[4], yy[4], xx[4];
  bool vv[4];
  size_t aoff[4];
  #pragma unroll
  for (int r = 0; r < 4; ++r) {
    int chunk = r * 4 + w;
    int c = col0 + chunk * 8 + lr;
    cj[r] = c;
    vv[r] = (c < 40000);
    int p = c % 10000;
    yy[r] = p / 100;
    xx[r] = p % 100;
    aoff[r] = (size_t)(chunk * 8 + lr) * 1152 + lk_sw;
  }
  f32x4 acc[4][4] = {};
  for (int s = 0; s < 9; ++s) {
    int dy = s / 3 - 1, dx = s % 3 - 1;
    int doff = dy * 100 + dx;
    #pragma unroll
    for (int half = 0; half < 2; ++half) {
      int k0 = s * 128 + half * 64;
      int c0 = half * 64;
      #pragma unroll
      for (int r = 0; r < 4; ++r) {
        int chunk = r * 4 + w;
        glds16(Apk + aoff[r] + k0, As + chunk * 512);
        int y2 = yy[r] + dy, x2 = xx[r] + dx;
        bool ok = vv[r] && ((unsigned)y2 < 100u) && ((unsigned)x2 < 100u);
        const u16* src = ok ? (X + (size_t)(cj[r] + doff) * 128 + c0 + lk_sw) : zp;
        glds16(src, Bs + chunk * 512);
      }
      __syncthreads();
      mfma_stepT<4>(As, Bs, l, wm, wn, acc);
      __syncthreads();
    }
  }
  if (FUSE == 0) {
    epilogue_coal(acc, SH, OUT, bias, 0, col0, tid, l, wm, wn, 40000, 128, 40000LL, nullptr);
  } else {
    uint32_t* W = (uint32_t*)SH;
    int r4 = (l >> 4) * 4, c1 = l & 15;
    #pragma unroll
    for (int i = 0; i < 4; ++i) {
      int ob = wm * 64 + i * 16 + r4;
      float b0 = bias[ob + 0], b1 = bias[ob + 1], b2 = bias[ob + 2], b3 = bias[ob + 3];
      #pragma unroll
      for (int j = 0; j < 4; ++j) {
        int col = wn * 64 + j * 16 + c1;
        f32x4 v = acc[i][j];
        uint32_t lo = (uint32_t)f2bf(fmaxf(v[0] + b0, 0.f)) |
                      ((uint32_t)f2bf(fmaxf(v[1] + b1, 0.f)) << 16);
        uint32_t hi = (uint32_t)f2bf(fmaxf(v[2] + b2, 0.f)) |
                      ((uint32_t)f2bf(fmaxf(v[3] + b3, 0.f)) << 16);
        int jj = ob >> 1;
        W[col * 64 + (jj ^ (col & 31))] = lo;
        W[col * 64 + ((jj + 1) ^ (col & 31))] = hi;
      }
    }
    __syncthreads();
    int col = tid & 127, sel = tid >> 7;
    int gcol = col0 + col;
    if (gcol < 40000) {
      float sum = b2d[sel];
      const uint32_t* Wc = W + col * 64;
      const float* wd = w2d + sel * 128;
      #pragma unroll 8
      for (int c = 0; c < 64; ++c) {
        uint32_t v = Wc[c ^ (col & 31)];
        sum += wd[2 * c] * bf2f((u16)(v & 0xffffu)) + wd[2 * c + 1] * bf2f((u16)(v >> 16));
      }
      int b = gcol / 10000, pidx = gcol - b * 10000;
      out[((size_t)b * 2 + sel) * 10000 + pidx] = sigmoidf_(sum);
    }
  }
}

// ---------- launch ----------
extern "C" void kernel_launch(void* const* d_in, const int* in_sizes, int n_in, void* d_out,
                              int out_size, void* d_ws, size_t ws_size, hipStream_t stream) {
  const float* inputs = (const float*)d_in[0];
  const float* w_b1 = (const float*)d_in[1];
  const float* b_b1 = (const float*)d_in[2];
  const float* w_b2 = (const float*)d_in[3];
  const float* b_b2 = (const float*)d_in[4];
  const float* w_s1 = (const float*)d_in[5];
  const float* b_s1 = (const float*)d_in[6];
  const float* w_s2 = (const float*)d_in[7];
  const float* b_s2 = (const float*)d_in[8];
  const float* w_e1 = (const float*)d_in[9];
  const float* b_e1 = (const float*)d_in[10];
  const float* w_e2 = (const float*)d_in[11];
  const float* b_e2 = (const float*)d_in[12];
  const float* w_p1 = (const float*)d_in[13];
  const float* b_p1 = (const float*)d_in[14];
  const float* w3d = (const float*)d_in[15];
  const float* b3d = (const float*)d_in[16];
  const float* w2a = (const float*)d_in[17];
  const float* b2a = (const float*)d_in[18];
  const float* w2b = (const float*)d_in[19];
  const float* b2b = (const float*)d_in[20];
  const float* w2c = (const float*)d_in[21];
  const float* b2c = (const float*)d_in[22];
  const float* w2d = (const float*)d_in[23];
  const float* b2d = (const float*)d_in[24];
  float* out = (float*)d_out;
  char* ws = (char*)d_ws;

  int* tinfo = (int*)(ws + 0);
  int* order = (int*)(ws + 2048);
  u16* zp = (u16*)(ws + 16384);
  int* invperm = (int*)(ws + 45056);
  float* base1 = (float*)(ws + 90112);          // 409600
  float* base = (float*)(ws + 499712);          // 409600
  float* s1buf = (float*)(ws + 909312);         // 409600
  u16* Pt = (u16*)(ws + 1318912);               // 102400
  u16* w2a_bf = (u16*)(ws + 1421312);           // 131072
  u16* w2b_pk = (u16*)(ws + 1552384);           // 294912
  u16* w2c_pk = (u16*)(ws + 1847296);           // 294912
  u16* Qb = (u16*)(ws + 2142208);               // 13107200 (ends 15249408)
  u16* Mt = (u16*)(ws + 15249408);              // rows 0..5119 used -> ends 48017408
  float* e1buf = (float*)(ws + 48017408);       // 409600, in Mt-region free tail (no alias!)
  u16* C1t = (u16*)(ws + 79249408);             // 40960000  (end 120209408)
  u16* Wq = (u16*)(ws + 79249408);              // aliases C1t: dead before G1 writes C1t
  u16* x2t = Qb;   // alias: Qb dead after G1
  u16* x3t = C1t;  // alias: C1t dead after G2

  // 1) fused prep: conv1 first (overlaps), weight casts, invperm, tile spans, mask rows
  prep_fused<<<3641, 256, 0, stream>>>(w2a, w2b, w2c, w2a_bf, w2b_pk, w2c_pk, w3d, Wq,
                                       invperm, tinfo, order, zp, Mt, inputs, w_b1, b_b1,
                                       base1);

  // 2-3) front end (fp32 exact; p-branch ic-split 4-way for occupancy)
  conv1d_k3v<<<100, 256, 0, stream>>>(base1, w_b2, b_b2, base, 256, 64, 64, 256);
  branch_split<<<400, 256, 0, stream>>>(base, w_s1, b_s1, w_e1, b_e1, w_p1, b_p1,
                                        s1buf, e1buf, Pt);

  // 4) qprep GEMM [16384 x 400 x 128] + fused start/end sigmoid heads
  qprep_sig<<<dim3(129, 4), 256, 0, stream>>>(Wq, Pt, Qb, s1buf, e1buf, w_s2, b_s2,
                                              w_e2, b_e2, out);

  // 5) G1: out3d, 128x128 tiles, longest-first; de-permuted coalesced store into C1t
  gemm_bt<<<dim3(16, 79), 256, 0, stream>>>(Qb, Mt, C1t, b3d, 10000, 3200, tinfo, order, 50,
                                            512, 10000LL, 10000, invperm);
  // 6) G2: 1x1 conv 512->128
  gemm_bt<<<dim3(1, 313), 256, 0, stream>>>(w2a_bf, C1t, x2t, b2a, 40000, 512, nullptr,
                                            nullptr, 8, 128, 40000LL, 40000, nullptr);
  // 7) G3: 3x3 conv 128->128
  conv3x3_gemm<0><<<dim3(313), 256, 0, stream>>>(w2b_pk, x2t, x3t, b2b, zp, nullptr, nullptr,
                                                 nullptr);
  // 8) G4: 3x3 conv 128->128 + fused conf head (no x4 global round-trip)
  conv3x3_gemm<1><<<dim3(313), 256, 0, stream>>>(w2c_pk, x3t, nullptr, b2c, zp, w2d, b2d,
                                                 out);
}

// Round 18
// 223.234 us; speedup vs baseline: 1.1982x; 1.0420x over previous
//
#include <hip/hip_runtime.h>
#include <cstdint>
#include <cstddef>
#include <math.h>

typedef unsigned short u16;
typedef short bf16x8 __attribute__((ext_vector_type(8)));
typedef float f32x4 __attribute__((ext_vector_type(4)));

// ---------- helpers ----------
__device__ __forceinline__ u16 f2bf(float f) {
  union { float f; uint32_t u; } c; c.f = f;
  uint32_t u = c.u;
  return (u16)((u + 0x7FFFu + ((u >> 16) & 1u)) >> 16);
}
__device__ __forceinline__ float bf2f(u16 h) {
  union { uint32_t u; float f; } c; c.u = ((uint32_t)h) << 16;
  return c.f;
}
__device__ __forceinline__ float sigmoidf_(float x) { return 1.f / (1.f + expf(-x)); }

__device__ __forceinline__ void glds16(const void* g, void* l) {
  __builtin_amdgcn_global_load_lds((const __attribute__((address_space(1))) void*)g,
                                   (__attribute__((address_space(3))) void*)l, 16, 0, 0);
}

// column permutation: valid (s<=e) pairs compacted in natural order, invalid at end
__device__ __forceinline__ int col_rank(int p) {
  int s = p / 100, e = p - s * 100;
  int tri = (s * (s - 1)) >> 1;
  return (e >= s) ? (p - tri - s) : (5050 + tri + e);
}

// ---------- front-end 1D convs, ILP version: 4 t per thread via float4 ----------
__global__ void conv1d_k3v(const float* __restrict__ in, const float* __restrict__ w,
                           const float* __restrict__ bias, float* __restrict__ out,
                           int Cin_total, int Cin_g, int ocPerGroup, int OC) {
  int idx = blockIdx.x * 256 + threadIdx.x;
  int sub = idx % 25;
  int tmp = idx / 25;
  int oc = tmp % OC;
  int bb = tmp / OC;
  if (bb >= 4) return;
  int t4 = sub * 4;
  int g = oc / ocPerGroup;
  const float* ip = in + ((size_t)bb * Cin_total + (size_t)g * Cin_g) * 100 + t4;
  const float* wp = w + (size_t)oc * Cin_g * 3;
  float bs = bias[oc];
  float s0 = bs, s1 = bs, s2 = bs, s3 = bs;
  #pragma unroll 4
  for (int ic = 0; ic < Cin_g; ++ic) {
    const float* r = ip + (size_t)ic * 100;
    float4 a = *(const float4*)r;
    float xm = (t4 > 0) ? r[-1] : 0.f;
    float xp = (t4 < 96) ? r[4] : 0.f;
    float w0 = wp[ic * 3 + 0], w1 = wp[ic * 3 + 1], w2 = wp[ic * 3 + 2];
    s0 += w0 * xm + w1 * a.x + w2 * a.y;
    s1 += w0 * a.x + w1 * a.y + w2 * a.z;
    s2 += w0 * a.y + w1 * a.z + w2 * a.w;
    s3 += w0 * a.z + w1 * a.w + w2 * xp;
  }
  float4 o;
  o.x = fmaxf(s0, 0.f); o.y = fmaxf(s1, 0.f);
  o.z = fmaxf(s2, 0.f); o.w = fmaxf(s3, 0.f);
  *(float4*)(out + ((size_t)bb * OC + oc) * 100 + t4) = o;
}

// fused s1/e1/p branches; s/e full-reduction, p-part 4-way ic-split
__global__ void branch_split(const float* __restrict__ in, const float* __restrict__ wS,
                             const float* __restrict__ bS, const float* __restrict__ wE,
                             const float* __restrict__ bE, const float* __restrict__ wP,
                             const float* __restrict__ bP, float* __restrict__ outS,
                             float* __restrict__ outE, u16* __restrict__ Pt) {
  int idx = blockIdx.x * 256 + threadIdx.x;
  if (idx < 51200) {
    int sub = idx % 25;
    int tmp = idx / 25;
    int ocx = tmp & 511;
    int bb = tmp >> 9;
    int t4 = sub * 4;
    int sel = ocx >> 8;
    int oc = ocx & 255;
    const float* w = sel ? wE : wS;
    const float* bias = sel ? bE : bS;
    int g = oc >> 6;
    const float* ip = in + ((size_t)bb * 256 + (size_t)g * 64) * 100 + t4;
    const float* wp = w + (size_t)oc * 192;
    float bs = bias[oc];
    float s0 = bs, s1 = bs, s2 = bs, s3 = bs;
    #pragma unroll 4
    for (int ic = 0; ic < 64; ++ic) {
      const float* r = ip + (size_t)ic * 100;
      float4 a = *(const float4*)r;
      float xm = (t4 > 0) ? r[-1] : 0.f;
      float xp = (t4 < 96) ? r[4] : 0.f;
      float w0 = wp[ic * 3 + 0], w1 = wp[ic * 3 + 1], w2 = wp[ic * 3 + 2];
      s0 += w0 * xm + w1 * a.x + w2 * a.y;
      s1 += w0 * a.x + w1 * a.y + w2 * a.z;
      s2 += w0 * a.y + w1 * a.z + w2 * a.w;
      s3 += w0 * a.z + w1 * a.w + w2 * xp;
    }
    float* out = sel ? outE : outS;
    float4 o;
    o.x = fmaxf(s0, 0.f); o.y = fmaxf(s1, 0.f);
    o.z = fmaxf(s2, 0.f); o.w = fmaxf(s3, 0.f);
    *(float4*)(out + ((size_t)bb * 256 + oc) * 100 + t4) = o;
  } else {
    int j = idx - 51200;
    int r = j & 3;
    int quad = j >> 2;
    int sub = quad % 25;
    int tmp = quad / 25;
    int oc = tmp & 127;
    int bb = tmp >> 7;
    int t4 = sub * 4;
    const float* wp = wP + (size_t)oc * 768 + r * 192;
    const float* ip = in + ((size_t)bb * 256 + r * 64) * 100 + t4;
    float s0 = 0.f, s1 = 0.f, s2 = 0.f, s3 = 0.f;
    #pragma unroll 4
    for (int i = 0; i < 64; ++i) {
      const float* rr = ip + (size_t)i * 100;
      float4 a = *(const float4*)rr;
      float xm = (t4 > 0) ? rr[-1] : 0.f;
      float xp = (t4 < 96) ? rr[4] : 0.f;
      float w0 = wp[i * 3 + 0], w1 = wp[i * 3 + 1], w2 = wp[i * 3 + 2];
      s0 += w0 * xm + w1 * a.x + w2 * a.y;
      s1 += w0 * a.x + w1 * a.y + w2 * a.z;
      s2 += w0 * a.y + w1 * a.z + w2 * a.w;
      s3 += w0 * a.z + w1 * a.w + w2 * xp;
    }
    s0 += __shfl_xor(s0, 1); s0 += __shfl_xor(s0, 2);
    s1 += __shfl_xor(s1, 1); s1 += __shfl_xor(s1, 2);
    s2 += __shfl_xor(s2, 1); s2 += __shfl_xor(s2, 2);
    s3 += __shfl_xor(s3, 1); s3 += __shfl_xor(s3, 2);
    if (r == 0) {
      float b = bP[oc];
      Pt[((size_t)bb * 100 + t4 + 0) * 128 + oc] = f2bf(fmaxf(s0 + b, 0.f));
      Pt[((size_t)bb * 100 + t4 + 1) * 128 + oc] = f2bf(fmaxf(s1 + b, 0.f));
      Pt[((size_t)bb * 100 + t4 + 2) * 128 + oc] = f2bf(fmaxf(s2 + b, 0.f));
      Pt[((size_t)bb * 100 + t4 + 3) * 128 + oc] = f2bf(fmaxf(s3 + b, 0.f));
    }
  }
}

// ---------- fused prep; conv1 FIRST (bids 0-399, 4-way ic-split), mask rows 2/block ----------
__global__ void prep_fused(const float* __restrict__ w2a, const float* __restrict__ w2b,
                           const float* __restrict__ w2c, u16* __restrict__ w2a_bf,
                           u16* __restrict__ w2b_pk, u16* __restrict__ w2c_pk,
                           const float* __restrict__ w3d, u16* __restrict__ Wq,
                           int* __restrict__ invperm, int* __restrict__ tinfo,
                           int* __restrict__ order, u16* __restrict__ zp,
                           u16* __restrict__ Mt, const float* __restrict__ inputs,
                           const float* __restrict__ w_b1, const float* __restrict__ b_b1,
                           float* __restrict__ base1) {
  __shared__ __align__(16) u16 ML[2 * 3200];   // 12.8 KB: 2 mask rows
  __shared__ int C[128];
  int bid = blockIdx.x, tid = threadIdx.x;
  if (bid < 400) {
    int u = bid * 256 + tid;
    int r = u & 3;
    int quad = u >> 2;
    int sub = quad % 25;
    int tmp = quad / 25;
    int oc = tmp & 255;
    int bb = tmp >> 8;
    int t4 = sub * 4;
    int g = oc >> 6;
    const float* ip = inputs + ((size_t)bb * 400 + g * 100 + r * 25) * 100 + t4;
    const float* wp = w_b1 + (size_t)oc * 300 + r * 75;
    float s0 = 0.f, s1 = 0.f, s2 = 0.f, s3 = 0.f;
    #pragma unroll 5
    for (int i = 0; i < 25; ++i) {
      const float* rr = ip + (size_t)i * 100;
      float4 a = *(const float4*)rr;
      float xm = (t4 > 0) ? rr[-1] : 0.f;
      float xp = (t4 < 96) ? rr[4] : 0.f;
      float w0 = wp[i * 3 + 0], w1 = wp[i * 3 + 1], w2 = wp[i * 3 + 2];
      s0 += w0 * xm + w1 * a.x + w2 * a.y;
      s1 += w0 * a.x + w1 * a.y + w2 * a.z;
      s2 += w0 * a.y + w1 * a.z + w2 * a.w;
      s3 += w0 * a.z + w1 * a.w + w2 * xp;
    }
    s0 += __shfl_xor(s0, 1); s0 += __shfl_xor(s0, 2);
    s1 += __shfl_xor(s1, 1); s1 += __shfl_xor(s1, 2);
    s2 += __shfl_xor(s2, 1); s2 += __shfl_xor(s2, 2);
    s3 += __shfl_xor(s3, 1); s3 += __shfl_xor(s3, 2);
    if (r == 0) {
      float b = b_b1[oc];
      float4 o;
      o.x = fmaxf(s0 + b, 0.f); o.y = fmaxf(s1 + b, 0.f);
      o.z = fmaxf(s2 + b, 0.f); o.w = fmaxf(s3 + b, 0.f);
      *(float4*)(base1 + ((size_t)bb * 256 + oc) * 100 + t4) = o;
    }
  } else if (bid < 976) {
    int i = (bid - 400) * 256 + tid;
    if (i < 65536) w2a_bf[i] = f2bf(w2a[i]);
    if (i < 147456) {
      int oc = i / 1152, r = i % 1152, kk = r >> 7, ic = r & 127;
      int src = (oc * 128 + ic) * 9 + kk;
      w2b_pk[i] = f2bf(w2b[src]);
      w2c_pk[i] = f2bf(w2c[src]);
    }
  } else if (bid < 1040) {
    int u = (bid - 976) * 256 + tid;
    int o = u >> 5, n = u & 31;
    const float* src = w3d + (size_t)o * 4096 + n;
    u16* dst = Wq + (size_t)u * 128;
    for (int c0 = 0; c0 < 128; c0 += 8) {
      __align__(16) u16 h[8];
      #pragma unroll
      for (int j = 0; j < 8; ++j) h[j] = f2bf(src[(size_t)(c0 + j) * 32]);
      *(uint4*)(dst + c0) = *(const uint4*)h;
    }
  } else if (bid < 1080) {
    int p = (bid - 1040) * 256 + tid;
    if (p < 10000) invperm[col_rank(p)] = p;
  } else if (bid == 1080) {
    if (tid < 128) zp[tid] = 0;
    int t = tid;
    int kbmin = 0, cnt = 0;
    if (t < 79) {
      int rlo = t * 128;
      int rhi = rlo + 128;
      if (rhi > 5050) rhi = 5050;
      if (rlo < 5050) {
        int s = 0;
        while (100 * (s + 1) - ((s + 1) * s) / 2 <= rlo) ++s;
        int cum = 100 * s - (s * (s - 1)) / 2;
        int tmin = 100, tmax = -1;
        for (int r = rlo; r < rhi; ++r) {
          while (r - cum >= 100 - s) { ++s; cum = 100 * s - (s * (s - 1)) / 2; }
          int e = s + (r - cum);
          float L = (float)(e - s + 2);
          float sp2 = (float)s - 0.5f * L;
          float ep2 = (float)(e + 1) + 0.5f * L;
          int a = (int)floorf(sp2) - 1;
          if (a < 0) a = 0;
          int b = (int)floorf(ep2) + 2;
          if (b > 99) b = 99;
          if (a < tmin) tmin = a;
          if (b > tmax) tmax = b;
        }
        kbmin = tmin >> 1;
        cnt = (tmax >> 1) - kbmin + 1;
      }
      tinfo[2 * t] = kbmin;
      tinfo[2 * t + 1] = cnt;
    }
    if (t < 128) C[t] = (t < 79) ? cnt : -1;
    __syncthreads();
    if (t < 79) {
      int pos = 0;
      int ct = C[t];
      for (int u = 0; u < 79; ++u) {
        int cu = C[u];
        pos += (cu > ct) || (cu == ct && u < t);
      }
      order[pos] = t;
    }
  } else {
    int r0 = (bid - 1081) * 2;
    uint32_t* MZ = (uint32_t*)ML;
    for (int i = tid; i < 3200; i += 256) MZ[i] = 0;
    __syncthreads();
    int g = tid >> 6, lane = tid & 63;
    int r = r0 + g;
    if (g < 2 && r < 5050 && lane < 32) {
      int n = lane;
      int s = (int)((201.0 - sqrt((double)(40401 - 8 * r))) * 0.5);
      if (s < 0) s = 0;
      while (s * (201 - s) / 2 > r) --s;
      while ((s + 1) * (200 - s) / 2 <= r) ++s;
      int e = s + (r - s * (201 - s) / 2);
      double sp = (double)s, ep = (double)(e + 1);
      double L = ep - sp + 1.0;
      double sp2 = sp - L * 0.5;
      double ep2 = ep + L * 0.5;
      double step = (ep2 - sp2) / 95.0;
      double win[8];
      #pragma unroll
      for (int k = 0; k < 8; ++k) win[k] = 0.0;
      int base = -1;
      #pragma unroll
      for (int jj = 0; jj < 3; ++jj) {
        double pos = sp2 + step * (double)(n * 3 + jj);
        double ip;
        double fr = modf(pos, &ip);
        int it = (int)ip;
        if (it >= 0 && it < 99) {
          if (base < 0) base = it;
          int off = it - base;
          win[off] += (1.0 - fr) / 3.0;
          win[off + 1] += fr / 3.0;
        }
      }
      if (base >= 0) {
        u16* dst = ML + g * 3200 + n;
        #pragma unroll
        for (int k = 0; k < 8; ++k) {
          int t = base + k;
          if (t < 100) dst[t * 32] = f2bf((float)win[k]);
        }
      }
    }
    __syncthreads();
    for (int i = tid; i < 800; i += 256) {
      int rl = i / 400, off = i - rl * 400;
      *(uint4*)(Mt + (size_t)(r0 + rl) * 3200 + off * 8) = ((const uint4*)ML)[i];
    }
  }
}

// ---------- shared MFMA pieces (T2 XOR-swizzled reads; sources pre-swizzled) ----------
template<int MI>
__device__ __forceinline__ void mfma_stepT(const u16* As, const u16* Bs, int l, int wm, int wn,
                                           f32x4 (&acc)[MI][4]) {
  int m15 = l & 15, q = l >> 4, sw = m15 & 7;
  #pragma unroll
  for (int kk = 0; kk < 2; ++kk) {
    int koff = ((kk * 4 + q) ^ sw) * 8;
    bf16x8 av[MI], bv[4];
    #pragma unroll
    for (int i = 0; i < MI; ++i)
      av[i] = *(const bf16x8*)(As + (size_t)(wm * (MI * 16) + i * 16 + m15) * 64 + koff);
    #pragma unroll
    for (int j = 0; j < 4; ++j)
      bv[j] = *(const bf16x8*)(Bs + (size_t)(wn * 64 + j * 16 + m15) * 64 + koff);
    #pragma unroll
    for (int i = 0; i < MI; ++i) {
      #pragma unroll
      for (int j = 0; j < 4; ++j)
        acc[i][j] = __builtin_amdgcn_mfma_f32_16x16x32_bf16(av[i], bv[j], acc[i][j], 0, 0, 0);
    }
  }
}

// 64-col variant: waves 2(M)x2(N), acc 64 rows x 32 cols per wave
__device__ __forceinline__ void mfma_step64(const u16* As, const u16* Bs, int l, int wm, int wn,
                                            f32x4 (&acc)[4][2]) {
  int m15 = l & 15, q = l >> 4, sw = m15 & 7;
  #pragma unroll
  for (int kk = 0; kk < 2; ++kk) {
    int koff = ((kk * 4 + q) ^ sw) * 8;
    bf16x8 av[4], bv[2];
    #pragma unroll
    for (int i = 0; i < 4; ++i)
      av[i] = *(const bf16x8*)(As + (size_t)(wm * 64 + i * 16 + m15) * 64 + koff);
    #pragma unroll
    for (int j = 0; j < 2; ++j)
      bv[j] = *(const bf16x8*)(Bs + (size_t)(wn * 32 + j * 16 + m15) * 64 + koff);
    #pragma unroll
    for (int i = 0; i < 4; ++i) {
      #pragma unroll
      for (int j = 0; j < 2; ++j)
        acc[i][j] = __builtin_amdgcn_mfma_f32_16x16x32_bf16(av[i], bv[j], acc[i][j], 0, 0, 0);
    }
  }
}

// ---------- coalesced epilogue (128-col tiles) ----------
__device__ __forceinline__ void epilogue_coal(f32x4 (&acc)[4][4], u16* SH, u16* OUT,
                                              const float* bias, int row0, int col0, int tid,
                                              int l, int wm, int wn, int N, int OC,
                                              long long NPB, const int* colmap) {
  uint32_t* W = (uint32_t*)SH;
  int r4 = (l >> 4) * 4, c1 = l & 15;
  int bb0 = row0 % OC;
  #pragma unroll
  for (int i = 0; i < 4; ++i) {
    int ob = wm * 64 + i * 16 + r4;
    float b0 = bias[bb0 + ob + 0], b1 = bias[bb0 + ob + 1];
    float b2 = bias[bb0 + ob + 2], b3 = bias[bb0 + ob + 3];
    int jj = ob >> 1;
    #pragma unroll
    for (int j = 0; j < 4; ++j) {
      int col = wn * 64 + j * 16 + c1;
      f32x4 v = acc[i][j];
      uint32_t lo = (uint32_t)f2bf(fmaxf(v[0] + b0, 0.f)) |
                    ((uint32_t)f2bf(fmaxf(v[1] + b1, 0.f)) << 16);
      uint32_t hi = (uint32_t)f2bf(fmaxf(v[2] + b2, 0.f)) |
                    ((uint32_t)f2bf(fmaxf(v[3] + b3, 0.f)) << 16);
      W[col * 64 + (jj ^ (col & 31))] = lo;
      W[col * 64 + ((jj + 1) ^ (col & 31))] = hi;
    }
  }
  __syncthreads();
  int col = tid >> 1, half = tid & 1;
  int gcol = col0 + col;
  if (gcol < N) {
    int pcol = colmap ? colmap[gcol] : gcol;
    const uint32_t* Wc = W + col * 64;
    __align__(16) uint32_t tbuf[32];
    #pragma unroll
    for (int k = 0; k < 32; ++k) tbuf[k] = Wc[(half * 32 + k) ^ (col & 31)];
    u16* dst = OUT + (size_t)(row0 / OC) * (size_t)OC * (size_t)NPB + (size_t)pcol * OC +
               bb0 + half * 64;
    #pragma unroll
    for (int q = 0; q < 8; ++q) *(uint4*)(dst + q * 8) = *(const uint4*)(tbuf + q * 4);
  }
}

// 64-col coalesced epilogue: 128 ch x 64 cols, OUT[(col)][128]
__device__ __forceinline__ void epilogue_coal64(f32x4 (&acc)[4][2], u16* SH, u16* OUT,
                                                const float* bias, int col0, int tid, int l,
                                                int wm, int wn) {
  uint32_t* W = (uint32_t*)SH;   // 64 cols x 64 u32 = 16KB
  int r4 = (l >> 4) * 4, c1 = l & 15;
  #pragma unroll
  for (int i = 0; i < 4; ++i) {
    int ob = wm * 64 + i * 16 + r4;
    float b0 = bias[ob + 0], b1 = bias[ob + 1], b2 = bias[ob + 2], b3 = bias[ob + 3];
    int jj = ob >> 1;
    #pragma unroll
    for (int j = 0; j < 2; ++j) {
      int col = wn * 32 + j * 16 + c1;
      f32x4 v = acc[i][j];
      uint32_t lo = (uint32_t)f2bf(fmaxf(v[0] + b0, 0.f)) |
                    ((uint32_t)f2bf(fmaxf(v[1] + b1, 0.f)) << 16);
      uint32_t hi = (uint32_t)f2bf(fmaxf(v[2] + b2, 0.f)) |
                    ((uint32_t)f2bf(fmaxf(v[3] + b3, 0.f)) << 16);
      W[col * 64 + (jj ^ (col & 31))] = lo;
      W[col * 64 + ((jj + 1) ^ (col & 31))] = hi;
    }
  }
  __syncthreads();
  if (tid < 128) {
    int col = tid >> 1, half = tid & 1;
    const uint32_t* Wc = W + col * 64;
    __align__(16) uint32_t tbuf[32];
    #pragma unroll
    for (int k = 0; k < 32; ++k) tbuf[k] = Wc[(half * 32 + k) ^ (col & 31)];
    u16* dst = OUT + (size_t)(col0 + col) * 128 + half * 64;
    #pragma unroll
    for (int q = 0; q < 8; ++q) *(uint4*)(dst + q * 8) = *(const uint4*)(tbuf + q * 4);
  }
}

// ---------- generic BT-GEMM (128-col); used for G1 ----------
__global__ __launch_bounds__(256, 2) void gemm_bt(const u16* __restrict__ A,
                                                  const u16* __restrict__ B,
                                                  u16* __restrict__ OUT,
                                                  const float* __restrict__ bias, int N, int K,
                                                  const int* __restrict__ tinfo,
                                                  const int* __restrict__ order, int kblocks,
                                                  int OC, long long NPB, int NclampB,
                                                  const int* __restrict__ colmap) {
  __shared__ __align__(16) u16 SH[2 * 128 * 64];
  u16* As = SH;
  u16* Bs = SH + 128 * 64;
  int mt = blockIdx.x;
  int nt = order ? order[blockIdx.y] : blockIdx.y;
  int col0 = nt * 128, row0 = mt * 128;
  int tid = threadIdx.x, w = tid >> 6, l = tid & 63;
  int wm = w >> 1, wn = w & 1;
  int lr = l >> 3;
  int lk_sw = ((l & 7) ^ lr) * 8;
  f32x4 acc[4][4] = {};
  size_t aoff[4];
  size_t boff[4];
  #pragma unroll
  for (int r = 0; r < 4; ++r) {
    int chunk = r * 4 + w;
    int rowA = row0 + chunk * 8 + lr;
    aoff[r] = (size_t)rowA * K + lk_sw;
    int colB = col0 + chunk * 8 + lr;
    if (colB >= NclampB) colB = NclampB - 1;
    boff[r] = (size_t)colB * K + lk_sw;
  }
  int kbmin = 0, cnt = kblocks;
  if (tinfo) { kbmin = tinfo[2 * nt]; cnt = tinfo[2 * nt + 1]; }
  for (int i = 0; i < cnt; ++i) {
    int k0 = (kbmin + i) * 64;
    #pragma unroll
    for (int r = 0; r < 4; ++r) {
      int chunk = r * 4 + w;
      glds16(A + aoff[r] + k0, As + chunk * 512);
      glds16(B + boff[r] + k0, Bs + chunk * 512);
    }
    __syncthreads();
    mfma_stepT<4>(As, Bs, l, wm, wn, acc);
    __syncthreads();
  }
  epilogue_coal(acc, SH, OUT, bias, row0, col0, tid, l, wm, wn, N, OC, NPB, colmap);
}

// ---------- 64-col BT-GEMM; used for G2 (K=512, M=128) ----------
__global__ __launch_bounds__(256, 2) void gemm_bt64(const u16* __restrict__ A,
                                                    const u16* __restrict__ B,
                                                    u16* __restrict__ OUT,
                                                    const float* __restrict__ bias) {
  __shared__ __align__(16) u16 SH[128 * 64 + 64 * 64];   // 24KB
  u16* As = SH;
  u16* Bs = SH + 128 * 64;
  int col0 = blockIdx.x * 64;
  int tid = threadIdx.x, w = tid >> 6, l = tid & 63;
  int wm = w >> 1, wn = w & 1;
  int lr = l >> 3;
  int lk_sw = ((l & 7) ^ lr) * 8;
  f32x4 acc[4][2] = {};
  size_t aoff[4], boff[2];
  #pragma unroll
  for (int r = 0; r < 4; ++r) {
    int chunk = r * 4 + w;
    aoff[r] = (size_t)(chunk * 8 + lr) * 512 + lk_sw;
  }
  #pragma unroll
  for (int r = 0; r < 2; ++r) {
    int chunk = r * 4 + w;
    boff[r] = (size_t)(col0 + chunk * 8 + lr) * 512 + lk_sw;
  }
  for (int kb = 0; kb < 8; ++kb) {
    int k0 = kb * 64;
    #pragma unroll
    for (int r = 0; r < 4; ++r)
      glds16(A + aoff[r] + k0, As + (r * 4 + w) * 512);
    #pragma unroll
    for (int r = 0; r < 2; ++r)
      glds16(B + boff[r] + k0, Bs + (r * 4 + w) * 512);
    __syncthreads();
    mfma_step64(As, Bs, l, wm, wn, acc);
    __syncthreads();
  }
  epilogue_coal64(acc, SH, OUT, bias, col0, tid, l, wm, wn);
}

// ---------- qprep as MFMA GEMM + fused start/end sigmoid heads ----------
__global__ __launch_bounds__(256, 2) void qprep_sig(const u16* __restrict__ Wq,
                                                    const u16* __restrict__ Pt,
                                                    u16* __restrict__ Qb,
                                                    const float* __restrict__ s1,
                                                    const float* __restrict__ e1,
                                                    const float* __restrict__ ws2,
                                                    const float* __restrict__ bs2,
                                                    const float* __restrict__ we2,
                                                    const float* __restrict__ be2,
                                                    float* __restrict__ out) {
  if (blockIdx.x == 128) {
    int t = threadIdx.x & 127;
    int sel = threadIdx.x >> 7;
    int bb = blockIdx.y;
    if (t >= 100) return;
    const float* in = sel ? e1 : s1;
    const float* w = sel ? we2 : ws2;
    float s = sel ? be2[0] : bs2[0];
    #pragma unroll 8
    for (int c = 0; c < 256; ++c) s += w[c] * in[((size_t)bb * 256 + c) * 100 + t];
    out[80000 + sel * 400 + bb * 100 + t] = sigmoidf_(s);
    return;
  }
  __shared__ __align__(16) u16 As[128 * 64];
  __shared__ __align__(16) u16 Bs[128 * 64];
  int mt = blockIdx.x, nt = blockIdx.y;
  int col0 = nt * 128, row0 = mt * 128;
  int tid = threadIdx.x, w = tid >> 6, l = tid & 63;
  int wm = w >> 1, wn = w & 1;
  int lr = l >> 3;
  int lk_sw = ((l & 7) ^ lr) * 8;
  f32x4 acc[4][4] = {};
  size_t aoff[4];
  size_t boff[4];
  #pragma unroll
  for (int r = 0; r < 4; ++r) {
    int chunk = r * 4 + w;
    int rowA = row0 + chunk * 8 + lr;
    aoff[r] = (size_t)rowA * 128 + lk_sw;
    int colB = col0 + chunk * 8 + lr;
    if (colB >= 400) colB = 399;
    boff[r] = (size_t)colB * 128 + lk_sw;
  }
  #pragma unroll
  for (int kb = 0; kb < 2; ++kb) {
    int k0 = kb * 64;
    #pragma unroll
    for (int r = 0; r < 4; ++r) {
      int chunk = r * 4 + w;
      glds16(Wq + aoff[r] + k0, As + chunk * 512);
      glds16(Pt + boff[r] + k0, Bs + chunk * 512);
    }
    __syncthreads();
    mfma_stepT<4>(As, Bs, l, wm, wn, acc);
    __syncthreads();
  }
  int r4 = (l >> 4) * 4, c1 = l & 15;
  #pragma unroll
  for (int i = 0; i < 4; ++i) {
    int row = row0 + wm * 64 + i * 16 + r4;
    int o = row >> 5, n = row & 31;
    #pragma unroll
    for (int j = 0; j < 4; ++j) {
      int col = col0 + wn * 64 + j * 16 + c1;
      if (col < 400) {
        int b = col / 100, t = col - b * 100;
        f32x4 v = acc[i][j];
        __align__(8) u16 h[4];
        h[0] = f2bf(v[0]);
        h[1] = f2bf(v[1]);
        h[2] = f2bf(v[2]);
        h[3] = f2bf(v[3]);
        *(uint2*)(Qb + ((size_t)(b * 512 + o)) * 3200 + t * 32 + n) = *(const uint2*)h;
      }
    }
  }
}

// ---------- 64-col 3x3 conv as shifted BT-GEMM; FUSE=1 fuses conf head ----------
template<int FUSE>
__global__ __launch_bounds__(256, 2) void conv3x3_gemm64(const u16* __restrict__ Apk,
                                                         const u16* __restrict__ X,
                                                         u16* __restrict__ OUT,
                                                         const float* __restrict__ bias,
                                                         const u16* __restrict__ zp,
                                                         const float* __restrict__ w2d,
                                                         const float* __restrict__ b2d,
                                                         float* __restrict__ out) {
  __shared__ __align__(16) u16 SH[128 * 64 + 64 * 64];   // As 16KB + Bs 8KB
  u16* As = SH;
  u16* Bs = SH + 128 * 64;
  int col0 = blockIdx.x * 64;
  int tid = threadIdx.x, w = tid >> 6, l = tid & 63;
  int wm = w >> 1, wn = w & 1;
  int lr = l >> 3;
  int lk_sw = ((l & 7) ^ lr) * 8;
  int cj[2], yy[2], xx[2];
  size_t aoff[4];
  #pragma unroll
  for (int r = 0; r < 4; ++r) {
    int chunk = r * 4 + w;
    aoff[r] = (size_t)(chunk * 8 + lr) * 1152 + lk_sw;
  }
  #pragma unroll
  for (int r = 0; r < 2; ++r) {
    int chunk = r * 4 + w;
    int c = col0 + chunk * 8 + lr;
    cj[r] = c;
    int p = c % 10000;
    yy[r] = p / 100;
    xx[r] = p % 100;
  }
  f32x4 acc[4][2] = {};
  for (int s = 0; s < 9; ++s) {
    int dy = s / 3 - 1, dx = s % 3 - 1;
    int doff = dy * 100 + dx;
    #pragma unroll
    for (int half = 0; half < 2; ++half) {
      int k0 = s * 128 + half * 64;
      int c0 = half * 64;
      #pragma unroll
      for (int r = 0; r < 4; ++r)
        glds16(Apk + aoff[r] + k0, As + (r * 4 + w) * 512);
      #pragma unroll
      for (int r = 0; r < 2; ++r) {
        int y2 = yy[r] + dy, x2 = xx[r] + dx;
        bool ok = ((unsigned)y2 < 100u) && ((unsigned)x2 < 100u);
        const u16* src = ok ? (X + (size_t)(cj[r] + doff) * 128 + c0 + lk_sw) : zp;
        glds16(src, Bs + (r * 4 + w) * 512);
      }
      __syncthreads();
      mfma_step64(As, Bs, l, wm, wn, acc);
      __syncthreads();
    }
  }
  if (FUSE == 0) {
    epilogue_coal64(acc, SH, OUT, bias, col0, tid, l, wm, wn);
  } else {
    uint32_t* W = (uint32_t*)SH;
    int r4 = (l >> 4) * 4, c1 = l & 15;
    #pragma unroll
    for (int i = 0; i < 4; ++i) {
      int ob = wm * 64 + i * 16 + r4;
      float b0 = bias[ob + 0], b1 = bias[ob + 1], b2 = bias[ob + 2], b3 = bias[ob + 3];
      int jj = ob >> 1;
      #pragma unroll
      for (int j = 0; j < 2; ++j) {
        int col = wn * 32 + j * 16 + c1;
        f32x4 v = acc[i][j];
        uint32_t lo = (uint32_t)f2bf(fmaxf(v[0] + b0, 0.f)) |
                      ((uint32_t)f2bf(fmaxf(v[1] + b1, 0.f)) << 16);
        uint32_t hi = (uint32_t)f2bf(fmaxf(v[2] + b2, 0.f)) |
                      ((uint32_t)f2bf(fmaxf(v[3] + b3, 0.f)) << 16);
        W[col * 64 + (jj ^ (col & 31))] = lo;
        W[col * 64 + ((jj + 1) ^ (col & 31))] = hi;
      }
    }
    __syncthreads();
    if (tid < 128) {
      int col = tid & 63, sel = tid >> 6;
      int gcol = col0 + col;
      float sum = b2d[sel];
      const uint32_t* Wc = W + col * 64;
      const float* wd = w2d + sel * 128;
      #pragma unroll 8
      for (int c = 0; c < 64; ++c) {
        uint32_t v = Wc[c ^ (col & 31)];
        sum += wd[2 * c] * bf2f((u16)(v & 0xffffu)) + wd[2 * c + 1] * bf2f((u16)(v >> 16));
      }
      int b = gcol / 10000, pidx = gcol - b * 10000;
      out[((size_t)b * 2 + sel) * 10000 + pidx] = sigmoidf_(sum);
    }
  }
}

// ---------- launch ----------
extern "C" void kernel_launch(void* const* d_in, const int* in_sizes, int n_in, void* d_out,
                              int out_size, void* d_ws, size_t ws_size, hipStream_t stream) {
  const float* inputs = (const float*)d_in[0];
  const float* w_b1 = (const float*)d_in[1];
  const float* b_b1 = (const float*)d_in[2];
  const float* w_b2 = (const float*)d_in[3];
  const float* b_b2 = (const float*)d_in[4];
  const float* w_s1 = (const float*)d_in[5];
  const float* b_s1 = (const float*)d_in[6];
  const float* w_s2 = (const float*)d_in[7];
  const float* b_s2 = (const float*)d_in[8];
  const float* w_e1 = (const float*)d_in[9];
  const float* b_e1 = (const float*)d_in[10];
  const float* w_e2 = (const float*)d_in[11];
  const float* b_e2 = (const float*)d_in[12];
  const float* w_p1 = (const float*)d_in[13];
  const float* b_p1 = (const float*)d_in[14];
  const float* w3d = (const float*)d_in[15];
  const float* b3d = (const float*)d_in[16];
  const float* w2a = (const float*)d_in[17];
  const float* b2a = (const float*)d_in[18];
  const float* w2b = (const float*)d_in[19];
  const float* b2b = (const float*)d_in[20];
  const float* w2c = (const float*)d_in[21];
  const float* b2c = (const float*)d_in[22];
  const float* w2d = (const float*)d_in[23];
  const float* b2d = (const float*)d_in[24];
  float* out = (float*)d_out;
  char* ws = (char*)d_ws;

  int* tinfo = (int*)(ws + 0);
  int* order = (int*)(ws + 2048);
  u16* zp = (u16*)(ws + 16384);
  int* invperm = (int*)(ws + 45056);
  float* base1 = (float*)(ws + 90112);          // 409600
  float* base = (float*)(ws + 499712);          // 409600
  float* s1buf = (float*)(ws + 909312);         // 409600
  u16* Pt = (u16*)(ws + 1318912);               // 102400
  u16* w2a_bf = (u16*)(ws + 1421312);           // 131072
  u16* w2b_pk = (u16*)(ws + 1552384);           // 294912
  u16* w2c_pk = (u16*)(ws + 1847296);           // 294912
  u16* Qb = (u16*)(ws + 2142208);               // 13107200 (ends 15249408)
  u16* Mt = (u16*)(ws + 15249408);              // rows 0..5119 used -> ends 48017408
  float* e1buf = (float*)(ws + 48017408);       // 409600, in Mt-region free tail (no alias!)
  u16* C1t = (u16*)(ws + 79249408);             // 40960000  (end 120209408)
  u16* Wq = (u16*)(ws + 79249408);              // aliases C1t: dead before G1 writes C1t
  u16* x2t = Qb;   // alias: Qb dead after G1
  u16* x3t = C1t;  // alias: C1t dead after G2

  // 1) fused prep: conv1 first (overlaps), weight casts, invperm, tile spans, mask rows
  prep_fused<<<3641, 256, 0, stream>>>(w2a, w2b, w2c, w2a_bf, w2b_pk, w2c_pk, w3d, Wq,
                                       invperm, tinfo, order, zp, Mt, inputs, w_b1, b_b1,
                                       base1);

  // 2-3) front end (fp32 exact; p-branch ic-split 4-way for occupancy)
  conv1d_k3v<<<100, 256, 0, stream>>>(base1, w_b2, b_b2, base, 256, 64, 64, 256);
  branch_split<<<400, 256, 0, stream>>>(base, w_s1, b_s1, w_e1, b_e1, w_p1, b_p1,
                                        s1buf, e1buf, Pt);

  // 4) qprep GEMM [16384 x 400 x 128] + fused start/end sigmoid heads
  qprep_sig<<<dim3(129, 4), 256, 0, stream>>>(Wq, Pt, Qb, s1buf, e1buf, w_s2, b_s2,
                                              w_e2, b_e2, out);

  // 5) G1: out3d, 128x128 tiles, longest-first; de-permuted coalesced store into C1t
  gemm_bt<<<dim3(16, 79), 256, 0, stream>>>(Qb, Mt, C1t, b3d, 10000, 3200, tinfo, order, 50,
                                            512, 10000LL, 10000, invperm);
  // 6) G2: 1x1 conv 512->128, 64-col tiles (625 blocks, tail-balanced)
  gemm_bt64<<<625, 256, 0, stream>>>(w2a_bf, C1t, x2t, b2a);
  // 7) G3: 3x3 conv 128->128, 64-col tiles
  conv3x3_gemm64<0><<<625, 256, 0, stream>>>(w2b_pk, x2t, x3t, b2b, zp, nullptr, nullptr,
                                             nullptr);
  // 8) G4: 3x3 conv 128->128 + fused conf head, 64-col tiles
  conv3x3_gemm64<1><<<625, 256, 0, stream>>>(w2c_pk, x3t, nullptr, b2c, zp, w2d, b2d,
                                             out);
}

// Round 19
// 214.473 us; speedup vs baseline: 1.2471x; 1.0408x over previous
//
#include <hip/hip_runtime.h>
#include <cstdint>
#include <cstddef>
#include <math.h>

typedef unsigned short u16;
typedef short bf16x8 __attribute__((ext_vector_type(8)));
typedef float f32x4 __attribute__((ext_vector_type(4)));

// ---------- helpers ----------
__device__ __forceinline__ u16 f2bf(float f) {
  union { float f; uint32_t u; } c; c.f = f;
  uint32_t u = c.u;
  return (u16)((u + 0x7FFFu + ((u >> 16) & 1u)) >> 16);
}
__device__ __forceinline__ float bf2f(u16 h) {
  union { uint32_t u; float f; } c; c.u = ((uint32_t)h) << 16;
  return c.f;
}
__device__ __forceinline__ float sigmoidf_(float x) { return 1.f / (1.f + expf(-x)); }

__device__ __forceinline__ void glds16(const void* g, void* l) {
  __builtin_amdgcn_global_load_lds((const __attribute__((address_space(1))) void*)g,
                                   (__attribute__((address_space(3))) void*)l, 16, 0, 0);
}

// column permutation: valid (s<=e) pairs compacted in natural order, invalid at end
__device__ __forceinline__ int col_rank(int p) {
  int s = p / 100, e = p - s * 100;
  int tri = (s * (s - 1)) >> 1;
  return (e >= s) ? (p - tri - s) : (5050 + tri + e);
}

// ---------- conv2: 256->256 grouped k=3, 4-way ic-split reduction (fp32 exact) ----------
__global__ void conv2_r(const float* __restrict__ in, const float* __restrict__ w,
                        const float* __restrict__ bias, float* __restrict__ out) {
  int u = blockIdx.x * 256 + threadIdx.x;   // 102400
  int r = u & 3;
  int quad = u >> 2;
  int sub = quad % 25;
  int tmp = quad / 25;
  int oc = tmp & 255;
  int bb = tmp >> 8;
  int t4 = sub * 4;
  int g = oc >> 6;
  const float* ip = in + ((size_t)bb * 256 + g * 64 + r * 16) * 100 + t4;
  const float* wp = w + (size_t)oc * 192 + r * 48;
  float s0 = 0.f, s1 = 0.f, s2 = 0.f, s3 = 0.f;
  #pragma unroll 4
  for (int i = 0; i < 16; ++i) {
    const float* rr = ip + (size_t)i * 100;
    float4 a = *(const float4*)rr;
    float xm = (t4 > 0) ? rr[-1] : 0.f;
    float xp = (t4 < 96) ? rr[4] : 0.f;
    float w0 = wp[i * 3 + 0], w1 = wp[i * 3 + 1], w2 = wp[i * 3 + 2];
    s0 += w0 * xm + w1 * a.x + w2 * a.y;
    s1 += w0 * a.x + w1 * a.y + w2 * a.z;
    s2 += w0 * a.y + w1 * a.z + w2 * a.w;
    s3 += w0 * a.z + w1 * a.w + w2 * xp;
  }
  s0 += __shfl_xor(s0, 1); s0 += __shfl_xor(s0, 2);
  s1 += __shfl_xor(s1, 1); s1 += __shfl_xor(s1, 2);
  s2 += __shfl_xor(s2, 1); s2 += __shfl_xor(s2, 2);
  s3 += __shfl_xor(s3, 1); s3 += __shfl_xor(s3, 2);
  if (r == 0) {
    float b = bias[oc];
    float4 o;
    o.x = fmaxf(s0 + b, 0.f); o.y = fmaxf(s1 + b, 0.f);
    o.z = fmaxf(s2 + b, 0.f); o.w = fmaxf(s3 + b, 0.f);
    *(float4*)(out + ((size_t)bb * 256 + oc) * 100 + t4) = o;
  }
}

// fused s1/e1/p branches; s/e full-reduction, p-part 4-way ic-split
__global__ void branch_split(const float* __restrict__ in, const float* __restrict__ wS,
                             const float* __restrict__ bS, const float* __restrict__ wE,
                             const float* __restrict__ bE, const float* __restrict__ wP,
                             const float* __restrict__ bP, float* __restrict__ outS,
                             float* __restrict__ outE, u16* __restrict__ Pt) {
  int idx = blockIdx.x * 256 + threadIdx.x;
  if (idx < 51200) {
    int sub = idx % 25;
    int tmp = idx / 25;
    int ocx = tmp & 511;
    int bb = tmp >> 9;
    int t4 = sub * 4;
    int sel = ocx >> 8;
    int oc = ocx & 255;
    const float* w = sel ? wE : wS;
    const float* bias = sel ? bE : bS;
    int g = oc >> 6;
    const float* ip = in + ((size_t)bb * 256 + (size_t)g * 64) * 100 + t4;
    const float* wp = w + (size_t)oc * 192;
    float bs = bias[oc];
    float s0 = bs, s1 = bs, s2 = bs, s3 = bs;
    #pragma unroll 4
    for (int ic = 0; ic < 64; ++ic) {
      const float* r = ip + (size_t)ic * 100;
      float4 a = *(const float4*)r;
      float xm = (t4 > 0) ? r[-1] : 0.f;
      float xp = (t4 < 96) ? r[4] : 0.f;
      float w0 = wp[ic * 3 + 0], w1 = wp[ic * 3 + 1], w2 = wp[ic * 3 + 2];
      s0 += w0 * xm + w1 * a.x + w2 * a.y;
      s1 += w0 * a.x + w1 * a.y + w2 * a.z;
      s2 += w0 * a.y + w1 * a.z + w2 * a.w;
      s3 += w0 * a.z + w1 * a.w + w2 * xp;
    }
    float* out = sel ? outE : outS;
    float4 o;
    o.x = fmaxf(s0, 0.f); o.y = fmaxf(s1, 0.f);
    o.z = fmaxf(s2, 0.f); o.w = fmaxf(s3, 0.f);
    *(float4*)(out + ((size_t)bb * 256 + oc) * 100 + t4) = o;
  } else {
    int j = idx - 51200;
    int r = j & 3;
    int quad = j >> 2;
    int sub = quad % 25;
    int tmp = quad / 25;
    int oc = tmp & 127;
    int bb = tmp >> 7;
    int t4 = sub * 4;
    const float* wp = wP + (size_t)oc * 768 + r * 192;
    const float* ip = in + ((size_t)bb * 256 + r * 64) * 100 + t4;
    float s0 = 0.f, s1 = 0.f, s2 = 0.f, s3 = 0.f;
    #pragma unroll 4
    for (int i = 0; i < 64; ++i) {
      const float* rr = ip + (size_t)i * 100;
      float4 a = *(const float4*)rr;
      float xm = (t4 > 0) ? rr[-1] : 0.f;
      float xp = (t4 < 96) ? rr[4] : 0.f;
      float w0 = wp[i * 3 + 0], w1 = wp[i * 3 + 1], w2 = wp[i * 3 + 2];
      s0 += w0 * xm + w1 * a.x + w2 * a.y;
      s1 += w0 * a.x + w1 * a.y + w2 * a.z;
      s2 += w0 * a.y + w1 * a.z + w2 * a.w;
      s3 += w0 * a.z + w1 * a.w + w2 * xp;
    }
    s0 += __shfl_xor(s0, 1); s0 += __shfl_xor(s0, 2);
    s1 += __shfl_xor(s1, 1); s1 += __shfl_xor(s1, 2);
    s2 += __shfl_xor(s2, 1); s2 += __shfl_xor(s2, 2);
    s3 += __shfl_xor(s3, 1); s3 += __shfl_xor(s3, 2);
    if (r == 0) {
      float b = bP[oc];
      Pt[((size_t)bb * 100 + t4 + 0) * 128 + oc] = f2bf(fmaxf(s0 + b, 0.f));
      Pt[((size_t)bb * 100 + t4 + 1) * 128 + oc] = f2bf(fmaxf(s1 + b, 0.f));
      Pt[((size_t)bb * 100 + t4 + 2) * 128 + oc] = f2bf(fmaxf(s2 + b, 0.f));
      Pt[((size_t)bb * 100 + t4 + 3) * 128 + oc] = f2bf(fmaxf(s3 + b, 0.f));
    }
  }
}

// ---------- fused prep; conv1 FIRST (bids 0-399, 4-way ic-split), mask rows 2/block ----------
__global__ void prep_fused(const float* __restrict__ w2a, const float* __restrict__ w2b,
                           const float* __restrict__ w2c, u16* __restrict__ w2a_bf,
                           u16* __restrict__ w2b_pk, u16* __restrict__ w2c_pk,
                           const float* __restrict__ w3d, u16* __restrict__ Wq,
                           int* __restrict__ invperm, int* __restrict__ tinfo,
                           int* __restrict__ order, u16* __restrict__ zp,
                           u16* __restrict__ Mt, const float* __restrict__ inputs,
                           const float* __restrict__ w_b1, const float* __restrict__ b_b1,
                           float* __restrict__ base1) {
  __shared__ __align__(16) u16 ML[2 * 3200];   // 12.8 KB: 2 mask rows
  __shared__ int C[128];
  int bid = blockIdx.x, tid = threadIdx.x;
  if (bid < 400) {
    int u = bid * 256 + tid;
    int r = u & 3;
    int quad = u >> 2;
    int sub = quad % 25;
    int tmp = quad / 25;
    int oc = tmp & 255;
    int bb = tmp >> 8;
    int t4 = sub * 4;
    int g = oc >> 6;
    const float* ip = inputs + ((size_t)bb * 400 + g * 100 + r * 25) * 100 + t4;
    const float* wp = w_b1 + (size_t)oc * 300 + r * 75;
    float s0 = 0.f, s1 = 0.f, s2 = 0.f, s3 = 0.f;
    #pragma unroll 5
    for (int i = 0; i < 25; ++i) {
      const float* rr = ip + (size_t)i * 100;
      float4 a = *(const float4*)rr;
      float xm = (t4 > 0) ? rr[-1] : 0.f;
      float xp = (t4 < 96) ? rr[4] : 0.f;
      float w0 = wp[i * 3 + 0], w1 = wp[i * 3 + 1], w2 = wp[i * 3 + 2];
      s0 += w0 * xm + w1 * a.x + w2 * a.y;
      s1 += w0 * a.x + w1 * a.y + w2 * a.z;
      s2 += w0 * a.y + w1 * a.z + w2 * a.w;
      s3 += w0 * a.z + w1 * a.w + w2 * xp;
    }
    s0 += __shfl_xor(s0, 1); s0 += __shfl_xor(s0, 2);
    s1 += __shfl_xor(s1, 1); s1 += __shfl_xor(s1, 2);
    s2 += __shfl_xor(s2, 1); s2 += __shfl_xor(s2, 2);
    s3 += __shfl_xor(s3, 1); s3 += __shfl_xor(s3, 2);
    if (r == 0) {
      float b = b_b1[oc];
      float4 o;
      o.x = fmaxf(s0 + b, 0.f); o.y = fmaxf(s1 + b, 0.f);
      o.z = fmaxf(s2 + b, 0.f); o.w = fmaxf(s3 + b, 0.f);
      *(float4*)(base1 + ((size_t)bb * 256 + oc) * 100 + t4) = o;
    }
  } else if (bid < 976) {
    int i = (bid - 400) * 256 + tid;
    if (i < 65536) w2a_bf[i] = f2bf(w2a[i]);
    if (i < 147456) {
      int oc = i / 1152, r = i % 1152, kk = r >> 7, ic = r & 127;
      int src = (oc * 128 + ic) * 9 + kk;
      w2b_pk[i] = f2bf(w2b[src]);
      w2c_pk[i] = f2bf(w2c[src]);
    }
  } else if (bid < 1040) {
    int u = (bid - 976) * 256 + tid;
    int o = u >> 5, n = u & 31;
    const float* src = w3d + (size_t)o * 4096 + n;
    u16* dst = Wq + (size_t)u * 128;
    for (int c0 = 0; c0 < 128; c0 += 8) {
      __align__(16) u16 h[8];
      #pragma unroll
      for (int j = 0; j < 8; ++j) h[j] = f2bf(src[(size_t)(c0 + j) * 32]);
      *(uint4*)(dst + c0) = *(const uint4*)h;
    }
  } else if (bid < 1080) {
    int p = (bid - 1040) * 256 + tid;
    if (p < 10000) invperm[col_rank(p)] = p;
  } else if (bid == 1080) {
    if (tid < 128) zp[tid] = 0;
    int t = tid;
    int kbmin = 0, cnt = 0;
    if (t < 79) {
      int rlo = t * 128;
      int rhi = rlo + 128;
      if (rhi > 5050) rhi = 5050;
      if (rlo < 5050) {
        int s = 0;
        while (100 * (s + 1) - ((s + 1) * s) / 2 <= rlo) ++s;
        int cum = 100 * s - (s * (s - 1)) / 2;
        int tmin = 100, tmax = -1;
        for (int r = rlo; r < rhi; ++r) {
          while (r - cum >= 100 - s) { ++s; cum = 100 * s - (s * (s - 1)) / 2; }
          int e = s + (r - cum);
          float L = (float)(e - s + 2);
          float sp2 = (float)s - 0.5f * L;
          float ep2 = (float)(e + 1) + 0.5f * L;
          int a = (int)floorf(sp2) - 1;
          if (a < 0) a = 0;
          int b = (int)floorf(ep2) + 2;
          if (b > 99) b = 99;
          if (a < tmin) tmin = a;
          if (b > tmax) tmax = b;
        }
        kbmin = tmin >> 1;
        cnt = (tmax >> 1) - kbmin + 1;
      }
      tinfo[2 * t] = kbmin;
      tinfo[2 * t + 1] = cnt;
    }
    if (t < 128) C[t] = (t < 79) ? cnt : -1;
    __syncthreads();
    if (t < 79) {
      int pos = 0;
      int ct = C[t];
      for (int u = 0; u < 79; ++u) {
        int cu = C[u];
        pos += (cu > ct) || (cu == ct && u < t);
      }
      order[pos] = t;
    }
  } else {
    int r0 = (bid - 1081) * 2;
    uint32_t* MZ = (uint32_t*)ML;
    for (int i = tid; i < 3200; i += 256) MZ[i] = 0;
    __syncthreads();
    int g = tid >> 6, lane = tid & 63;
    int r = r0 + g;
    if (g < 2 && r < 5050 && lane < 32) {
      int n = lane;
      int s = (int)((201.0 - sqrt((double)(40401 - 8 * r))) * 0.5);
      if (s < 0) s = 0;
      while (s * (201 - s) / 2 > r) --s;
      while ((s + 1) * (200 - s) / 2 <= r) ++s;
      int e = s + (r - s * (201 - s) / 2);
      double sp = (double)s, ep = (double)(e + 1);
      double L = ep - sp + 1.0;
      double sp2 = sp - L * 0.5;
      double ep2 = ep + L * 0.5;
      double step = (ep2 - sp2) / 95.0;
      double win[8];
      #pragma unroll
      for (int k = 0; k < 8; ++k) win[k] = 0.0;
      int base = -1;
      #pragma unroll
      for (int jj = 0; jj < 3; ++jj) {
        double pos = sp2 + step * (double)(n * 3 + jj);
        double ip;
        double fr = modf(pos, &ip);
        int it = (int)ip;
        if (it >= 0 && it < 99) {
          if (base < 0) base = it;
          int off = it - base;
          win[off] += (1.0 - fr) / 3.0;
          win[off + 1] += fr / 3.0;
        }
      }
      if (base >= 0) {
        u16* dst = ML + g * 3200 + n;
        #pragma unroll
        for (int k = 0; k < 8; ++k) {
          int t = base + k;
          if (t < 100) dst[t * 32] = f2bf((float)win[k]);
        }
      }
    }
    __syncthreads();
    for (int i = tid; i < 800; i += 256) {
      int rl = i / 400, off = i - rl * 400;
      *(uint4*)(Mt + (size_t)(r0 + rl) * 3200 + off * 8) = ((const uint4*)ML)[i];
    }
  }
}

// ---------- shared MFMA pieces (T2 XOR-swizzled reads; sources pre-swizzled) ----------
template<int MI>
__device__ __forceinline__ void mfma_stepT(const u16* As, const u16* Bs, int l, int wm, int wn,
                                           f32x4 (&acc)[MI][4]) {
  int m15 = l & 15, q = l >> 4, sw = m15 & 7;
  #pragma unroll
  for (int kk = 0; kk < 2; ++kk) {
    int koff = ((kk * 4 + q) ^ sw) * 8;
    bf16x8 av[MI], bv[4];
    #pragma unroll
    for (int i = 0; i < MI; ++i)
      av[i] = *(const bf16x8*)(As + (size_t)(wm * (MI * 16) + i * 16 + m15) * 64 + koff);
    #pragma unroll
    for (int j = 0; j < 4; ++j)
      bv[j] = *(const bf16x8*)(Bs + (size_t)(wn * 64 + j * 16 + m15) * 64 + koff);
    #pragma unroll
    for (int i = 0; i < MI; ++i) {
      #pragma unroll
      for (int j = 0; j < 4; ++j)
        acc[i][j] = __builtin_amdgcn_mfma_f32_16x16x32_bf16(av[i], bv[j], acc[i][j], 0, 0, 0);
    }
  }
}

// 64-col variant: waves 2(M)x2(N), acc 64 rows x 32 cols per wave
__device__ __forceinline__ void mfma_step64(const u16* As, const u16* Bs, int l, int wm, int wn,
                                            f32x4 (&acc)[4][2]) {
  int m15 = l & 15, q = l >> 4, sw = m15 & 7;
  #pragma unroll
  for (int kk = 0; kk < 2; ++kk) {
    int koff = ((kk * 4 + q) ^ sw) * 8;
    bf16x8 av[4], bv[2];
    #pragma unroll
    for (int i = 0; i < 4; ++i)
      av[i] = *(const bf16x8*)(As + (size_t)(wm * 64 + i * 16 + m15) * 64 + koff);
    #pragma unroll
    for (int j = 0; j < 2; ++j)
      bv[j] = *(const bf16x8*)(Bs + (size_t)(wn * 32 + j * 16 + m15) * 64 + koff);
    #pragma unroll
    for (int i = 0; i < 4; ++i) {
      #pragma unroll
      for (int j = 0; j < 2; ++j)
        acc[i][j] = __builtin_amdgcn_mfma_f32_16x16x32_bf16(av[i], bv[j], acc[i][j], 0, 0, 0);
    }
  }
}

// ---------- coalesced epilogue (128-col tiles) ----------
__device__ __forceinline__ void epilogue_coal(f32x4 (&acc)[4][4], u16* SH, u16* OUT,
                                              const float* bias, int row0, int col0, int tid,
                                              int l, int wm, int wn, int N, int OC,
                                              long long NPB, const int* colmap) {
  uint32_t* W = (uint32_t*)SH;
  int r4 = (l >> 4) * 4, c1 = l & 15;
  int bb0 = row0 % OC;
  #pragma unroll
  for (int i = 0; i < 4; ++i) {
    int ob = wm * 64 + i * 16 + r4;
    float b0 = bias[bb0 + ob + 0], b1 = bias[bb0 + ob + 1];
    float b2 = bias[bb0 + ob + 2], b3 = bias[bb0 + ob + 3];
    int jj = ob >> 1;
    #pragma unroll
    for (int j = 0; j < 4; ++j) {
      int col = wn * 64 + j * 16 + c1;
      f32x4 v = acc[i][j];
      uint32_t lo = (uint32_t)f2bf(fmaxf(v[0] + b0, 0.f)) |
                    ((uint32_t)f2bf(fmaxf(v[1] + b1, 0.f)) << 16);
      uint32_t hi = (uint32_t)f2bf(fmaxf(v[2] + b2, 0.f)) |
                    ((uint32_t)f2bf(fmaxf(v[3] + b3, 0.f)) << 16);
      W[col * 64 + (jj ^ (col & 31))] = lo;
      W[col * 64 + ((jj + 1) ^ (col & 31))] = hi;
    }
  }
  __syncthreads();
  int col = tid >> 1, half = tid & 1;
  int gcol = col0 + col;
  if (gcol < N) {
    int pcol = colmap ? colmap[gcol] : gcol;
    const uint32_t* Wc = W + col * 64;
    __align__(16) uint32_t tbuf[32];
    #pragma unroll
    for (int k = 0; k < 32; ++k) tbuf[k] = Wc[(half * 32 + k) ^ (col & 31)];
    u16* dst = OUT + (size_t)(row0 / OC) * (size_t)OC * (size_t)NPB + (size_t)pcol * OC +
               bb0 + half * 64;
    #pragma unroll
    for (int q = 0; q < 8; ++q) *(uint4*)(dst + q * 8) = *(const uint4*)(tbuf + q * 4);
  }
}

// 64-col coalesced epilogue: 128 ch x 64 cols, OUT[(col)][128]
__device__ __forceinline__ void epilogue_coal64(f32x4 (&acc)[4][2], u16* SH, u16* OUT,
                                                const float* bias, int col0, int tid, int l,
                                                int wm, int wn) {
  uint32_t* W = (uint32_t*)SH;
  int r4 = (l >> 4) * 4, c1 = l & 15;
  #pragma unroll
  for (int i = 0; i < 4; ++i) {
    int ob = wm * 64 + i * 16 + r4;
    float b0 = bias[ob + 0], b1 = bias[ob + 1], b2 = bias[ob + 2], b3 = bias[ob + 3];
    int jj = ob >> 1;
    #pragma unroll
    for (int j = 0; j < 2; ++j) {
      int col = wn * 32 + j * 16 + c1;
      f32x4 v = acc[i][j];
      uint32_t lo = (uint32_t)f2bf(fmaxf(v[0] + b0, 0.f)) |
                    ((uint32_t)f2bf(fmaxf(v[1] + b1, 0.f)) << 16);
      uint32_t hi = (uint32_t)f2bf(fmaxf(v[2] + b2, 0.f)) |
                    ((uint32_t)f2bf(fmaxf(v[3] + b3, 0.f)) << 16);
      W[col * 64 + (jj ^ (col & 31))] = lo;
      W[col * 64 + ((jj + 1) ^ (col & 31))] = hi;
    }
  }
  __syncthreads();
  if (tid < 128) {
    int col = tid >> 1, half = tid & 1;
    const uint32_t* Wc = W + col * 64;
    __align__(16) uint32_t tbuf[32];
    #pragma unroll
    for (int k = 0; k < 32; ++k) tbuf[k] = Wc[(half * 32 + k) ^ (col & 31)];
    u16* dst = OUT + (size_t)(col0 + col) * 128 + half * 64;
    #pragma unroll
    for (int q = 0; q < 8; ++q) *(uint4*)(dst + q * 8) = *(const uint4*)(tbuf + q * 4);
  }
}

// ---------- generic BT-GEMM (128-col); used for G1 ----------
__global__ __launch_bounds__(256, 2) void gemm_bt(const u16* __restrict__ A,
                                                  const u16* __restrict__ B,
                                                  u16* __restrict__ OUT,
                                                  const float* __restrict__ bias, int N, int K,
                                                  const int* __restrict__ tinfo,
                                                  const int* __restrict__ order, int kblocks,
                                                  int OC, long long NPB, int NclampB,
                                                  const int* __restrict__ colmap) {
  __shared__ __align__(16) u16 SH[2 * 128 * 64];
  u16* As = SH;
  u16* Bs = SH + 128 * 64;
  int mt = blockIdx.x;
  int nt = order ? order[blockIdx.y] : blockIdx.y;
  int col0 = nt * 128, row0 = mt * 128;
  int tid = threadIdx.x, w = tid >> 6, l = tid & 63;
  int wm = w >> 1, wn = w & 1;
  int lr = l >> 3;
  int lk_sw = ((l & 7) ^ lr) * 8;
  f32x4 acc[4][4] = {};
  size_t aoff[4];
  size_t boff[4];
  #pragma unroll
  for (int r = 0; r < 4; ++r) {
    int chunk = r * 4 + w;
    int rowA = row0 + chunk * 8 + lr;
    aoff[r] = (size_t)rowA * K + lk_sw;
    int colB = col0 + chunk * 8 + lr;
    if (colB >= NclampB) colB = NclampB - 1;
    boff[r] = (size_t)colB * K + lk_sw;
  }
  int kbmin = 0, cnt = kblocks;
  if (tinfo) { kbmin = tinfo[2 * nt]; cnt = tinfo[2 * nt + 1]; }
  for (int i = 0; i < cnt; ++i) {
    int k0 = (kbmin + i) * 64;
    #pragma unroll
    for (int r = 0; r < 4; ++r) {
      int chunk = r * 4 + w;
      glds16(A + aoff[r] + k0, As + chunk * 512);
      glds16(B + boff[r] + k0, Bs + chunk * 512);
    }
    __syncthreads();
    mfma_stepT<4>(As, Bs, l, wm, wn, acc);
    __syncthreads();
  }
  epilogue_coal(acc, SH, OUT, bias, row0, col0, tid, l, wm, wn, N, OC, NPB, colmap);
}

// ---------- 64-col BT-GEMM; used for G2 (K=512, M=128) ----------
__global__ __launch_bounds__(256, 2) void gemm_bt64(const u16* __restrict__ A,
                                                    const u16* __restrict__ B,
                                                    u16* __restrict__ OUT,
                                                    const float* __restrict__ bias) {
  __shared__ __align__(16) u16 SH[128 * 64 + 64 * 64];   // 24KB
  u16* As = SH;
  u16* Bs = SH + 128 * 64;
  int col0 = blockIdx.x * 64;
  int tid = threadIdx.x, w = tid >> 6, l = tid & 63;
  int wm = w >> 1, wn = w & 1;
  int lr = l >> 3;
  int lk_sw = ((l & 7) ^ lr) * 8;
  f32x4 acc[4][2] = {};
  size_t aoff[4], boff[2];
  #pragma unroll
  for (int r = 0; r < 4; ++r) {
    int chunk = r * 4 + w;
    aoff[r] = (size_t)(chunk * 8 + lr) * 512 + lk_sw;
  }
  #pragma unroll
  for (int r = 0; r < 2; ++r) {
    int chunk = r * 4 + w;
    boff[r] = (size_t)(col0 + chunk * 8 + lr) * 512 + lk_sw;
  }
  for (int kb = 0; kb < 8; ++kb) {
    int k0 = kb * 64;
    #pragma unroll
    for (int r = 0; r < 4; ++r)
      glds16(A + aoff[r] + k0, As + (r * 4 + w) * 512);
    #pragma unroll
    for (int r = 0; r < 2; ++r)
      glds16(B + boff[r] + k0, Bs + (r * 4 + w) * 512);
    __syncthreads();
    mfma_step64(As, Bs, l, wm, wn, acc);
    __syncthreads();
  }
  epilogue_coal64(acc, SH, OUT, bias, col0, tid, l, wm, wn);
}

// ---------- qprep as MFMA GEMM + fused start/end sigmoid heads ----------
__global__ __launch_bounds__(256, 2) void qprep_sig(const u16* __restrict__ Wq,
                                                    const u16* __restrict__ Pt,
                                                    u16* __restrict__ Qb,
                                                    const float* __restrict__ s1,
                                                    const float* __restrict__ e1,
                                                    const float* __restrict__ ws2,
                                                    const float* __restrict__ bs2,
                                                    const float* __restrict__ we2,
                                                    const float* __restrict__ be2,
                                                    float* __restrict__ out) {
  if (blockIdx.x == 128) {
    int t = threadIdx.x & 127;
    int sel = threadIdx.x >> 7;
    int bb = blockIdx.y;
    if (t >= 100) return;
    const float* in = sel ? e1 : s1;
    const float* w = sel ? we2 : ws2;
    float s = sel ? be2[0] : bs2[0];
    #pragma unroll 8
    for (int c = 0; c < 256; ++c) s += w[c] * in[((size_t)bb * 256 + c) * 100 + t];
    out[80000 + sel * 400 + bb * 100 + t] = sigmoidf_(s);
    return;
  }
  __shared__ __align__(16) u16 As[128 * 64];
  __shared__ __align__(16) u16 Bs[128 * 64];
  int mt = blockIdx.x, nt = blockIdx.y;
  int col0 = nt * 128, row0 = mt * 128;
  int tid = threadIdx.x, w = tid >> 6, l = tid & 63;
  int wm = w >> 1, wn = w & 1;
  int lr = l >> 3;
  int lk_sw = ((l & 7) ^ lr) * 8;
  f32x4 acc[4][4] = {};
  size_t aoff[4];
  size_t boff[4];
  #pragma unroll
  for (int r = 0; r < 4; ++r) {
    int chunk = r * 4 + w;
    int rowA = row0 + chunk * 8 + lr;
    aoff[r] = (size_t)rowA * 128 + lk_sw;
    int colB = col0 + chunk * 8 + lr;
    if (colB >= 400) colB = 399;
    boff[r] = (size_t)colB * 128 + lk_sw;
  }
  #pragma unroll
  for (int kb = 0; kb < 2; ++kb) {
    int k0 = kb * 64;
    #pragma unroll
    for (int r = 0; r < 4; ++r) {
      int chunk = r * 4 + w;
      glds16(Wq + aoff[r] + k0, As + chunk * 512);
      glds16(Pt + boff[r] + k0, Bs + chunk * 512);
    }
    __syncthreads();
    mfma_stepT<4>(As, Bs, l, wm, wn, acc);
    __syncthreads();
  }
  int r4 = (l >> 4) * 4, c1 = l & 15;
  #pragma unroll
  for (int i = 0; i < 4; ++i) {
    int row = row0 + wm * 64 + i * 16 + r4;
    int o = row >> 5, n = row & 31;
    #pragma unroll
    for (int j = 0; j < 4; ++j) {
      int col = col0 + wn * 64 + j * 16 + c1;
      if (col < 400) {
        int b = col / 100, t = col - b * 100;
        f32x4 v = acc[i][j];
        __align__(8) u16 h[4];
        h[0] = f2bf(v[0]);
        h[1] = f2bf(v[1]);
        h[2] = f2bf(v[2]);
        h[3] = f2bf(v[3]);
        *(uint2*)(Qb + ((size_t)(b * 512 + o)) * 3200 + t * 32 + n) = *(const uint2*)h;
      }
    }
  }
}

// ---------- 64-col 3x3 conv as shifted BT-GEMM; FUSE=1 fuses conf head ----------
template<int FUSE>
__global__ __launch_bounds__(256, 2) void conv3x3_gemm64(const u16* __restrict__ Apk,
                                                         const u16* __restrict__ X,
                                                         u16* __restrict__ OUT,
                                                         const float* __restrict__ bias,
                                                         const u16* __restrict__ zp,
                                                         const float* __restrict__ w2d,
                                                         const float* __restrict__ b2d,
                                                         float* __restrict__ out) {
  __shared__ __align__(16) u16 SH[128 * 64 + 64 * 64];   // As 16KB + Bs 8KB
  u16* As = SH;
  u16* Bs = SH + 128 * 64;
  int col0 = blockIdx.x * 64;
  int tid = threadIdx.x, w = tid >> 6, l = tid & 63;
  int wm = w >> 1, wn = w & 1;
  int lr = l >> 3;
  int lk_sw = ((l & 7) ^ lr) * 8;
  int cj[2], yy[2], xx[2];
  size_t aoff[4];
  #pragma unroll
  for (int r = 0; r < 4; ++r) {
    int chunk = r * 4 + w;
    aoff[r] = (size_t)(chunk * 8 + lr) * 1152 + lk_sw;
  }
  #pragma unroll
  for (int r = 0; r < 2; ++r) {
    int chunk = r * 4 + w;
    int c = col0 + chunk * 8 + lr;
    cj[r] = c;
    int p = c % 10000;
    yy[r] = p / 100;
    xx[r] = p % 100;
  }
  f32x4 acc[4][2] = {};
  for (int s = 0; s < 9; ++s) {
    int dy = s / 3 - 1, dx = s % 3 - 1;
    int doff = dy * 100 + dx;
    #pragma unroll
    for (int half = 0; half < 2; ++half) {
      int k0 = s * 128 + half * 64;
      int c0 = half * 64;
      #pragma unroll
      for (int r = 0; r < 4; ++r)
        glds16(Apk + aoff[r] + k0, As + (r * 4 + w) * 512);
      #pragma unroll
      for (int r = 0; r < 2; ++r) {
        int y2 = yy[r] + dy, x2 = xx[r] + dx;
        bool ok = ((unsigned)y2 < 100u) && ((unsigned)x2 < 100u);
        const u16* src = ok ? (X + (size_t)(cj[r] + doff) * 128 + c0 + lk_sw) : zp;
        glds16(src, Bs + (r * 4 + w) * 512);
      }
      __syncthreads();
      mfma_step64(As, Bs, l, wm, wn, acc);
      __syncthreads();
    }
  }
  if (FUSE == 0) {
    epilogue_coal64(acc, SH, OUT, bias, col0, tid, l, wm, wn);
  } else {
    uint32_t* W = (uint32_t*)SH;
    int r4 = (l >> 4) * 4, c1 = l & 15;
    #pragma unroll
    for (int i = 0; i < 4; ++i) {
      int ob = wm * 64 + i * 16 + r4;
      float b0 = bias[ob + 0], b1 = bias[ob + 1], b2 = bias[ob + 2], b3 = bias[ob + 3];
      int jj = ob >> 1;
      #pragma unroll
      for (int j = 0; j < 2; ++j) {
        int col = wn * 32 + j * 16 + c1;
        f32x4 v = acc[i][j];
        uint32_t lo = (uint32_t)f2bf(fmaxf(v[0] + b0, 0.f)) |
                      ((uint32_t)f2bf(fmaxf(v[1] + b1, 0.f)) << 16);
        uint32_t hi = (uint32_t)f2bf(fmaxf(v[2] + b2, 0.f)) |
                      ((uint32_t)f2bf(fmaxf(v[3] + b3, 0.f)) << 16);
        W[col * 64 + (jj ^ (col & 31))] = lo;
        W[col * 64 + ((jj + 1) ^ (col & 31))] = hi;
      }
    }
    __syncthreads();
    if (tid < 128) {
      int col = tid & 63, sel = tid >> 6;
      int gcol = col0 + col;
      float sum = b2d[sel];
      const uint32_t* Wc = W + col * 64;
      const float* wd = w2d + sel * 128;
      #pragma unroll 8
      for (int c = 0; c < 64; ++c) {
        uint32_t v = Wc[c ^ (col & 31)];
        sum += wd[2 * c] * bf2f((u16)(v & 0xffffu)) + wd[2 * c + 1] * bf2f((u16)(v >> 16));
      }
      int b = gcol / 10000, pidx = gcol - b * 10000;
      out[((size_t)b * 2 + sel) * 10000 + pidx] = sigmoidf_(sum);
    }
  }
}

// ---------- launch ----------
extern "C" void kernel_launch(void* const* d_in, const int* in_sizes, int n_in, void* d_out,
                              int out_size, void* d_ws, size_t ws_size, hipStream_t stream) {
  const float* inputs = (const float*)d_in[0];
  const float* w_b1 = (const float*)d_in[1];
  const float* b_b1 = (const float*)d_in[2];
  const float* w_b2 = (const float*)d_in[3];
  const float* b_b2 = (const float*)d_in[4];
  const float* w_s1 = (const float*)d_in[5];
  const float* b_s1 = (const float*)d_in[6];
  const float* w_s2 = (const float*)d_in[7];
  const float* b_s2 = (const float*)d_in[8];
  const float* w_e1 = (const float*)d_in[9];
  const float* b_e1 = (const float*)d_in[10];
  const float* w_e2 = (const float*)d_in[11];
  const float* b_e2 = (const float*)d_in[12];
  const float* w_p1 = (const float*)d_in[13];
  const float* b_p1 = (const float*)d_in[14];
  const float* w3d = (const float*)d_in[15];
  const float* b3d = (const float*)d_in[16];
  const float* w2a = (const float*)d_in[17];
  const float* b2a = (const float*)d_in[18];
  const float* w2b = (const float*)d_in[19];
  const float* b2b = (const float*)d_in[20];
  const float* w2c = (const float*)d_in[21];
  const float* b2c = (const float*)d_in[22];
  const float* w2d = (const float*)d_in[23];
  const float* b2d = (const float*)d_in[24];
  float* out = (float*)d_out;
  char* ws = (char*)d_ws;

  int* tinfo = (int*)(ws + 0);
  int* order = (int*)(ws + 2048);
  u16* zp = (u16*)(ws + 16384);
  int* invperm = (int*)(ws + 45056);
  float* base1 = (float*)(ws + 90112);          // 409600
  float* base = (float*)(ws + 499712);          // 409600
  float* s1buf = (float*)(ws + 909312);         // 409600
  u16* Pt = (u16*)(ws + 1318912);               // 102400
  u16* w2a_bf = (u16*)(ws + 1421312);           // 131072
  u16* w2b_pk = (u16*)(ws + 1552384);           // 294912
  u16* w2c_pk = (u16*)(ws + 1847296);           // 294912
  u16* Qb = (u16*)(ws + 2142208);               // 13107200 (ends 15249408)
  u16* Mt = (u16*)(ws + 15249408);              // rows 0..5119 used -> ends 48017408
  float* e1buf = (float*)(ws + 48017408);       // 409600, in Mt-region free tail (no alias!)
  u16* C1t = (u16*)(ws + 79249408);             // 40960000  (end 120209408)
  u16* Wq = (u16*)(ws + 79249408);              // aliases C1t: dead before G1 writes C1t
  u16* x2t = Qb;   // alias: Qb dead after G1
  u16* x3t = C1t;  // alias: C1t dead after G2

  // 1) fused prep: conv1 first (overlaps), weight casts, invperm, tile spans, mask rows
  prep_fused<<<3641, 256, 0, stream>>>(w2a, w2b, w2c, w2a_bf, w2b_pk, w2c_pk, w3d, Wq,
                                       invperm, tinfo, order, zp, Mt, inputs, w_b1, b_b1,
                                       base1);

  // 2-3) front end (fp32 exact; conv2 + p-branch ic-split 4-way for occupancy)
  conv2_r<<<400, 256, 0, stream>>>(base1, w_b2, b_b2, base);
  branch_split<<<400, 256, 0, stream>>>(base, w_s1, b_s1, w_e1, b_e1, w_p1, b_p1,
                                        s1buf, e1buf, Pt);

  // 4) qprep GEMM [16384 x 400 x 128] + fused start/end sigmoid heads
  qprep_sig<<<dim3(129, 4), 256, 0, stream>>>(Wq, Pt, Qb, s1buf, e1buf, w_s2, b_s2,
                                              w_e2, b_e2, out);

  // 5) G1: out3d, 128x128 tiles, longest-first; de-permuted coalesced store into C1t
  gemm_bt<<<dim3(16, 79), 256, 0, stream>>>(Qb, Mt, C1t, b3d, 10000, 3200, tinfo, order, 50,
                                            512, 10000LL, 10000, invperm);
  // 6) G2: 1x1 conv 512->128, 64-col tiles (625 blocks, tail-balanced)
  gemm_bt64<<<625, 256, 0, stream>>>(w2a_bf, C1t, x2t, b2a);
  // 7) G3: 3x3 conv 128->128, 64-col tiles
  conv3x3_gemm64<0><<<625, 256, 0, stream>>>(w2b_pk, x2t, x3t, b2b, zp, nullptr, nullptr,
                                             nullptr);
  // 8) G4: 3x3 conv 128->128 + fused conf head, 64-col tiles
  conv3x3_gemm64<1><<<625, 256, 0, stream>>>(w2c_pk, x3t, nullptr, b2c, zp, w2d, b2d,
                                             out);
}